// Round 1
// baseline (3902.456 us; speedup 1.0000x reference)
//
#include <hip/hip_runtime.h>
#include <math.h>

// ---------------- problem constants ----------------
#define NUSERS   100000
#define NITEMS   100000
#define NNODES   200000
#define DD       64
#define NI       128
#define E_UI     1000000
#define E_MP     500000
#define BB       4096

// ---------------- workspace layout (float/int elements, 4B each) ----------------
// zero-initialized region first (single memset)
#define O_CNT       0LL          // 600000 ints: [0,200K) main node deg, [200K,600K) mp in-deg (4 graphs x 100K)
#define O_OUTCNT    600000LL     // 400000 ints: mp out-deg
#define O_CURSOR    1000000LL    // 600000 ints: scatter cursors
#define O_PARTIALS  1600000LL    // 100000 f32: mp_score per-block partials (4 x 25000)
#define O_SUMEXP    1700000LL    // 8192 f32
#define O_POS       1708192LL    // 8192 f32 (fully written, zeroing harmless)
#define ZEND        1716384LL
// non-zeroed
#define O_OFF       1716384LL    // 600064 ints
#define O_BSUM      2316448LL    // 1024 ints
#define O_DINV      2317472LL    // 200000 f32
#define O_OINV      2517472LL    // 400000 f32
#define O_IINV      2917472LL    // 400000 f32
#define O_ADJ       3317472LL    // 4000000 ints (2M main + 2M mp, combined index space)
#define O_WSUM      7317472LL    // 8 f32
#define O_EMB       7317480LL    // 12800000 f32
#define O_TOTAL     20117480LL   // 12800000 f32
#define O_GNN       32917480LL   // 12800000 f32
#define O_E1U       45717480LL   // 262144 f32
#define O_E2U       45979624LL   // 262144 f32
#define O_E1I       46241768LL   // 262144 f32
#define O_E2I       46503912LL   // 262144 f32
// END = 46766056 elems = ~187 MB

// ---------------- degree histograms ----------------
__global__ void k_hist_main(const int* __restrict__ src, const int* __restrict__ dst,
                            int* __restrict__ cnt) {
  int e = blockIdx.x * 256 + threadIdx.x;
  if (e < E_UI) {
    atomicAdd(&cnt[src[e]], 1);
    atomicAdd(&cnt[NUSERS + dst[e]], 1);
  }
}

__global__ void k_hist_mp(const int* __restrict__ mpu, const int* __restrict__ mpi,
                          int* __restrict__ cnt, int* __restrict__ outcnt) {
  int e = blockIdx.x * 256 + threadIdx.x;
  int g = blockIdx.y;  // 0,1 user graphs; 2,3 item graphs
  if (e < E_MP) {
    const int* base = (g < 2) ? (mpu + (long long)g * 2 * E_MP)
                              : (mpi + (long long)(g - 2) * 2 * E_MP);
    int s = base[e];
    int d = base[E_MP + e];
    atomicAdd(&outcnt[g * NUSERS + s], 1);
    atomicAdd(&cnt[NNODES + g * NUSERS + d], 1);
  }
}

// ---------------- exclusive scan (3-phase, 1024 elems/block) ----------------
__global__ __launch_bounds__(1024) void k_scan1(const int* __restrict__ in, int* __restrict__ out,
                                                int* __restrict__ bsum, int n) {
  __shared__ int s[1024];
  int i = blockIdx.x * 1024 + threadIdx.x;
  int v = (i < n) ? in[i] : 0;
  s[threadIdx.x] = v;
  __syncthreads();
  for (int off = 1; off < 1024; off <<= 1) {
    int x = (threadIdx.x >= off) ? s[threadIdx.x - off] : 0;
    __syncthreads();
    s[threadIdx.x] += x;
    __syncthreads();
  }
  if (i < n) out[i] = s[threadIdx.x] - v;  // exclusive
  if (threadIdx.x == 1023) bsum[blockIdx.x] = s[1023];
}

__global__ __launch_bounds__(1024) void k_scan2(int* __restrict__ bsum, int nb) {
  __shared__ int s[1024];
  int v = (threadIdx.x < nb) ? bsum[threadIdx.x] : 0;
  s[threadIdx.x] = v;
  __syncthreads();
  for (int off = 1; off < 1024; off <<= 1) {
    int x = (threadIdx.x >= off) ? s[threadIdx.x - off] : 0;
    __syncthreads();
    s[threadIdx.x] += x;
    __syncthreads();
  }
  if (threadIdx.x < nb) bsum[threadIdx.x] = s[threadIdx.x] - v;
}

__global__ __launch_bounds__(1024) void k_scan3(int* __restrict__ out, const int* __restrict__ bsum, int n) {
  int i = blockIdx.x * 1024 + threadIdx.x;
  if (i < n) out[i] += bsum[blockIdx.x];
}

// ---------------- inverse-sqrt degree arrays ----------------
__global__ void k_inv(const int* __restrict__ cnt, const int* __restrict__ outcnt,
                      float* __restrict__ dinv, float* __restrict__ iinv, float* __restrict__ oinv) {
  int i = blockIdx.x * 256 + threadIdx.x;
  if (i < NNODES) {
    int c = cnt[i]; if (c < 1) c = 1;
    dinv[i] = 1.0f / sqrtf((float)c);
  } else if (i < 600000) {
    int c = cnt[i]; if (c < 1) c = 1;
    iinv[i - NNODES] = 1.0f / sqrtf((float)c);
  }
  if (i < 400000) {
    int c = outcnt[i]; if (c < 1) c = 1;
    oinv[i] = 1.0f / sqrtf((float)c);
  }
}

// ---------------- CSR scatter ----------------
__global__ void k_scatter_main(const int* __restrict__ src, const int* __restrict__ dst,
                               const int* __restrict__ off, int* __restrict__ cursor,
                               int* __restrict__ adj) {
  int e = blockIdx.x * 256 + threadIdx.x;
  if (e < E_UI) {
    int u = src[e];
    int it = NUSERS + dst[e];
    int p = atomicAdd(&cursor[u], 1);
    adj[off[u] + p] = it;
    int q = atomicAdd(&cursor[it], 1);
    adj[off[it] + q] = u;
  }
}

__global__ void k_scatter_mp(const int* __restrict__ mpu, const int* __restrict__ mpi,
                             const int* __restrict__ off, int* __restrict__ cursor,
                             int* __restrict__ adj) {
  int e = blockIdx.x * 256 + threadIdx.x;
  int g = blockIdx.y;
  if (e < E_MP) {
    const int* base = (g < 2) ? (mpu + (long long)g * 2 * E_MP)
                              : (mpi + (long long)(g - 2) * 2 * E_MP);
    int s = base[e];
    int d = base[E_MP + e];
    int node = NNODES + g * NUSERS + d;
    int p = atomicAdd(&cursor[node], 1);
    adj[off[node] + p] = s;
  }
}

// ---------------- emb/total init (float4 vectorized) ----------------
__global__ void k_init(const float4* __restrict__ uf, const float4* __restrict__ itf,
                       float4* __restrict__ emb, float4* __restrict__ total) {
  int i = blockIdx.x * 256 + threadIdx.x;  // 3.2M float4s
  if (i < 3200000) {
    float4 v = (i < 1600000) ? uf[i] : itf[i - 1600000];
    emb[i] = v;
    total[i] = v;
  }
}

// ---------------- spmm: gnn[r] = dinv[r] * sum dinv[c]*emb[c] ----------------
__global__ __launch_bounds__(256) void k_spmm(const float* __restrict__ emb, float* __restrict__ gnn,
                                              const int* __restrict__ adj, const int* __restrict__ off,
                                              const int* __restrict__ cnt, const float* __restrict__ dinv) {
  int row = (blockIdx.x << 2) + (threadIdx.x >> 6);  // wave per row
  int lane = threadIdx.x & 63;
  int start = off[row];
  int c = cnt[row];
  float acc = 0.0f;
  for (int k = 0; k < c; k++) {
    int nb = adj[start + k];
    acc += dinv[nb] * emb[((long long)nb << 6) + lane];
  }
  gnn[((long long)row << 6) + lane] = dinv[row] * acc;
}

// ---------------- intent attention + layer update (fused) ----------------
// new_emb = gnn + softmax(emb@UI)@UI^T + emb ; total += new_emb
__global__ __launch_bounds__(256) void k_fuse(float* __restrict__ emb, const float* __restrict__ gnn,
                                              float* __restrict__ total,
                                              const float* __restrict__ UIu, const float* __restrict__ UIi) {
  __shared__ float sUIT[128 * 65];  // sUIT[j*65+d] = UI[d][j]; pad 65 -> 2-way max (free)
  const float* G = blockIdx.y ? UIi : UIu;
  for (int idx = threadIdx.x; idx < DD * NI; idx += 256) {
    int d = idx >> 7, j = idx & 127;
    sUIT[j * 65 + d] = G[idx];
  }
  __syncthreads();
  int lane = threadIdx.x & 63;
  int node = blockIdx.y * NUSERS + (blockIdx.x << 2) + (threadIdx.x >> 6);
  long long base = (long long)node << 6;
  float v = emb[base + lane];
  // phase 1: s_j = sum_d emb_d * UI[d][j], lane holds j=lane and j=lane+64
  float s0 = 0.0f, s1 = 0.0f;
  for (int d = 0; d < 64; d++) {
    float ed = __shfl(v, d);
    s0 += ed * sUIT[lane * 65 + d];
    s1 += ed * sUIT[(lane + 64) * 65 + d];
  }
  // softmax over 128
  float mx = fmaxf(s0, s1);
  for (int m = 32; m; m >>= 1) mx = fmaxf(mx, __shfl_xor(mx, m));
  float e0 = expf(s0 - mx), e1 = expf(s1 - mx);
  float sm = e0 + e1;
  for (int m = 32; m; m >>= 1) sm += __shfl_xor(sm, m);
  float p0 = e0 / sm, p1 = e1 / sm;
  // phase 2: out_d = sum_j p_j * UI[d][j], lane = d
  float o = 0.0f;
  for (int j = 0; j < 64; j++) o += __shfl(p0, j) * sUIT[j * 65 + lane];
  for (int j = 0; j < 64; j++) o += __shfl(p1, j) * sUIT[(64 + j) * 65 + lane];
  float ne = gnn[base + lane] + o + v;
  emb[base + lane] = ne;
  total[base + lane] += ne;
}

// ---------------- metapath graphconv + semantic-att score sweep ----------------
__global__ __launch_bounds__(256) void k_mp_score(
    const float* __restrict__ uf, const float* __restrict__ itf,
    const float* __restrict__ W1u, const float* __restrict__ b1u, const float* __restrict__ w2u,
    const float* __restrict__ W1i, const float* __restrict__ b1i, const float* __restrict__ w2i,
    const int* __restrict__ adj, const int* __restrict__ off, const int* __restrict__ cnt,
    const float* __restrict__ oinv, const float* __restrict__ iinv, float* __restrict__ partials) {
  int g = blockIdx.y;
  const float* feat = (g < 2) ? uf : itf;
  const float* W1 = (g < 2) ? W1u : W1i;
  const float* b1 = (g < 2) ? b1u : b1i;
  const float* w2 = (g < 2) ? w2u : w2i;
  __shared__ float sW1[64 * 128];
  __shared__ float red[4];
  for (int idx = threadIdx.x; idx < 8192; idx += 256) sW1[idx] = W1[idx];
  __syncthreads();
  int lane = threadIdx.x & 63, w = threadIdx.x >> 6;
  int n = (blockIdx.x << 2) + w;
  int node = NNODES + g * NUSERS + n;
  int start = off[node];
  int c = cnt[node];
  float z = 0.0f;
  for (int k = 0; k < c; k++) {
    int s = adj[start + k];
    z += oinv[g * NUSERS + s] * feat[((long long)s << 6) + lane];
  }
  z *= iinv[g * NUSERS + n];
  // score = tanh(z@W1+b1) . w2  (lane handles hid units lane, lane+64)
  float h0 = b1[lane], h1 = b1[lane + 64];
  for (int d = 0; d < 64; d++) {
    float zd = __shfl(z, d);
    h0 += zd * sW1[(d << 7) + lane];
    h1 += zd * sW1[(d << 7) + 64 + lane];
  }
  float p = tanhf(h0) * w2[lane] + tanhf(h1) * w2[lane + 64];
  for (int m = 32; m; m >>= 1) p += __shfl_xor(p, m);
  if (lane == 0) red[w] = p;
  __syncthreads();
  if (threadIdx.x == 0) partials[g * 25000 + blockIdx.x] = red[0] + red[1] + red[2] + red[3];
}

__global__ void k_beta(const float* __restrict__ partials, float* __restrict__ wsum) {
  int g = blockIdx.x;
  float s = 0.0f;
  for (int i = threadIdx.x; i < 25000; i += 256) s += partials[g * 25000 + i];
  for (int m = 32; m; m >>= 1) s += __shfl_xor(s, m);
  __shared__ float r[4];
  if ((threadIdx.x & 63) == 0) r[threadIdx.x >> 6] = s;
  __syncthreads();
  if (threadIdx.x == 0) wsum[g] = r[0] + r[1] + r[2] + r[3];
}

// ---------------- gather outputs + ssl embedding prep ----------------
__global__ __launch_bounds__(256) void k_h2out(
    const float* __restrict__ uf, const float* __restrict__ itf,
    const int* __restrict__ user_idx, const int* __restrict__ item_idx, const int* __restrict__ neg_idx,
    const float* __restrict__ total, const int* __restrict__ adj, const int* __restrict__ off,
    const int* __restrict__ cnt, const float* __restrict__ oinv, const float* __restrict__ iinv,
    const float* __restrict__ wsum, float* __restrict__ out,
    float* __restrict__ e1u, float* __restrict__ e2u,
    float* __restrict__ e1i, float* __restrict__ e2i, float* __restrict__ pos) {
  int lane = threadIdx.x & 63;
  int row = (blockIdx.x << 2) + (threadIdx.x >> 6);  // 0..12287
  int seg = row >> 12;
  int r = row & 4095;
  int idx;
  const float* feat;
  int gbase;
  if (seg == 0)      { idx = user_idx[r]; feat = uf;  gbase = 0; }
  else if (seg == 1) { idx = item_idx[r]; feat = itf; gbase = 2; }
  else               { idx = neg_idx[r];  feat = itf; gbase = 2; }
  int tnode = gbase ? (NUSERS + idx) : idx;
  float t = total[((long long)tnode << 6) + lane];
  // semantic-attention beta (softmax over the side's 2 metapath means)
  float w0 = wsum[gbase] * (1.0f / 100000.0f);
  float w1 = wsum[gbase + 1] * (1.0f / 100000.0f);
  float mb = fmaxf(w0, w1);
  float b0 = expf(w0 - mb), b1 = expf(w1 - mb);
  float bs = b0 + b1;
  b0 /= bs; b1 /= bs;
  float h2 = 0.0f;
  for (int m = 0; m < 2; m++) {
    int g = gbase + m;
    int node = NNODES + g * NUSERS + idx;
    int start = off[node];
    int c = cnt[node];
    float z = 0.0f;
    for (int k = 0; k < c; k++) {
      int s = adj[start + k];
      z += oinv[g * NUSERS + s] * feat[((long long)s << 6) + lane];
    }
    z *= iinv[g * NUSERS + idx];
    h2 += (m ? b1 : b0) * z;
  }
  out[((long long)row << 6) + lane] = 0.5f * t + 0.5f * h2;
  if (seg < 2) {
    float n1 = h2 * h2, n2 = t * t;
    for (int m = 32; m; m >>= 1) { n1 += __shfl_xor(n1, m); n2 += __shfl_xor(n2, m); }
    n1 = sqrtf(n1); n2 = sqrtf(n2);
    float a = h2 / n1, b = t / n2;  // matches ref: no epsilon
    float d = a * b;
    for (int m = 32; m; m >>= 1) d += __shfl_xor(d, m);
    float* e1 = seg ? e1i : e1u;
    float* e2 = seg ? e2i : e2u;
    e1[((long long)r << 6) + lane] = a;
    e2[((long long)r << 6) + lane] = b;
    if (lane == 0) pos[seg * BB + r] = 2.0f * d;
  }
}

// ---------------- ssl similarity matrix: sumexp[b] += exp(2 * e1_b . e2_k) ----------------
__global__ __launch_bounds__(256) void k_gemm(const float* __restrict__ e1u, const float* __restrict__ e2u,
                                              const float* __restrict__ e1i, const float* __restrict__ e2i,
                                              float* __restrict__ sumexp) {
  int side = blockIdx.z;
  const float* A = side ? e1i : e1u;
  const float* Bm = side ? e2i : e2u;
  __shared__ float sA[16 * 65], sB[16 * 65];
  int bb = blockIdx.y, kk = blockIdx.x;
  for (int idx = threadIdx.x; idx < 1024; idx += 256) {
    int rr = idx >> 6, cc = idx & 63;
    sA[rr * 65 + cc] = A[(((long long)bb * 16 + rr) << 6) + cc];
    sB[rr * 65 + cc] = Bm[(((long long)kk * 16 + rr) << 6) + cc];
  }
  __syncthreads();
  int tx = threadIdx.x & 15, ty = threadIdx.x >> 4;
  float acc = 0.0f;
  for (int d = 0; d < 64; d++) acc += sA[ty * 65 + d] * sB[tx * 65 + d];
  float val = expf(2.0f * acc);
  for (int m = 8; m; m >>= 1) val += __shfl_down(val, m, 16);
  if (tx == 0)
    __hip_atomic_fetch_add(&sumexp[side * BB + bb * 16 + ty], val,
                           __ATOMIC_RELAXED, __HIP_MEMORY_SCOPE_AGENT);
}

__global__ void k_loss(const float* __restrict__ sumexp, const float* __restrict__ pos,
                       float* __restrict__ out) {
  float s = 0.0f;
  for (int i = threadIdx.x; i < 2 * BB; i += 256) s += logf(sumexp[i]) - pos[i];
  for (int m = 32; m; m >>= 1) s += __shfl_xor(s, m);
  __shared__ float r[4];
  if ((threadIdx.x & 63) == 0) r[threadIdx.x >> 6] = s;
  __syncthreads();
  if (threadIdx.x == 0) out[3 * BB * DD] = (r[0] + r[1] + r[2] + r[3]) * (1.0f / (float)BB);
}

// ---------------- launch ----------------
extern "C" void kernel_launch(void* const* d_in, const int* in_sizes, int n_in,
                              void* d_out, int out_size, void* d_ws, size_t ws_size,
                              hipStream_t stream) {
  const float* uf  = (const float*)d_in[0];
  const float* itf = (const float*)d_in[1];
  const float* UIu = (const float*)d_in[2];
  const float* UIi = (const float*)d_in[3];
  const float* W1u = (const float*)d_in[4];
  const float* b1u = (const float*)d_in[5];
  const float* w2u = (const float*)d_in[6];
  const float* W1i = (const float*)d_in[7];
  const float* b1i = (const float*)d_in[8];
  const float* w2i = (const float*)d_in[9];
  const int* ui_src   = (const int*)d_in[10];
  const int* ui_dst   = (const int*)d_in[11];
  const int* mpu      = (const int*)d_in[12];
  const int* mpi      = (const int*)d_in[13];
  const int* user_idx = (const int*)d_in[14];
  const int* item_idx = (const int*)d_in[15];
  const int* neg_idx  = (const int*)d_in[16];
  float* out = (float*)d_out;

  float* wf = (float*)d_ws;
  int*   wi = (int*)d_ws;

  int*   cnt      = wi + O_CNT;
  int*   outcnt   = wi + O_OUTCNT;
  int*   cursor   = wi + O_CURSOR;
  float* partials = wf + O_PARTIALS;
  float* sumexp   = wf + O_SUMEXP;
  float* pos      = wf + O_POS;
  int*   off      = wi + O_OFF;
  int*   bsum     = wi + O_BSUM;
  float* dinv     = wf + O_DINV;
  float* oinv     = wf + O_OINV;
  float* iinv     = wf + O_IINV;
  int*   adj      = wi + O_ADJ;
  float* wsum     = wf + O_WSUM;
  float* emb      = wf + O_EMB;
  float* total    = wf + O_TOTAL;
  float* gnn      = wf + O_GNN;
  float* e1u      = wf + O_E1U;
  float* e2u      = wf + O_E2U;
  float* e1i      = wf + O_E1I;
  float* e2i      = wf + O_E2I;

  // zero the accumulator region
  hipMemsetAsync(d_ws, 0, (size_t)ZEND * 4, stream);

  // degree histograms
  k_hist_main<<<(E_UI + 255) / 256, 256, 0, stream>>>(ui_src, ui_dst, cnt);
  k_hist_mp<<<dim3((E_MP + 255) / 256, 4), 256, 0, stream>>>(mpu, mpi, cnt, outcnt);

  // exclusive scan over combined 600K counts -> CSR offsets
  const int NSCAN = 600000;
  const int NB = (NSCAN + 1023) / 1024;  // 586
  k_scan1<<<NB, 1024, 0, stream>>>(cnt, off, bsum, NSCAN);
  k_scan2<<<1, 1024, 0, stream>>>(bsum, NB);
  k_scan3<<<NB, 1024, 0, stream>>>(off, bsum, NSCAN);

  // inverse-sqrt degrees
  k_inv<<<(600000 + 255) / 256, 256, 0, stream>>>(cnt, outcnt, dinv, iinv, oinv);

  // CSR adjacency scatter
  k_scatter_main<<<(E_UI + 255) / 256, 256, 0, stream>>>(ui_src, ui_dst, off, cursor, adj);
  k_scatter_mp<<<dim3((E_MP + 255) / 256, 4), 256, 0, stream>>>(mpu, mpi, off, cursor, adj);

  // emb = total = features
  k_init<<<(3200000 + 255) / 256, 256, 0, stream>>>((const float4*)uf, (const float4*)itf,
                                                    (float4*)emb, (float4*)total);

  // 2 GNN layers
  for (int l = 0; l < 2; l++) {
    k_spmm<<<50000, 256, 0, stream>>>(emb, gnn, adj, off, cnt, dinv);
    k_fuse<<<dim3(25000, 2), 256, 0, stream>>>(emb, gnn, total, UIu, UIi);
  }

  // metapath semantic-attention score sweep + beta
  k_mp_score<<<dim3(25000, 4), 256, 0, stream>>>(uf, itf, W1u, b1u, w2u, W1i, b1i, w2i,
                                                 adj, off, cnt, oinv, iinv, partials);
  k_beta<<<4, 256, 0, stream>>>(partials, wsum);

  // gather outputs at sampled indices + normalized ssl embeddings + pos
  k_h2out<<<3072, 256, 0, stream>>>(uf, itf, user_idx, item_idx, neg_idx, total, adj, off, cnt,
                                    oinv, iinv, wsum, out, e1u, e2u, e1i, e2i, pos);

  // ssl logsumexp matrices + final loss
  k_gemm<<<dim3(256, 256, 2), 256, 0, stream>>>(e1u, e2u, e1i, e2i, sumexp);
  k_loss<<<1, 256, 0, stream>>>(sumexp, pos, out);
}

// Round 2
// 3442.257 us; speedup vs baseline: 1.1337x; 1.1337x over previous
//
#include <hip/hip_runtime.h>
#include <math.h>

// ---------------- problem constants ----------------
#define NUSERS   100000
#define NITEMS   100000
#define NNODES   200000
#define DD       64
#define NI       128
#define E_UI     1000000
#define E_MP     500000
#define BB       4096

// ---------------- workspace layout (float/int elements, 4B each) ----------------
// zero-initialized region first (single memset)
#define O_CNT       0LL          // 600000 ints
#define O_OUTCNT    600000LL     // 400000 ints
#define O_CURSOR    1000000LL    // 600000 ints
#define O_PARTIALS  1600000LL    // 100000 f32
#define O_SUMEXP    1700000LL    // 8192 f32
#define O_POS       1708192LL    // 8192 f32
#define ZEND        1716384LL
// non-zeroed
#define O_OFF       1716384LL    // 600064 ints
#define O_BSUM      2316448LL    // 1024 ints
#define O_DINV      2317472LL    // 200000 f32
#define O_OINV      2517472LL    // 400000 f32
#define O_IINV      2917472LL    // 400000 f32
#define O_ADJ       3317472LL    // 4000000 ints
#define O_WSUM      7317472LL    // 8 f32
#define O_EMBA      7317480LL    // 12800000 f32  (layer ping)
#define O_TOTAL     20117480LL   // 12800000 f32
#define O_EMBB      32917480LL   // 12800000 f32  (layer pong)
#define O_E1U       45717480LL   // 262144 f32
#define O_E2U       45979624LL   // 262144 f32
#define O_E1I       46241768LL   // 262144 f32
#define O_E2I       46503912LL   // 262144 f32

// ---------------- degree histograms ----------------
__global__ void k_hist_main(const int* __restrict__ src, const int* __restrict__ dst,
                            int* __restrict__ cnt) {
  int e = blockIdx.x * 256 + threadIdx.x;
  if (e < E_UI) {
    atomicAdd(&cnt[src[e]], 1);
    atomicAdd(&cnt[NUSERS + dst[e]], 1);
  }
}

__global__ void k_hist_mp(const int* __restrict__ mpu, const int* __restrict__ mpi,
                          int* __restrict__ cnt, int* __restrict__ outcnt) {
  int e = blockIdx.x * 256 + threadIdx.x;
  int g = blockIdx.y;
  if (e < E_MP) {
    const int* base = (g < 2) ? (mpu + (long long)g * 2 * E_MP)
                              : (mpi + (long long)(g - 2) * 2 * E_MP);
    int s = base[e];
    int d = base[E_MP + e];
    atomicAdd(&outcnt[g * NUSERS + s], 1);
    atomicAdd(&cnt[NNODES + g * NUSERS + d], 1);
  }
}

// ---------------- exclusive scan (3-phase) ----------------
__global__ __launch_bounds__(1024) void k_scan1(const int* __restrict__ in, int* __restrict__ out,
                                                int* __restrict__ bsum, int n) {
  __shared__ int s[1024];
  int i = blockIdx.x * 1024 + threadIdx.x;
  int v = (i < n) ? in[i] : 0;
  s[threadIdx.x] = v;
  __syncthreads();
  for (int off = 1; off < 1024; off <<= 1) {
    int x = (threadIdx.x >= off) ? s[threadIdx.x - off] : 0;
    __syncthreads();
    s[threadIdx.x] += x;
    __syncthreads();
  }
  if (i < n) out[i] = s[threadIdx.x] - v;
  if (threadIdx.x == 1023) bsum[blockIdx.x] = s[1023];
}

__global__ __launch_bounds__(1024) void k_scan2(int* __restrict__ bsum, int nb) {
  __shared__ int s[1024];
  int v = (threadIdx.x < nb) ? bsum[threadIdx.x] : 0;
  s[threadIdx.x] = v;
  __syncthreads();
  for (int off = 1; off < 1024; off <<= 1) {
    int x = (threadIdx.x >= off) ? s[threadIdx.x - off] : 0;
    __syncthreads();
    s[threadIdx.x] += x;
    __syncthreads();
  }
  if (threadIdx.x < nb) bsum[threadIdx.x] = s[threadIdx.x] - v;
}

__global__ __launch_bounds__(1024) void k_scan3(int* __restrict__ out, const int* __restrict__ bsum, int n) {
  int i = blockIdx.x * 1024 + threadIdx.x;
  if (i < n) out[i] += bsum[blockIdx.x];
}

// ---------------- inverse-sqrt degree arrays ----------------
__global__ void k_inv(const int* __restrict__ cnt, const int* __restrict__ outcnt,
                      float* __restrict__ dinv, float* __restrict__ iinv, float* __restrict__ oinv) {
  int i = blockIdx.x * 256 + threadIdx.x;
  if (i < NNODES) {
    int c = cnt[i]; if (c < 1) c = 1;
    dinv[i] = 1.0f / sqrtf((float)c);
  } else if (i < 600000) {
    int c = cnt[i]; if (c < 1) c = 1;
    iinv[i - NNODES] = 1.0f / sqrtf((float)c);
  }
  if (i < 400000) {
    int c = outcnt[i]; if (c < 1) c = 1;
    oinv[i] = 1.0f / sqrtf((float)c);
  }
}

// ---------------- CSR scatter ----------------
__global__ void k_scatter_main(const int* __restrict__ src, const int* __restrict__ dst,
                               const int* __restrict__ off, int* __restrict__ cursor,
                               int* __restrict__ adj) {
  int e = blockIdx.x * 256 + threadIdx.x;
  if (e < E_UI) {
    int u = src[e];
    int it = NUSERS + dst[e];
    int p = atomicAdd(&cursor[u], 1);
    adj[off[u] + p] = it;
    int q = atomicAdd(&cursor[it], 1);
    adj[off[it] + q] = u;
  }
}

__global__ void k_scatter_mp(const int* __restrict__ mpu, const int* __restrict__ mpi,
                             const int* __restrict__ off, int* __restrict__ cursor,
                             int* __restrict__ adj) {
  int e = blockIdx.x * 256 + threadIdx.x;
  int g = blockIdx.y;
  if (e < E_MP) {
    const int* base = (g < 2) ? (mpu + (long long)g * 2 * E_MP)
                              : (mpi + (long long)(g - 2) * 2 * E_MP);
    int s = base[e];
    int d = base[E_MP + e];
    int node = NNODES + g * NUSERS + d;
    int p = atomicAdd(&cursor[node], 1);
    adj[off[node] + p] = s;
  }
}

// ---------------- emb init ----------------
__global__ void k_init(const float4* __restrict__ uf, const float4* __restrict__ itf,
                       float4* __restrict__ emb) {
  int i = blockIdx.x * 256 + threadIdx.x;  // 3.2M float4s
  if (i < 3200000) {
    emb[i] = (i < 1600000) ? uf[i] : itf[i - 1600000];
  }
}

// ---------------- gather macro: unrolled, lane-preloaded indices ----------------
// acc += sum_k w(idx_k) * tbl[idx_k*64+lane]; indices pre-gathered per lane,
// 8 independent row loads in flight per unroll step.
#define GATHER_UNROLL(acc, tbl, adjp, start, c, mi, mw, lane)                          \
  for (int kb = 0; kb < (c); kb += 64) {                                              \
    int rem = (c) - kb; if (rem > 64) rem = 64;                                       \
    /* mi/mw loaded by caller-provided loader for this chunk */                        \
    LOAD_CHUNK(mi, mw, adjp, start, kb, rem, lane);                                   \
    int k = 0;                                                                        \
    for (; k + 8 <= rem; k += 8) {                                                    \
      int n0=__shfl(mi,k+0),n1=__shfl(mi,k+1),n2=__shfl(mi,k+2),n3=__shfl(mi,k+3);    \
      int n4=__shfl(mi,k+4),n5=__shfl(mi,k+5),n6=__shfl(mi,k+6),n7=__shfl(mi,k+7);    \
      float w0=__shfl(mw,k+0),w1=__shfl(mw,k+1),w2=__shfl(mw,k+2),w3=__shfl(mw,k+3);  \
      float w4=__shfl(mw,k+4),w5=__shfl(mw,k+5),w6=__shfl(mw,k+6),w7=__shfl(mw,k+7);  \
      float v0=(tbl)[((long long)n0<<6)+lane], v1=(tbl)[((long long)n1<<6)+lane];     \
      float v2=(tbl)[((long long)n2<<6)+lane], v3=(tbl)[((long long)n3<<6)+lane];     \
      float v4=(tbl)[((long long)n4<<6)+lane], v5=(tbl)[((long long)n5<<6)+lane];     \
      float v6=(tbl)[((long long)n6<<6)+lane], v7=(tbl)[((long long)n7<<6)+lane];     \
      acc += w0*v0; acc += w1*v1; acc += w2*v2; acc += w3*v3;                         \
      acc += w4*v4; acc += w5*v5; acc += w6*v6; acc += w7*v7;                         \
    }                                                                                 \
    for (; k < rem; k++) {                                                            \
      int nn=__shfl(mi,k); float ww=__shfl(mw,k);                                     \
      acc += ww * (tbl)[((long long)nn<<6)+lane];                                     \
    }                                                                                 \
  }

// ---------------- fused GNN layer: spmm + intent attention + residual + total ----------------
// enext = spmm(ecur) + softmax(ecur@UI)@UI^T + ecur ; total (=feat+sum of layers) updated
__global__ __launch_bounds__(256) void k_layer(
    const float* __restrict__ ecur, float* __restrict__ enext, float* __restrict__ total,
    const int* __restrict__ adj, const int* __restrict__ off, const int* __restrict__ cnt,
    const float* __restrict__ dinv,
    const float* __restrict__ UIu, const float* __restrict__ UIi, int layer) {
  __shared__ float sUIT[128 * 65];  // sUIT[j*65+d] = UI[d][j]
  const float* G = (blockIdx.x >= 25000) ? UIi : UIu;
  for (int idx = threadIdx.x; idx < DD * NI; idx += 256) {
    int d = idx >> 7, j = idx & 127;
    sUIT[j * 65 + d] = G[idx];
  }
  __syncthreads();
  int lane = threadIdx.x & 63;
  int node = (blockIdx.x << 2) + (threadIdx.x >> 6);
  long long base = (long long)node << 6;
  int start = off[node];
  int c = cnt[node];
  float acc = 0.0f;
#define LOAD_CHUNK(mi, mw, adjp, start, kb, rem, lane)                 \
    int mi = (lane < rem) ? (adjp)[(start) + (kb) + lane] : 0;         \
    float mw = dinv[mi];
  GATHER_UNROLL(acc, ecur, adj, start, c, mi, mw, lane)
#undef LOAD_CHUNK
  float gnnv = dinv[node] * acc;
  float v = ecur[base + lane];
  // intent attention: s_j = sum_d v_d * UI[d][j]
  float s0 = 0.0f, s1 = 0.0f;
  for (int d = 0; d < 64; d++) {
    float ed = __shfl(v, d);
    s0 += ed * sUIT[lane * 65 + d];
    s1 += ed * sUIT[(lane + 64) * 65 + d];
  }
  float mx = fmaxf(s0, s1);
  for (int m = 32; m; m >>= 1) mx = fmaxf(mx, __shfl_xor(mx, m));
  float e0 = expf(s0 - mx), e1 = expf(s1 - mx);
  float sm = e0 + e1;
  for (int m = 32; m; m >>= 1) sm += __shfl_xor(sm, m);
  float p0 = e0 / sm, p1 = e1 / sm;
  float o = 0.0f;
  for (int j = 0; j < 64; j++) o += __shfl(p0, j) * sUIT[j * 65 + lane];
  for (int j = 0; j < 64; j++) o += __shfl(p1, j) * sUIT[(64 + j) * 65 + lane];
  float ne = gnnv + o + v;
  enext[base + lane] = ne;
  if (layer == 0) total[base + lane] = v + ne;   // feat + layer1 emb
  else            total[base + lane] += ne;
}

// ---------------- metapath graphconv + semantic-att score sweep ----------------
__global__ __launch_bounds__(256) void k_mp_score(
    const float* __restrict__ uf, const float* __restrict__ itf,
    const float* __restrict__ W1u, const float* __restrict__ b1u, const float* __restrict__ w2u,
    const float* __restrict__ W1i, const float* __restrict__ b1i, const float* __restrict__ w2i,
    const int* __restrict__ adj, const int* __restrict__ off, const int* __restrict__ cnt,
    const float* __restrict__ oinv, const float* __restrict__ iinv, float* __restrict__ partials) {
  int g = blockIdx.y;
  const float* feat = (g < 2) ? uf : itf;
  const float* W1 = (g < 2) ? W1u : W1i;
  const float* b1 = (g < 2) ? b1u : b1i;
  const float* w2 = (g < 2) ? w2u : w2i;
  __shared__ float sW1[64 * 128];
  __shared__ float red[4];
  for (int idx = threadIdx.x; idx < 8192; idx += 256) sW1[idx] = W1[idx];
  __syncthreads();
  int lane = threadIdx.x & 63, w = threadIdx.x >> 6;
  int n = (blockIdx.x << 2) + w;
  int node = NNODES + g * NUSERS + n;
  int start = off[node];
  int c = cnt[node];
  int gofs = g * NUSERS;
  float z = 0.0f;
#define LOAD_CHUNK(mi, mw, adjp, start, kb, rem, lane)                 \
    int mi = (lane < rem) ? (adjp)[(start) + (kb) + lane] : 0;         \
    float mw = oinv[gofs + mi];
  GATHER_UNROLL(z, feat, adj, start, c, mi, mw, lane)
#undef LOAD_CHUNK
  z *= iinv[gofs + n];
  float h0 = b1[lane], h1 = b1[lane + 64];
  for (int d = 0; d < 64; d++) {
    float zd = __shfl(z, d);
    h0 += zd * sW1[(d << 7) + lane];
    h1 += zd * sW1[(d << 7) + 64 + lane];
  }
  float p = tanhf(h0) * w2[lane] + tanhf(h1) * w2[lane + 64];
  for (int m = 32; m; m >>= 1) p += __shfl_xor(p, m);
  if (lane == 0) red[w] = p;
  __syncthreads();
  if (threadIdx.x == 0) partials[g * 25000 + blockIdx.x] = red[0] + red[1] + red[2] + red[3];
}

__global__ void k_beta(const float* __restrict__ partials, float* __restrict__ wsum) {
  int g = blockIdx.x;
  float s = 0.0f;
  for (int i = threadIdx.x; i < 25000; i += 256) s += partials[g * 25000 + i];
  for (int m = 32; m; m >>= 1) s += __shfl_xor(s, m);
  __shared__ float r[4];
  if ((threadIdx.x & 63) == 0) r[threadIdx.x >> 6] = s;
  __syncthreads();
  if (threadIdx.x == 0) wsum[g] = r[0] + r[1] + r[2] + r[3];
}

// ---------------- gather outputs + ssl embedding prep ----------------
__global__ __launch_bounds__(256) void k_h2out(
    const float* __restrict__ uf, const float* __restrict__ itf,
    const int* __restrict__ user_idx, const int* __restrict__ item_idx, const int* __restrict__ neg_idx,
    const float* __restrict__ total, const int* __restrict__ adj, const int* __restrict__ off,
    const int* __restrict__ cnt, const float* __restrict__ oinv, const float* __restrict__ iinv,
    const float* __restrict__ wsum, float* __restrict__ out,
    float* __restrict__ e1u, float* __restrict__ e2u,
    float* __restrict__ e1i, float* __restrict__ e2i, float* __restrict__ pos) {
  int lane = threadIdx.x & 63;
  int row = (blockIdx.x << 2) + (threadIdx.x >> 6);  // 0..12287
  int seg = row >> 12;
  int r = row & 4095;
  int idx;
  const float* feat;
  int gbase;
  if (seg == 0)      { idx = user_idx[r]; feat = uf;  gbase = 0; }
  else if (seg == 1) { idx = item_idx[r]; feat = itf; gbase = 2; }
  else               { idx = neg_idx[r];  feat = itf; gbase = 2; }
  int tnode = gbase ? (NUSERS + idx) : idx;
  float t = total[((long long)tnode << 6) + lane];
  float w0 = wsum[gbase] * (1.0f / 100000.0f);
  float w1 = wsum[gbase + 1] * (1.0f / 100000.0f);
  float mb = fmaxf(w0, w1);
  float b0 = expf(w0 - mb), b1 = expf(w1 - mb);
  float bs = b0 + b1;
  b0 /= bs; b1 /= bs;
  float h2 = 0.0f;
  for (int m = 0; m < 2; m++) {
    int g = gbase + m;
    int gofs = g * NUSERS;
    int node = NNODES + g * NUSERS + idx;
    int start = off[node];
    int c = cnt[node];
    float z = 0.0f;
#define LOAD_CHUNK(mi, mw, adjp, start, kb, rem, lane)                 \
    int mi = (lane < rem) ? (adjp)[(start) + (kb) + lane] : 0;         \
    float mw = oinv[gofs + mi];
    GATHER_UNROLL(z, feat, adj, start, c, mi, mw, lane)
#undef LOAD_CHUNK
    z *= iinv[gofs + idx];
    h2 += (m ? b1 : b0) * z;
  }
  out[((long long)row << 6) + lane] = 0.5f * t + 0.5f * h2;
  if (seg < 2) {
    float n1 = h2 * h2, n2 = t * t;
    for (int m = 32; m; m >>= 1) { n1 += __shfl_xor(n1, m); n2 += __shfl_xor(n2, m); }
    n1 = sqrtf(n1); n2 = sqrtf(n2);
    float a = h2 / n1, b = t / n2;
    float d = a * b;
    for (int m = 32; m; m >>= 1) d += __shfl_xor(d, m);
    float* e1 = seg ? e1i : e1u;
    float* e2 = seg ? e2i : e2u;
    e1[((long long)r << 6) + lane] = a;
    e2[((long long)r << 6) + lane] = b;
    if (lane == 0) pos[seg * BB + r] = 2.0f * d;
  }
}

// ---------------- ssl similarity matrix ----------------
__global__ __launch_bounds__(256) void k_gemm(const float* __restrict__ e1u, const float* __restrict__ e2u,
                                              const float* __restrict__ e1i, const float* __restrict__ e2i,
                                              float* __restrict__ sumexp) {
  int side = blockIdx.z;
  const float* A = side ? e1i : e1u;
  const float* Bm = side ? e2i : e2u;
  __shared__ float sA[16 * 65], sB[16 * 65];
  int bb = blockIdx.y, kk = blockIdx.x;
  for (int idx = threadIdx.x; idx < 1024; idx += 256) {
    int rr = idx >> 6, cc = idx & 63;
    sA[rr * 65 + cc] = A[(((long long)bb * 16 + rr) << 6) + cc];
    sB[rr * 65 + cc] = Bm[(((long long)kk * 16 + rr) << 6) + cc];
  }
  __syncthreads();
  int tx = threadIdx.x & 15, ty = threadIdx.x >> 4;
  float acc = 0.0f;
  for (int d = 0; d < 64; d++) acc += sA[ty * 65 + d] * sB[tx * 65 + d];
  float val = expf(2.0f * acc);
  for (int m = 8; m; m >>= 1) val += __shfl_down(val, m, 16);
  if (tx == 0)
    __hip_atomic_fetch_add(&sumexp[side * BB + bb * 16 + ty], val,
                           __ATOMIC_RELAXED, __HIP_MEMORY_SCOPE_AGENT);
}

__global__ void k_loss(const float* __restrict__ sumexp, const float* __restrict__ pos,
                       float* __restrict__ out) {
  float s = 0.0f;
  for (int i = threadIdx.x; i < 2 * BB; i += 256) s += logf(sumexp[i]) - pos[i];
  for (int m = 32; m; m >>= 1) s += __shfl_xor(s, m);
  __shared__ float r[4];
  if ((threadIdx.x & 63) == 0) r[threadIdx.x >> 6] = s;
  __syncthreads();
  if (threadIdx.x == 0) out[3 * BB * DD] = (r[0] + r[1] + r[2] + r[3]) * (1.0f / (float)BB);
}

// ---------------- launch ----------------
extern "C" void kernel_launch(void* const* d_in, const int* in_sizes, int n_in,
                              void* d_out, int out_size, void* d_ws, size_t ws_size,
                              hipStream_t stream) {
  const float* uf  = (const float*)d_in[0];
  const float* itf = (const float*)d_in[1];
  const float* UIu = (const float*)d_in[2];
  const float* UIi = (const float*)d_in[3];
  const float* W1u = (const float*)d_in[4];
  const float* b1u = (const float*)d_in[5];
  const float* w2u = (const float*)d_in[6];
  const float* W1i = (const float*)d_in[7];
  const float* b1i = (const float*)d_in[8];
  const float* w2i = (const float*)d_in[9];
  const int* ui_src   = (const int*)d_in[10];
  const int* ui_dst   = (const int*)d_in[11];
  const int* mpu      = (const int*)d_in[12];
  const int* mpi      = (const int*)d_in[13];
  const int* user_idx = (const int*)d_in[14];
  const int* item_idx = (const int*)d_in[15];
  const int* neg_idx  = (const int*)d_in[16];
  float* out = (float*)d_out;

  float* wf = (float*)d_ws;
  int*   wi = (int*)d_ws;

  int*   cnt      = wi + O_CNT;
  int*   outcnt   = wi + O_OUTCNT;
  int*   cursor   = wi + O_CURSOR;
  float* partials = wf + O_PARTIALS;
  float* sumexp   = wf + O_SUMEXP;
  float* pos      = wf + O_POS;
  int*   off      = wi + O_OFF;
  int*   bsum     = wi + O_BSUM;
  float* dinv     = wf + O_DINV;
  float* oinv     = wf + O_OINV;
  float* iinv     = wf + O_IINV;
  int*   adj      = wi + O_ADJ;
  float* wsum     = wf + O_WSUM;
  float* emba     = wf + O_EMBA;
  float* total    = wf + O_TOTAL;
  float* embb     = wf + O_EMBB;
  float* e1u      = wf + O_E1U;
  float* e2u      = wf + O_E2U;
  float* e1i      = wf + O_E1I;
  float* e2i      = wf + O_E2I;

  hipMemsetAsync(d_ws, 0, (size_t)ZEND * 4, stream);

  k_hist_main<<<(E_UI + 255) / 256, 256, 0, stream>>>(ui_src, ui_dst, cnt);
  k_hist_mp<<<dim3((E_MP + 255) / 256, 4), 256, 0, stream>>>(mpu, mpi, cnt, outcnt);

  const int NSCAN = 600000;
  const int NB = (NSCAN + 1023) / 1024;
  k_scan1<<<NB, 1024, 0, stream>>>(cnt, off, bsum, NSCAN);
  k_scan2<<<1, 1024, 0, stream>>>(bsum, NB);
  k_scan3<<<NB, 1024, 0, stream>>>(off, bsum, NSCAN);

  k_inv<<<(600000 + 255) / 256, 256, 0, stream>>>(cnt, outcnt, dinv, iinv, oinv);

  k_scatter_main<<<(E_UI + 255) / 256, 256, 0, stream>>>(ui_src, ui_dst, off, cursor, adj);
  k_scatter_mp<<<dim3((E_MP + 255) / 256, 4), 256, 0, stream>>>(mpu, mpi, off, cursor, adj);

  k_init<<<(3200000 + 255) / 256, 256, 0, stream>>>((const float4*)uf, (const float4*)itf,
                                                    (float4*)emba);

  // fused layers (double-buffered)
  k_layer<<<50000, 256, 0, stream>>>(emba, embb, total, adj, off, cnt, dinv, UIu, UIi, 0);
  k_layer<<<50000, 256, 0, stream>>>(embb, emba, total, adj, off, cnt, dinv, UIu, UIi, 1);

  k_mp_score<<<dim3(25000, 4), 256, 0, stream>>>(uf, itf, W1u, b1u, w2u, W1i, b1i, w2i,
                                                 adj, off, cnt, oinv, iinv, partials);
  k_beta<<<4, 256, 0, stream>>>(partials, wsum);

  k_h2out<<<3072, 256, 0, stream>>>(uf, itf, user_idx, item_idx, neg_idx, total, adj, off, cnt,
                                    oinv, iinv, wsum, out, e1u, e2u, e1i, e2i, pos);

  k_gemm<<<dim3(256, 256, 2), 256, 0, stream>>>(e1u, e2u, e1i, e2i, sumexp);
  k_loss<<<1, 256, 0, stream>>>(sumexp, pos, out);
}

// Round 3
// 2344.348 us; speedup vs baseline: 1.6646x; 1.4683x over previous
//
#include <hip/hip_runtime.h>
#include <math.h>

// ---------------- problem constants ----------------
#define NUSERS   100000
#define NITEMS   100000
#define NNODES   200000
#define DD       64
#define NI       128
#define E_UI     1000000
#define E_MP     500000
#define BB       4096

// ---------------- workspace layout (float/int elements, 4B each) ----------------
#define O_CNT       0LL
#define O_OUTCNT    600000LL
#define O_CURSOR    1000000LL
#define O_PARTIALS  1600000LL
#define O_SUMEXP    1700000LL
#define O_POS       1708192LL
#define ZEND        1716384LL
#define O_OFF       1716384LL
#define O_BSUM      2316448LL
#define O_DINV      2317472LL
#define O_OINV      2517472LL
#define O_IINV      2917472LL
#define O_ADJ       3317472LL
#define O_WSUM      7317472LL
#define O_EMBA      7317480LL
#define O_TOTAL     20117480LL
#define O_EMBB      32917480LL
#define O_E1U       45717480LL
#define O_E2U       45979624LL
#define O_E1I       46241768LL
#define O_E2I       46503912LL

// ---------------- degree histograms ----------------
__global__ void k_hist_main(const int* __restrict__ src, const int* __restrict__ dst,
                            int* __restrict__ cnt) {
  int e = blockIdx.x * 256 + threadIdx.x;
  if (e < E_UI) {
    atomicAdd(&cnt[src[e]], 1);
    atomicAdd(&cnt[NUSERS + dst[e]], 1);
  }
}

__global__ void k_hist_mp(const int* __restrict__ mpu, const int* __restrict__ mpi,
                          int* __restrict__ cnt, int* __restrict__ outcnt) {
  int e = blockIdx.x * 256 + threadIdx.x;
  int g = blockIdx.y;
  if (e < E_MP) {
    const int* base = (g < 2) ? (mpu + (long long)g * 2 * E_MP)
                              : (mpi + (long long)(g - 2) * 2 * E_MP);
    int s = base[e];
    int d = base[E_MP + e];
    atomicAdd(&outcnt[g * NUSERS + s], 1);
    atomicAdd(&cnt[NNODES + g * NUSERS + d], 1);
  }
}

// ---------------- exclusive scan ----------------
__global__ __launch_bounds__(1024) void k_scan1(const int* __restrict__ in, int* __restrict__ out,
                                                int* __restrict__ bsum, int n) {
  __shared__ int s[1024];
  int i = blockIdx.x * 1024 + threadIdx.x;
  int v = (i < n) ? in[i] : 0;
  s[threadIdx.x] = v;
  __syncthreads();
  for (int off = 1; off < 1024; off <<= 1) {
    int x = (threadIdx.x >= off) ? s[threadIdx.x - off] : 0;
    __syncthreads();
    s[threadIdx.x] += x;
    __syncthreads();
  }
  if (i < n) out[i] = s[threadIdx.x] - v;
  if (threadIdx.x == 1023) bsum[blockIdx.x] = s[1023];
}

__global__ __launch_bounds__(1024) void k_scan2(int* __restrict__ bsum, int nb) {
  __shared__ int s[1024];
  int v = (threadIdx.x < nb) ? bsum[threadIdx.x] : 0;
  s[threadIdx.x] = v;
  __syncthreads();
  for (int off = 1; off < 1024; off <<= 1) {
    int x = (threadIdx.x >= off) ? s[threadIdx.x - off] : 0;
    __syncthreads();
    s[threadIdx.x] += x;
    __syncthreads();
  }
  if (threadIdx.x < nb) bsum[threadIdx.x] = s[threadIdx.x] - v;
}

__global__ __launch_bounds__(1024) void k_scan3(int* __restrict__ out, const int* __restrict__ bsum, int n) {
  int i = blockIdx.x * 1024 + threadIdx.x;
  if (i < n) out[i] += bsum[blockIdx.x];
}

// ---------------- inverse-sqrt degrees ----------------
__global__ void k_inv(const int* __restrict__ cnt, const int* __restrict__ outcnt,
                      float* __restrict__ dinv, float* __restrict__ iinv, float* __restrict__ oinv) {
  int i = blockIdx.x * 256 + threadIdx.x;
  if (i < NNODES) {
    int c = cnt[i]; if (c < 1) c = 1;
    dinv[i] = 1.0f / sqrtf((float)c);
  } else if (i < 600000) {
    int c = cnt[i]; if (c < 1) c = 1;
    iinv[i - NNODES] = 1.0f / sqrtf((float)c);
  }
  if (i < 400000) {
    int c = outcnt[i]; if (c < 1) c = 1;
    oinv[i] = 1.0f / sqrtf((float)c);
  }
}

// ---------------- CSR scatter ----------------
__global__ void k_scatter_main(const int* __restrict__ src, const int* __restrict__ dst,
                               const int* __restrict__ off, int* __restrict__ cursor,
                               int* __restrict__ adj) {
  int e = blockIdx.x * 256 + threadIdx.x;
  if (e < E_UI) {
    int u = src[e];
    int it = NUSERS + dst[e];
    int p = atomicAdd(&cursor[u], 1);
    adj[off[u] + p] = it;
    int q = atomicAdd(&cursor[it], 1);
    adj[off[it] + q] = u;
  }
}

__global__ void k_scatter_mp(const int* __restrict__ mpu, const int* __restrict__ mpi,
                             const int* __restrict__ off, int* __restrict__ cursor,
                             int* __restrict__ adj) {
  int e = blockIdx.x * 256 + threadIdx.x;
  int g = blockIdx.y;
  if (e < E_MP) {
    const int* base = (g < 2) ? (mpu + (long long)g * 2 * E_MP)
                              : (mpi + (long long)(g - 2) * 2 * E_MP);
    int s = base[e];
    int d = base[E_MP + e];
    int node = NNODES + g * NUSERS + d;
    int p = atomicAdd(&cursor[node], 1);
    adj[off[node] + p] = s;
  }
}

// ---------------- emb init ----------------
__global__ void k_init(const float4* __restrict__ uf, const float4* __restrict__ itf,
                       float4* __restrict__ emb) {
  int i = blockIdx.x * 256 + threadIdx.x;
  if (i < 3200000) {
    emb[i] = (i < 1600000) ? uf[i] : itf[i - 1600000];
  }
}

// ---------------- masked-unroll-8 gather ----------------
// acc = sum over neighbors: warr[wofs+idx] * tbl[idx*64+lane]
// Always full batches of 8 (weights zeroed past rem) -> 8 loads in flight,
// ONE vmcnt drain per batch instead of one per edge.
__device__ __forceinline__ float gather_rows(const float* __restrict__ tbl,
                                             const int* __restrict__ adj,
                                             int start, int c,
                                             const float* __restrict__ warr, int wofs,
                                             int lane) {
  float acc = 0.0f;
  for (int kb = 0; kb < c; kb += 64) {
    int rem = c - kb; if (rem > 64) rem = 64;
    int mi = 0; float mw = 0.0f;
    if (lane < rem) { mi = adj[start + kb + lane]; mw = warr[wofs + mi]; }
    for (int k = 0; k < rem; k += 8) {
      int n0=__shfl(mi,k+0),n1=__shfl(mi,k+1),n2=__shfl(mi,k+2),n3=__shfl(mi,k+3);
      int n4=__shfl(mi,k+4),n5=__shfl(mi,k+5),n6=__shfl(mi,k+6),n7=__shfl(mi,k+7);
      float w0=__shfl(mw,k+0),w1=__shfl(mw,k+1),w2=__shfl(mw,k+2),w3=__shfl(mw,k+3);
      float w4=__shfl(mw,k+4),w5=__shfl(mw,k+5),w6=__shfl(mw,k+6),w7=__shfl(mw,k+7);
      float v0=tbl[((long long)n0<<6)+lane], v1=tbl[((long long)n1<<6)+lane];
      float v2=tbl[((long long)n2<<6)+lane], v3=tbl[((long long)n3<<6)+lane];
      float v4=tbl[((long long)n4<<6)+lane], v5=tbl[((long long)n5<<6)+lane];
      float v6=tbl[((long long)n6<<6)+lane], v7=tbl[((long long)n7<<6)+lane];
      acc += w0*v0; acc += w1*v1; acc += w2*v2; acc += w3*v3;
      acc += w4*v4; acc += w5*v5; acc += w6*v6; acc += w7*v7;
    }
  }
  return acc;
}

// ---------------- fused GNN layer ----------------
// enext = spmm(ecur) + softmax(ecur@UI)@UI^T + ecur ; total updated
// LDS-broadcast structure: no sequential shfls in matmul phases.
__global__ __launch_bounds__(256) void k_layer(
    const float* __restrict__ ecur, float* __restrict__ enext, float* __restrict__ total,
    const int* __restrict__ adj, const int* __restrict__ off, const int* __restrict__ cnt,
    const float* __restrict__ dinv,
    const float* __restrict__ UIu, const float* __restrict__ UIi, int layer) {
  __shared__ float sUIT[128 * 68];  // sUIT[j*68+d] = UI[d][j]; pad 68 -> 16B aligned rows
  __shared__ float sV[4][72];
  __shared__ float sP[4][136];
  const float* G = (blockIdx.x >= 25000) ? UIi : UIu;
  for (int t = threadIdx.x; t < DD * NI; t += 256) {
    int d = t >> 7, j = t & 127;
    sUIT[j * 68 + d] = G[t];
  }
  __syncthreads();
  int lane = threadIdx.x & 63, w = threadIdx.x >> 6;
  int node = (blockIdx.x << 2) + w;
  long long base = (long long)node << 6;
  float v = ecur[base + lane];          // issue early, overlaps gather
  int start = off[node];
  int c = cnt[node];
  float acc = gather_rows(ecur, adj, start, c, dinv, 0, lane);
  float gnnv = dinv[node] * acc;
  sV[w][lane] = v;                      // same-wave LDS stage (no barrier needed)
  // phase 1: s_j = sum_d v_d * UI[d][j]; lane holds j=lane, j=lane+64
  const float* r0 = &sUIT[lane * 68];
  const float* r1 = &sUIT[(lane + 64) * 68];
  float s0a = 0.f, s0b = 0.f, s1a = 0.f, s1b = 0.f;
  for (int d8 = 0; d8 < 64; d8 += 8) {
    float4 za = *(const float4*)&sV[w][d8];
    float4 zb = *(const float4*)&sV[w][d8 + 4];
    float4 a0 = *(const float4*)&r0[d8];
    float4 b0 = *(const float4*)&r0[d8 + 4];
    float4 a1 = *(const float4*)&r1[d8];
    float4 b1 = *(const float4*)&r1[d8 + 4];
    s0a += za.x*a0.x + za.y*a0.y + za.z*a0.z + za.w*a0.w;
    s0b += zb.x*b0.x + zb.y*b0.y + zb.z*b0.z + zb.w*b0.w;
    s1a += za.x*a1.x + za.y*a1.y + za.z*a1.z + za.w*a1.w;
    s1b += zb.x*b1.x + zb.y*b1.y + zb.z*b1.z + zb.w*b1.w;
  }
  float s0 = s0a + s0b, s1 = s1a + s1b;
  float mx = fmaxf(s0, s1);
  for (int m = 32; m; m >>= 1) mx = fmaxf(mx, __shfl_xor(mx, m));
  float e0 = expf(s0 - mx), e1 = expf(s1 - mx);
  float sm = e0 + e1;
  for (int m = 32; m; m >>= 1) sm += __shfl_xor(sm, m);
  float p0 = e0 / sm, p1 = e1 / sm;
  sP[w][lane] = p0;
  sP[w][64 + lane] = p1;
  // phase 2: out_d = sum_j p_j * UI[d][j]; lane = d
  float oa = 0.f, ob = 0.f;
  for (int j = 0; j < 128; j += 8) {
    float4 pA = *(const float4*)&sP[w][j];
    float4 pB = *(const float4*)&sP[w][j + 4];
    oa += pA.x * sUIT[(j + 0) * 68 + lane] + pA.y * sUIT[(j + 1) * 68 + lane]
        + pA.z * sUIT[(j + 2) * 68 + lane] + pA.w * sUIT[(j + 3) * 68 + lane];
    ob += pB.x * sUIT[(j + 4) * 68 + lane] + pB.y * sUIT[(j + 5) * 68 + lane]
        + pB.z * sUIT[(j + 6) * 68 + lane] + pB.w * sUIT[(j + 7) * 68 + lane];
  }
  float ne = gnnv + (oa + ob) + v;
  enext[base + lane] = ne;
  if (layer == 0) total[base + lane] = v + ne;
  else            total[base + lane] += ne;
}

// ---------------- metapath graphconv + semantic-att score sweep ----------------
__global__ __launch_bounds__(256) void k_mp_score(
    const float* __restrict__ uf, const float* __restrict__ itf,
    const float* __restrict__ W1u, const float* __restrict__ b1u, const float* __restrict__ w2u,
    const float* __restrict__ W1i, const float* __restrict__ b1i, const float* __restrict__ w2i,
    const int* __restrict__ adj, const int* __restrict__ off, const int* __restrict__ cnt,
    const float* __restrict__ oinv, const float* __restrict__ iinv, float* __restrict__ partials) {
  int g = blockIdx.y;
  const float* feat = (g < 2) ? uf : itf;
  const float* W1 = (g < 2) ? W1u : W1i;
  const float* b1 = (g < 2) ? b1u : b1i;
  const float* w2 = (g < 2) ? w2u : w2i;
  __shared__ float sW1t[128 * 68];  // sW1t[j*68+d] = W1[d][j]
  __shared__ float sZ[4][72];
  __shared__ float red[4];
  for (int t = threadIdx.x; t < 8192; t += 256) {
    int d = t >> 7, j = t & 127;
    sW1t[j * 68 + d] = W1[t];
  }
  __syncthreads();
  int lane = threadIdx.x & 63, w = threadIdx.x >> 6;
  int n = (blockIdx.x << 2) + w;
  int node = NNODES + g * NUSERS + n;
  int start = off[node];
  int c = cnt[node];
  int gofs = g * NUSERS;
  float z = gather_rows(feat, adj, start, c, oinv, gofs, lane);
  z *= iinv[gofs + n];
  sZ[w][lane] = z;
  const float* r0 = &sW1t[lane * 68];
  const float* r1 = &sW1t[(lane + 64) * 68];
  float h0a = 0.f, h0b = 0.f, h1a = 0.f, h1b = 0.f;
  for (int d8 = 0; d8 < 64; d8 += 8) {
    float4 za = *(const float4*)&sZ[w][d8];
    float4 zb = *(const float4*)&sZ[w][d8 + 4];
    float4 a0 = *(const float4*)&r0[d8];
    float4 b0 = *(const float4*)&r0[d8 + 4];
    float4 a1 = *(const float4*)&r1[d8];
    float4 b1v = *(const float4*)&r1[d8 + 4];
    h0a += za.x*a0.x + za.y*a0.y + za.z*a0.z + za.w*a0.w;
    h0b += zb.x*b0.x + zb.y*b0.y + zb.z*b0.z + zb.w*b0.w;
    h1a += za.x*a1.x + za.y*a1.y + za.z*a1.z + za.w*a1.w;
    h1b += zb.x*b1v.x + zb.y*b1v.y + zb.z*b1v.z + zb.w*b1v.w;
  }
  float h0 = b1[lane] + h0a + h0b;
  float h1 = b1[lane + 64] + h1a + h1b;
  float p = tanhf(h0) * w2[lane] + tanhf(h1) * w2[lane + 64];
  for (int m = 32; m; m >>= 1) p += __shfl_xor(p, m);
  if (lane == 0) red[w] = p;
  __syncthreads();
  if (threadIdx.x == 0) partials[g * 25000 + blockIdx.x] = red[0] + red[1] + red[2] + red[3];
}

__global__ void k_beta(const float* __restrict__ partials, float* __restrict__ wsum) {
  int g = blockIdx.x;
  float s = 0.0f;
  for (int i = threadIdx.x; i < 25000; i += 256) s += partials[g * 25000 + i];
  for (int m = 32; m; m >>= 1) s += __shfl_xor(s, m);
  __shared__ float r[4];
  if ((threadIdx.x & 63) == 0) r[threadIdx.x >> 6] = s;
  __syncthreads();
  if (threadIdx.x == 0) wsum[g] = r[0] + r[1] + r[2] + r[3];
}

// ---------------- gather outputs + ssl embedding prep ----------------
__global__ __launch_bounds__(256) void k_h2out(
    const float* __restrict__ uf, const float* __restrict__ itf,
    const int* __restrict__ user_idx, const int* __restrict__ item_idx, const int* __restrict__ neg_idx,
    const float* __restrict__ total, const int* __restrict__ adj, const int* __restrict__ off,
    const int* __restrict__ cnt, const float* __restrict__ oinv, const float* __restrict__ iinv,
    const float* __restrict__ wsum, float* __restrict__ out,
    float* __restrict__ e1u, float* __restrict__ e2u,
    float* __restrict__ e1i, float* __restrict__ e2i, float* __restrict__ pos) {
  int lane = threadIdx.x & 63;
  int row = (blockIdx.x << 2) + (threadIdx.x >> 6);
  int seg = row >> 12;
  int r = row & 4095;
  int idx;
  const float* feat;
  int gbase;
  if (seg == 0)      { idx = user_idx[r]; feat = uf;  gbase = 0; }
  else if (seg == 1) { idx = item_idx[r]; feat = itf; gbase = 2; }
  else               { idx = neg_idx[r];  feat = itf; gbase = 2; }
  int tnode = gbase ? (NUSERS + idx) : idx;
  float t = total[((long long)tnode << 6) + lane];
  float w0 = wsum[gbase] * (1.0f / 100000.0f);
  float w1 = wsum[gbase + 1] * (1.0f / 100000.0f);
  float mb = fmaxf(w0, w1);
  float b0 = expf(w0 - mb), b1 = expf(w1 - mb);
  float bs = b0 + b1;
  b0 /= bs; b1 /= bs;
  float h2 = 0.0f;
  for (int m = 0; m < 2; m++) {
    int g = gbase + m;
    int gofs = g * NUSERS;
    int node = NNODES + g * NUSERS + idx;
    float z = gather_rows(feat, adj, off[node], cnt[node], oinv, gofs, lane);
    z *= iinv[gofs + idx];
    h2 += (m ? b1 : b0) * z;
  }
  out[((long long)row << 6) + lane] = 0.5f * t + 0.5f * h2;
  if (seg < 2) {
    float n1 = h2 * h2, n2 = t * t;
    for (int m = 32; m; m >>= 1) { n1 += __shfl_xor(n1, m); n2 += __shfl_xor(n2, m); }
    n1 = sqrtf(n1); n2 = sqrtf(n2);
    float a = h2 / n1, b = t / n2;
    float d = a * b;
    for (int m = 32; m; m >>= 1) d += __shfl_xor(d, m);
    float* e1 = seg ? e1i : e1u;
    float* e2 = seg ? e2i : e2u;
    e1[((long long)r << 6) + lane] = a;
    e2[((long long)r << 6) + lane] = b;
    if (lane == 0) pos[seg * BB + r] = 2.0f * d;
  }
}

// ---------------- ssl similarity matrix ----------------
__global__ __launch_bounds__(256) void k_gemm(const float* __restrict__ e1u, const float* __restrict__ e2u,
                                              const float* __restrict__ e1i, const float* __restrict__ e2i,
                                              float* __restrict__ sumexp) {
  int side = blockIdx.z;
  const float* A = side ? e1i : e1u;
  const float* Bm = side ? e2i : e2u;
  __shared__ float sA[16 * 65], sB[16 * 65];
  int bb = blockIdx.y, kk = blockIdx.x;
  for (int idx = threadIdx.x; idx < 1024; idx += 256) {
    int rr = idx >> 6, cc = idx & 63;
    sA[rr * 65 + cc] = A[(((long long)bb * 16 + rr) << 6) + cc];
    sB[rr * 65 + cc] = Bm[(((long long)kk * 16 + rr) << 6) + cc];
  }
  __syncthreads();
  int tx = threadIdx.x & 15, ty = threadIdx.x >> 4;
  float acc = 0.0f;
  for (int d = 0; d < 64; d++) acc += sA[ty * 65 + d] * sB[tx * 65 + d];
  float val = expf(2.0f * acc);
  for (int m = 8; m; m >>= 1) val += __shfl_down(val, m, 16);
  if (tx == 0)
    __hip_atomic_fetch_add(&sumexp[side * BB + bb * 16 + ty], val,
                           __ATOMIC_RELAXED, __HIP_MEMORY_SCOPE_AGENT);
}

__global__ void k_loss(const float* __restrict__ sumexp, const float* __restrict__ pos,
                       float* __restrict__ out) {
  float s = 0.0f;
  for (int i = threadIdx.x; i < 2 * BB; i += 256) s += logf(sumexp[i]) - pos[i];
  for (int m = 32; m; m >>= 1) s += __shfl_xor(s, m);
  __shared__ float r[4];
  if ((threadIdx.x & 63) == 0) r[threadIdx.x >> 6] = s;
  __syncthreads();
  if (threadIdx.x == 0) out[3 * BB * DD] = (r[0] + r[1] + r[2] + r[3]) * (1.0f / (float)BB);
}

// ---------------- launch ----------------
extern "C" void kernel_launch(void* const* d_in, const int* in_sizes, int n_in,
                              void* d_out, int out_size, void* d_ws, size_t ws_size,
                              hipStream_t stream) {
  const float* uf  = (const float*)d_in[0];
  const float* itf = (const float*)d_in[1];
  const float* UIu = (const float*)d_in[2];
  const float* UIi = (const float*)d_in[3];
  const float* W1u = (const float*)d_in[4];
  const float* b1u = (const float*)d_in[5];
  const float* w2u = (const float*)d_in[6];
  const float* W1i = (const float*)d_in[7];
  const float* b1i = (const float*)d_in[8];
  const float* w2i = (const float*)d_in[9];
  const int* ui_src   = (const int*)d_in[10];
  const int* ui_dst   = (const int*)d_in[11];
  const int* mpu      = (const int*)d_in[12];
  const int* mpi      = (const int*)d_in[13];
  const int* user_idx = (const int*)d_in[14];
  const int* item_idx = (const int*)d_in[15];
  const int* neg_idx  = (const int*)d_in[16];
  float* out = (float*)d_out;

  float* wf = (float*)d_ws;
  int*   wi = (int*)d_ws;

  int*   cnt      = wi + O_CNT;
  int*   outcnt   = wi + O_OUTCNT;
  int*   cursor   = wi + O_CURSOR;
  float* partials = wf + O_PARTIALS;
  float* sumexp   = wf + O_SUMEXP;
  float* pos      = wf + O_POS;
  int*   off      = wi + O_OFF;
  int*   bsum     = wi + O_BSUM;
  float* dinv     = wf + O_DINV;
  float* oinv     = wf + O_OINV;
  float* iinv     = wf + O_IINV;
  int*   adj      = wi + O_ADJ;
  float* wsum     = wf + O_WSUM;
  float* emba     = wf + O_EMBA;
  float* total    = wf + O_TOTAL;
  float* embb     = wf + O_EMBB;
  float* e1u      = wf + O_E1U;
  float* e2u      = wf + O_E2U;
  float* e1i      = wf + O_E1I;
  float* e2i      = wf + O_E2I;

  hipMemsetAsync(d_ws, 0, (size_t)ZEND * 4, stream);

  k_hist_main<<<(E_UI + 255) / 256, 256, 0, stream>>>(ui_src, ui_dst, cnt);
  k_hist_mp<<<dim3((E_MP + 255) / 256, 4), 256, 0, stream>>>(mpu, mpi, cnt, outcnt);

  const int NSCAN = 600000;
  const int NB = (NSCAN + 1023) / 1024;
  k_scan1<<<NB, 1024, 0, stream>>>(cnt, off, bsum, NSCAN);
  k_scan2<<<1, 1024, 0, stream>>>(bsum, NB);
  k_scan3<<<NB, 1024, 0, stream>>>(off, bsum, NSCAN);

  k_inv<<<(600000 + 255) / 256, 256, 0, stream>>>(cnt, outcnt, dinv, iinv, oinv);

  k_scatter_main<<<(E_UI + 255) / 256, 256, 0, stream>>>(ui_src, ui_dst, off, cursor, adj);
  k_scatter_mp<<<dim3((E_MP + 255) / 256, 4), 256, 0, stream>>>(mpu, mpi, off, cursor, adj);

  k_init<<<(3200000 + 255) / 256, 256, 0, stream>>>((const float4*)uf, (const float4*)itf,
                                                    (float4*)emba);

  k_layer<<<50000, 256, 0, stream>>>(emba, embb, total, adj, off, cnt, dinv, UIu, UIi, 0);
  k_layer<<<50000, 256, 0, stream>>>(embb, emba, total, adj, off, cnt, dinv, UIu, UIi, 1);

  k_mp_score<<<dim3(25000, 4), 256, 0, stream>>>(uf, itf, W1u, b1u, w2u, W1i, b1i, w2i,
                                                 adj, off, cnt, oinv, iinv, partials);
  k_beta<<<4, 256, 0, stream>>>(partials, wsum);

  k_h2out<<<3072, 256, 0, stream>>>(uf, itf, user_idx, item_idx, neg_idx, total, adj, off, cnt,
                                    oinv, iinv, wsum, out, e1u, e2u, e1i, e2i, pos);

  k_gemm<<<dim3(256, 256, 2), 256, 0, stream>>>(e1u, e2u, e1i, e2i, sumexp);
  k_loss<<<1, 256, 0, stream>>>(sumexp, pos, out);
}

// Round 4
// 2249.372 us; speedup vs baseline: 1.7349x; 1.0422x over previous
//
#include <hip/hip_runtime.h>
#include <math.h>

// ---------------- problem constants ----------------
#define NUSERS   100000
#define NITEMS   100000
#define NNODES   200000
#define DD       64
#define NI       128
#define E_UI     1000000
#define E_MP     500000
#define BB       4096
#define NUBLK    1563          // ceil(100000/64)

// ---------------- workspace layout (float/int elements, 4B each) ----------------
#define O_CNT       0LL
#define O_OUTCNT    600000LL
#define O_CURSOR    1000000LL
#define O_PARTIALS  1600000LL   // 4*1563 used; +16384.. hold transposed weights
#define O_UIT_U     (O_PARTIALS + 16384)   // 8192
#define O_UIT_I     (O_PARTIALS + 24576)   // 8192
#define O_W1T_U     (O_PARTIALS + 32768)   // 8192
#define O_W1T_I     (O_PARTIALS + 40960)   // 8192
#define O_SUMEXP    1700000LL
#define O_POS       1708192LL
#define ZEND        1716384LL
#define O_OFF       1716384LL
#define O_BSUM      2316448LL
#define O_DINV      2317472LL
#define O_OINV      2517472LL
#define O_IINV      2917472LL
#define O_ADJ       3317472LL
#define O_WSUM      7317472LL
#define O_EMBA      7317480LL
#define O_TOTAL     20117480LL
#define O_EMBB      32917480LL
#define O_E1U       45717480LL
#define O_E2U       45979624LL
#define O_E1I       46241768LL
#define O_E2I       46503912LL

// ---------------- degree histograms ----------------
__global__ void k_hist_main(const int* __restrict__ src, const int* __restrict__ dst,
                            int* __restrict__ cnt) {
  int e = blockIdx.x * 256 + threadIdx.x;
  if (e < E_UI) {
    atomicAdd(&cnt[src[e]], 1);
    atomicAdd(&cnt[NUSERS + dst[e]], 1);
  }
}

__global__ void k_hist_mp(const int* __restrict__ mpu, const int* __restrict__ mpi,
                          int* __restrict__ cnt, int* __restrict__ outcnt) {
  int e = blockIdx.x * 256 + threadIdx.x;
  int g = blockIdx.y;
  if (e < E_MP) {
    const int* base = (g < 2) ? (mpu + (long long)g * 2 * E_MP)
                              : (mpi + (long long)(g - 2) * 2 * E_MP);
    int s = base[e];
    int d = base[E_MP + e];
    atomicAdd(&outcnt[g * NUSERS + s], 1);
    atomicAdd(&cnt[NNODES + g * NUSERS + d], 1);
  }
}

// ---------------- exclusive scan ----------------
__global__ __launch_bounds__(1024) void k_scan1(const int* __restrict__ in, int* __restrict__ out,
                                                int* __restrict__ bsum, int n) {
  __shared__ int s[1024];
  int i = blockIdx.x * 1024 + threadIdx.x;
  int v = (i < n) ? in[i] : 0;
  s[threadIdx.x] = v;
  __syncthreads();
  for (int off = 1; off < 1024; off <<= 1) {
    int x = (threadIdx.x >= off) ? s[threadIdx.x - off] : 0;
    __syncthreads();
    s[threadIdx.x] += x;
    __syncthreads();
  }
  if (i < n) out[i] = s[threadIdx.x] - v;
  if (threadIdx.x == 1023) bsum[blockIdx.x] = s[1023];
}

__global__ __launch_bounds__(1024) void k_scan2(int* __restrict__ bsum, int nb) {
  __shared__ int s[1024];
  int v = (threadIdx.x < nb) ? bsum[threadIdx.x] : 0;
  s[threadIdx.x] = v;
  __syncthreads();
  for (int off = 1; off < 1024; off <<= 1) {
    int x = (threadIdx.x >= off) ? s[threadIdx.x - off] : 0;
    __syncthreads();
    s[threadIdx.x] += x;
    __syncthreads();
  }
  if (threadIdx.x < nb) bsum[threadIdx.x] = s[threadIdx.x] - v;
}

__global__ __launch_bounds__(1024) void k_scan3(int* __restrict__ out, const int* __restrict__ bsum, int n) {
  int i = blockIdx.x * 1024 + threadIdx.x;
  if (i < n) out[i] += bsum[blockIdx.x];
}

// ---------------- inverse-sqrt degrees ----------------
__global__ void k_inv(const int* __restrict__ cnt, const int* __restrict__ outcnt,
                      float* __restrict__ dinv, float* __restrict__ iinv, float* __restrict__ oinv) {
  int i = blockIdx.x * 256 + threadIdx.x;
  if (i < NNODES) {
    int c = cnt[i]; if (c < 1) c = 1;
    dinv[i] = 1.0f / sqrtf((float)c);
  } else if (i < 600000) {
    int c = cnt[i]; if (c < 1) c = 1;
    iinv[i - NNODES] = 1.0f / sqrtf((float)c);
  }
  if (i < 400000) {
    int c = outcnt[i]; if (c < 1) c = 1;
    oinv[i] = 1.0f / sqrtf((float)c);
  }
}

// ---------------- CSR scatter ----------------
__global__ void k_scatter_main(const int* __restrict__ src, const int* __restrict__ dst,
                               const int* __restrict__ off, int* __restrict__ cursor,
                               int* __restrict__ adj) {
  int e = blockIdx.x * 256 + threadIdx.x;
  if (e < E_UI) {
    int u = src[e];
    int it = NUSERS + dst[e];
    int p = atomicAdd(&cursor[u], 1);
    adj[off[u] + p] = it;
    int q = atomicAdd(&cursor[it], 1);
    adj[off[it] + q] = u;
  }
}

__global__ void k_scatter_mp(const int* __restrict__ mpu, const int* __restrict__ mpi,
                             const int* __restrict__ off, int* __restrict__ cursor,
                             int* __restrict__ adj) {
  int e = blockIdx.x * 256 + threadIdx.x;
  int g = blockIdx.y;
  if (e < E_MP) {
    const int* base = (g < 2) ? (mpu + (long long)g * 2 * E_MP)
                              : (mpi + (long long)(g - 2) * 2 * E_MP);
    int s = base[e];
    int d = base[E_MP + e];
    int node = NNODES + g * NUSERS + d;
    int p = atomicAdd(&cursor[node], 1);
    adj[off[node] + p] = s;
  }
}

// ---------------- emb init ----------------
__global__ void k_init(const float4* __restrict__ uf, const float4* __restrict__ itf,
                       float4* __restrict__ emb) {
  int i = blockIdx.x * 256 + threadIdx.x;
  if (i < 3200000) {
    emb[i] = (i < 1600000) ? uf[i] : itf[i - 1600000];
  }
}

// ---------------- weight transpose prep: WT[j*64+d] = W[d*128+j] ----------------
__global__ void k_tw(const float* __restrict__ UIu, const float* __restrict__ UIi,
                     const float* __restrict__ W1u, const float* __restrict__ W1i,
                     float* __restrict__ UITu, float* __restrict__ UITi,
                     float* __restrict__ W1Tu, float* __restrict__ W1Ti) {
  int t = blockIdx.x * 256 + threadIdx.x;
  if (t < 8192) {
    int d = t >> 7, j = t & 127;
    UITu[j * 64 + d] = UIu[t];
    UITi[j * 64 + d] = UIi[t];
    W1Tu[j * 64 + d] = W1u[t];
    W1Ti[j * 64 + d] = W1i[t];
  }
}

// ---------------- masked-unroll-8 gather (dim = lane) ----------------
__device__ __forceinline__ float gather_rows(const float* __restrict__ tbl,
                                             const int* __restrict__ adj,
                                             int start, int c,
                                             const float* __restrict__ warr, int wofs,
                                             int lane) {
  float acc = 0.0f;
  for (int kb = 0; kb < c; kb += 64) {
    int rem = c - kb; if (rem > 64) rem = 64;
    int mi = 0; float mw = 0.0f;
    if (lane < rem) { mi = adj[start + kb + lane]; mw = warr[wofs + mi]; }
    for (int k = 0; k < rem; k += 8) {
      int n0=__shfl(mi,k+0),n1=__shfl(mi,k+1),n2=__shfl(mi,k+2),n3=__shfl(mi,k+3);
      int n4=__shfl(mi,k+4),n5=__shfl(mi,k+5),n6=__shfl(mi,k+6),n7=__shfl(mi,k+7);
      float w0=__shfl(mw,k+0),w1=__shfl(mw,k+1),w2=__shfl(mw,k+2),w3=__shfl(mw,k+3);
      float w4=__shfl(mw,k+4),w5=__shfl(mw,k+5),w6=__shfl(mw,k+6),w7=__shfl(mw,k+7);
      float v0=tbl[((long long)n0<<6)+lane], v1=tbl[((long long)n1<<6)+lane];
      float v2=tbl[((long long)n2<<6)+lane], v3=tbl[((long long)n3<<6)+lane];
      float v4=tbl[((long long)n4<<6)+lane], v5=tbl[((long long)n5<<6)+lane];
      float v6=tbl[((long long)n6<<6)+lane], v7=tbl[((long long)n7<<6)+lane];
      acc += w0*v0; acc += w1*v1; acc += w2*v2; acc += w3*v3;
      acc += w4*v4; acc += w5*v5; acc += w6*v6; acc += w7*v7;
    }
  }
  return acc;
}

// ---------------- fused GNN layer, node=lane matmul, scalar-pipe weights ----------------
// One wave (block=64) handles 64 nodes: gather (dim=lane) -> LDS transpose ->
// per-lane intent attention with SGPR weight rows -> transpose back -> store.
__global__ __launch_bounds__(64) void k_layer(
    const float* __restrict__ ecur, float* __restrict__ enext, float* __restrict__ total,
    const int* __restrict__ adj, const int* __restrict__ off, const int* __restrict__ cnt,
    const float* __restrict__ dinv,
    const float* __restrict__ UITu, const float* __restrict__ UITi, int layer) {
  __shared__ float sZ[64 * 65];   // odd stride: conflict-free both directions
  int lane = threadIdx.x;
  int bx = blockIdx.x;
  int nb0, lim;
  const float* UIT;
  if (bx < NUBLK) { nb0 = bx << 6; lim = NUSERS; UIT = UITu; }
  else            { nb0 = NUSERS + ((bx - NUBLK) << 6); lim = NNODES; UIT = UITi; }
  int mmax = lim - nb0; if (mmax > 64) mmax = 64;

  // ---- gather phase: wave cooperates on one node at a time ----
  for (int m = 0; m < mmax; m++) {
    int node = nb0 + m;
    long long base = ((long long)node << 6) + lane;
    float vv = ecur[base];
    float acc = gather_rows(ecur, adj, off[node], cnt[node], dinv, 0, lane);
    enext[base] = dinv[node] * acc;     // stash gnn (re-read in store phase)
    sZ[m * 65 + lane] = vv;
  }
  // single wave: no barrier needed (compiler orders LDS ops via lgkmcnt)

  // ---- matmul phase: lane = node ----
  float v[64];
#pragma unroll
  for (int d = 0; d < 64; d++) v[d] = sZ[lane * 65 + d];
  float o[64];
#pragma unroll
  for (int d = 0; d < 64; d++) o[d] = 0.0f;
  float den = 0.0f;
  for (int j = 0; j < 128; j++) {
    const float* wr = &UIT[j * 64];   // wave-uniform -> s_load
    float s = 0.0f;
#pragma unroll
    for (int d = 0; d < 64; d++) s += v[d] * wr[d];
    float e = __expf(s);              // |s| << 1: no max-subtraction needed
    den += e;
#pragma unroll
    for (int d = 0; d < 64; d++) o[d] += e * wr[d];
  }
  float rden = 1.0f / den;
  // transpose intent output back to dim=lane (overwrite sZ)
#pragma unroll
  for (int d = 0; d < 64; d++) sZ[lane * 65 + d] = o[d] * rden;

  // ---- store phase: dim = lane, coalesced ----
  for (int m = 0; m < mmax; m++) {
    int node = nb0 + m;
    long long base = ((long long)node << 6) + lane;
    float ov = sZ[m * 65 + lane];
    float vv = ecur[base];
    float gn = enext[base];
    float ne = gn + ov + vv;
    enext[base] = ne;
    total[base] = (layer == 0) ? (vv + ne) : (total[base] + ne);
  }
}

// ---------------- metapath graphconv + semantic-att score, node=lane ----------------
__global__ __launch_bounds__(64) void k_mp_score(
    const float* __restrict__ uf, const float* __restrict__ itf,
    const float* __restrict__ W1Tu, const float* __restrict__ b1u, const float* __restrict__ w2u,
    const float* __restrict__ W1Ti, const float* __restrict__ b1i, const float* __restrict__ w2i,
    const int* __restrict__ adj, const int* __restrict__ off, const int* __restrict__ cnt,
    const float* __restrict__ oinv, const float* __restrict__ iinv, float* __restrict__ partials) {
  __shared__ float sZ[64 * 65];
  int lane = threadIdx.x;
  int g = blockIdx.y;
  const float* feat = (g < 2) ? uf : itf;
  const float* W1T  = (g < 2) ? W1Tu : W1Ti;
  const float* b1   = (g < 2) ? b1u : b1i;
  const float* w2   = (g < 2) ? w2u : w2i;
  int gofs = g * NUSERS;
  int nb0 = blockIdx.x << 6;
  int mmax = NUSERS - nb0; if (mmax > 64) mmax = 64;

  for (int m = 0; m < mmax; m++) {
    int n = nb0 + m;
    int node = NNODES + gofs + n;
    float z = gather_rows(feat, adj, off[node], cnt[node], oinv, gofs, lane);
    sZ[m * 65 + lane] = z * iinv[gofs + n];
  }

  float z[64];
#pragma unroll
  for (int d = 0; d < 64; d++) z[d] = sZ[lane * 65 + d];
  float p = 0.0f;
  for (int j = 0; j < 128; j++) {
    const float* wr = &W1T[j * 64];
    float s = b1[j];
#pragma unroll
    for (int d = 0; d < 64; d++) s += z[d] * wr[d];
    // tanh via fast exp: tanh(x) = 1 - 2/(e^{2x}+1)
    float t = 1.0f - 2.0f / (__expf(2.0f * s) + 1.0f);
    p += t * w2[j];
  }
  if (lane >= mmax) p = 0.0f;
  for (int m = 32; m; m >>= 1) p += __shfl_xor(p, m);
  if (lane == 0) partials[g * NUBLK + blockIdx.x] = p;
}

__global__ void k_beta(const float* __restrict__ partials, float* __restrict__ wsum) {
  int g = blockIdx.x;
  float s = 0.0f;
  for (int i = threadIdx.x; i < NUBLK; i += 256) s += partials[g * NUBLK + i];
  for (int m = 32; m; m >>= 1) s += __shfl_xor(s, m);
  __shared__ float r[4];
  if ((threadIdx.x & 63) == 0) r[threadIdx.x >> 6] = s;
  __syncthreads();
  if (threadIdx.x == 0) wsum[g] = r[0] + r[1] + r[2] + r[3];
}

// ---------------- gather outputs + ssl embedding prep ----------------
__global__ __launch_bounds__(256) void k_h2out(
    const float* __restrict__ uf, const float* __restrict__ itf,
    const int* __restrict__ user_idx, const int* __restrict__ item_idx, const int* __restrict__ neg_idx,
    const float* __restrict__ total, const int* __restrict__ adj, const int* __restrict__ off,
    const int* __restrict__ cnt, const float* __restrict__ oinv, const float* __restrict__ iinv,
    const float* __restrict__ wsum, float* __restrict__ out,
    float* __restrict__ e1u, float* __restrict__ e2u,
    float* __restrict__ e1i, float* __restrict__ e2i, float* __restrict__ pos) {
  int lane = threadIdx.x & 63;
  int row = (blockIdx.x << 2) + (threadIdx.x >> 6);
  int seg = row >> 12;
  int r = row & 4095;
  int idx;
  const float* feat;
  int gbase;
  if (seg == 0)      { idx = user_idx[r]; feat = uf;  gbase = 0; }
  else if (seg == 1) { idx = item_idx[r]; feat = itf; gbase = 2; }
  else               { idx = neg_idx[r];  feat = itf; gbase = 2; }
  int tnode = gbase ? (NUSERS + idx) : idx;
  float t = total[((long long)tnode << 6) + lane];
  float w0 = wsum[gbase] * (1.0f / 100000.0f);
  float w1 = wsum[gbase + 1] * (1.0f / 100000.0f);
  float mb = fmaxf(w0, w1);
  float b0 = expf(w0 - mb), b1 = expf(w1 - mb);
  float bs = b0 + b1;
  b0 /= bs; b1 /= bs;
  float h2 = 0.0f;
  for (int m = 0; m < 2; m++) {
    int g = gbase + m;
    int gofs = g * NUSERS;
    int node = NNODES + g * NUSERS + idx;
    float z = gather_rows(feat, adj, off[node], cnt[node], oinv, gofs, lane);
    z *= iinv[gofs + idx];
    h2 += (m ? b1 : b0) * z;
  }
  out[((long long)row << 6) + lane] = 0.5f * t + 0.5f * h2;
  if (seg < 2) {
    float n1 = h2 * h2, n2 = t * t;
    for (int m = 32; m; m >>= 1) { n1 += __shfl_xor(n1, m); n2 += __shfl_xor(n2, m); }
    n1 = sqrtf(n1); n2 = sqrtf(n2);
    float a = h2 / n1, b = t / n2;
    float d = a * b;
    for (int m = 32; m; m >>= 1) d += __shfl_xor(d, m);
    float* e1 = seg ? e1i : e1u;
    float* e2 = seg ? e2i : e2u;
    e1[((long long)r << 6) + lane] = a;
    e2[((long long)r << 6) + lane] = b;
    if (lane == 0) pos[seg * BB + r] = 2.0f * d;
  }
}

// ---------------- ssl similarity matrix ----------------
__global__ __launch_bounds__(256) void k_gemm(const float* __restrict__ e1u, const float* __restrict__ e2u,
                                              const float* __restrict__ e1i, const float* __restrict__ e2i,
                                              float* __restrict__ sumexp) {
  int side = blockIdx.z;
  const float* A = side ? e1i : e1u;
  const float* Bm = side ? e2i : e2u;
  __shared__ float sA[16 * 65], sB[16 * 65];
  int bb = blockIdx.y, kk = blockIdx.x;
  for (int idx = threadIdx.x; idx < 1024; idx += 256) {
    int rr = idx >> 6, cc = idx & 63;
    sA[rr * 65 + cc] = A[(((long long)bb * 16 + rr) << 6) + cc];
    sB[rr * 65 + cc] = Bm[(((long long)kk * 16 + rr) << 6) + cc];
  }
  __syncthreads();
  int tx = threadIdx.x & 15, ty = threadIdx.x >> 4;
  float acc = 0.0f;
  for (int d = 0; d < 64; d++) acc += sA[ty * 65 + d] * sB[tx * 65 + d];
  float val = expf(2.0f * acc);
  for (int m = 8; m; m >>= 1) val += __shfl_down(val, m, 16);
  if (tx == 0)
    __hip_atomic_fetch_add(&sumexp[side * BB + bb * 16 + ty], val,
                           __ATOMIC_RELAXED, __HIP_MEMORY_SCOPE_AGENT);
}

__global__ void k_loss(const float* __restrict__ sumexp, const float* __restrict__ pos,
                       float* __restrict__ out) {
  float s = 0.0f;
  for (int i = threadIdx.x; i < 2 * BB; i += 256) s += logf(sumexp[i]) - pos[i];
  for (int m = 32; m; m >>= 1) s += __shfl_xor(s, m);
  __shared__ float r[4];
  if ((threadIdx.x & 63) == 0) r[threadIdx.x >> 6] = s;
  __syncthreads();
  if (threadIdx.x == 0) out[3 * BB * DD] = (r[0] + r[1] + r[2] + r[3]) * (1.0f / (float)BB);
}

// ---------------- launch ----------------
extern "C" void kernel_launch(void* const* d_in, const int* in_sizes, int n_in,
                              void* d_out, int out_size, void* d_ws, size_t ws_size,
                              hipStream_t stream) {
  const float* uf  = (const float*)d_in[0];
  const float* itf = (const float*)d_in[1];
  const float* UIu = (const float*)d_in[2];
  const float* UIi = (const float*)d_in[3];
  const float* W1u = (const float*)d_in[4];
  const float* b1u = (const float*)d_in[5];
  const float* w2u = (const float*)d_in[6];
  const float* W1i = (const float*)d_in[7];
  const float* b1i = (const float*)d_in[8];
  const float* w2i = (const float*)d_in[9];
  const int* ui_src   = (const int*)d_in[10];
  const int* ui_dst   = (const int*)d_in[11];
  const int* mpu      = (const int*)d_in[12];
  const int* mpi      = (const int*)d_in[13];
  const int* user_idx = (const int*)d_in[14];
  const int* item_idx = (const int*)d_in[15];
  const int* neg_idx  = (const int*)d_in[16];
  float* out = (float*)d_out;

  float* wf = (float*)d_ws;
  int*   wi = (int*)d_ws;

  int*   cnt      = wi + O_CNT;
  int*   outcnt   = wi + O_OUTCNT;
  int*   cursor   = wi + O_CURSOR;
  float* partials = wf + O_PARTIALS;
  float* UITu     = wf + O_UIT_U;
  float* UITi     = wf + O_UIT_I;
  float* W1Tu     = wf + O_W1T_U;
  float* W1Ti     = wf + O_W1T_I;
  float* sumexp   = wf + O_SUMEXP;
  float* pos      = wf + O_POS;
  int*   off      = wi + O_OFF;
  int*   bsum     = wi + O_BSUM;
  float* dinv     = wf + O_DINV;
  float* oinv     = wf + O_OINV;
  float* iinv     = wf + O_IINV;
  int*   adj      = wi + O_ADJ;
  float* wsum     = wf + O_WSUM;
  float* emba     = wf + O_EMBA;
  float* total    = wf + O_TOTAL;
  float* embb     = wf + O_EMBB;
  float* e1u      = wf + O_E1U;
  float* e2u      = wf + O_E2U;
  float* e1i      = wf + O_E1I;
  float* e2i      = wf + O_E2I;

  hipMemsetAsync(d_ws, 0, (size_t)ZEND * 4, stream);

  k_hist_main<<<(E_UI + 255) / 256, 256, 0, stream>>>(ui_src, ui_dst, cnt);
  k_hist_mp<<<dim3((E_MP + 255) / 256, 4), 256, 0, stream>>>(mpu, mpi, cnt, outcnt);

  const int NSCAN = 600000;
  const int NB = (NSCAN + 1023) / 1024;
  k_scan1<<<NB, 1024, 0, stream>>>(cnt, off, bsum, NSCAN);
  k_scan2<<<1, 1024, 0, stream>>>(bsum, NB);
  k_scan3<<<NB, 1024, 0, stream>>>(off, bsum, NSCAN);

  k_inv<<<(600000 + 255) / 256, 256, 0, stream>>>(cnt, outcnt, dinv, iinv, oinv);

  k_scatter_main<<<(E_UI + 255) / 256, 256, 0, stream>>>(ui_src, ui_dst, off, cursor, adj);
  k_scatter_mp<<<dim3((E_MP + 255) / 256, 4), 256, 0, stream>>>(mpu, mpi, off, cursor, adj);

  k_init<<<(3200000 + 255) / 256, 256, 0, stream>>>((const float4*)uf, (const float4*)itf,
                                                    (float4*)emba);
  k_tw<<<32, 256, 0, stream>>>(UIu, UIi, W1u, W1i, UITu, UITi, W1Tu, W1Ti);

  // fused layers: 2*NUBLK blocks of one wave / 64 nodes each
  k_layer<<<2 * NUBLK, 64, 0, stream>>>(emba, embb, total, adj, off, cnt, dinv, UITu, UITi, 0);
  k_layer<<<2 * NUBLK, 64, 0, stream>>>(embb, emba, total, adj, off, cnt, dinv, UITu, UITi, 1);

  k_mp_score<<<dim3(NUBLK, 4), 64, 0, stream>>>(uf, itf, W1Tu, b1u, w2u, W1Ti, b1i, w2i,
                                                adj, off, cnt, oinv, iinv, partials);
  k_beta<<<4, 256, 0, stream>>>(partials, wsum);

  k_h2out<<<3072, 256, 0, stream>>>(uf, itf, user_idx, item_idx, neg_idx, total, adj, off, cnt,
                                    oinv, iinv, wsum, out, e1u, e2u, e1i, e2i, pos);

  k_gemm<<<dim3(256, 256, 2), 256, 0, stream>>>(e1u, e2u, e1i, e2i, sumexp);
  k_loss<<<1, 256, 0, stream>>>(sumexp, pos, out);
}

// Round 5
// 2248.098 us; speedup vs baseline: 1.7359x; 1.0006x over previous
//
#include <hip/hip_runtime.h>
#include <math.h>

// ---------------- problem constants ----------------
#define NUSERS   100000
#define NITEMS   100000
#define NNODES   200000
#define DD       64
#define NI       128
#define E_UI     1000000
#define E_MP     500000
#define BB       4096
#define NUBLK    1563          // ceil(100000/64)

// ---------------- workspace layout (float/int elements, 4B each) ----------------
#define O_CNT       0LL
#define O_OUTCNT    600000LL
#define O_CURSOR    1000000LL
#define O_PARTIALS  1600000LL   // 4*1563 used; +16384.. hold transposed weights
#define O_UIT_U     (O_PARTIALS + 16384)   // 8192
#define O_UIT_I     (O_PARTIALS + 24576)   // 8192
#define O_W1T_U     (O_PARTIALS + 32768)   // 8192
#define O_W1T_I     (O_PARTIALS + 40960)   // 8192
#define O_SUMEXP    1700000LL
#define O_POS       1708192LL
#define ZEND        1716384LL
#define O_OFF       1716384LL
#define O_BSUM      2316448LL
#define O_DINV      2317472LL
#define O_OINV      2517472LL
#define O_IINV      2917472LL
#define O_ADJ       3317472LL
#define O_WSUM      7317472LL
#define O_EMBA      7317480LL
#define O_TOTAL     20117480LL
#define O_EMBB      32917480LL
#define O_E1U       45717480LL
#define O_E2U       45979624LL
#define O_E1I       46241768LL
#define O_E2I       46503912LL

// ---------------- degree histograms ----------------
__global__ void k_hist_main(const int* __restrict__ src, const int* __restrict__ dst,
                            int* __restrict__ cnt) {
  int e = blockIdx.x * 256 + threadIdx.x;
  if (e < E_UI) {
    atomicAdd(&cnt[src[e]], 1);
    atomicAdd(&cnt[NUSERS + dst[e]], 1);
  }
}

__global__ void k_hist_mp(const int* __restrict__ mpu, const int* __restrict__ mpi,
                          int* __restrict__ cnt, int* __restrict__ outcnt) {
  int e = blockIdx.x * 256 + threadIdx.x;
  int g = blockIdx.y;
  if (e < E_MP) {
    const int* base = (g < 2) ? (mpu + (long long)g * 2 * E_MP)
                              : (mpi + (long long)(g - 2) * 2 * E_MP);
    int s = base[e];
    int d = base[E_MP + e];
    atomicAdd(&outcnt[g * NUSERS + s], 1);
    atomicAdd(&cnt[NNODES + g * NUSERS + d], 1);
  }
}

// ---------------- exclusive scan ----------------
__global__ __launch_bounds__(1024) void k_scan1(const int* __restrict__ in, int* __restrict__ out,
                                                int* __restrict__ bsum, int n) {
  __shared__ int s[1024];
  int i = blockIdx.x * 1024 + threadIdx.x;
  int v = (i < n) ? in[i] : 0;
  s[threadIdx.x] = v;
  __syncthreads();
  for (int off = 1; off < 1024; off <<= 1) {
    int x = (threadIdx.x >= off) ? s[threadIdx.x - off] : 0;
    __syncthreads();
    s[threadIdx.x] += x;
    __syncthreads();
  }
  if (i < n) out[i] = s[threadIdx.x] - v;
  if (threadIdx.x == 1023) bsum[blockIdx.x] = s[1023];
}

__global__ __launch_bounds__(1024) void k_scan2(int* __restrict__ bsum, int nb) {
  __shared__ int s[1024];
  int v = (threadIdx.x < nb) ? bsum[threadIdx.x] : 0;
  s[threadIdx.x] = v;
  __syncthreads();
  for (int off = 1; off < 1024; off <<= 1) {
    int x = (threadIdx.x >= off) ? s[threadIdx.x - off] : 0;
    __syncthreads();
    s[threadIdx.x] += x;
    __syncthreads();
  }
  if (threadIdx.x < nb) bsum[threadIdx.x] = s[threadIdx.x] - v;
}

__global__ __launch_bounds__(1024) void k_scan3(int* __restrict__ out, const int* __restrict__ bsum, int n) {
  int i = blockIdx.x * 1024 + threadIdx.x;
  if (i < n) out[i] += bsum[blockIdx.x];
}

// ---------------- inverse-sqrt degrees ----------------
__global__ void k_inv(const int* __restrict__ cnt, const int* __restrict__ outcnt,
                      float* __restrict__ dinv, float* __restrict__ iinv, float* __restrict__ oinv) {
  int i = blockIdx.x * 256 + threadIdx.x;
  if (i < NNODES) {
    int c = cnt[i]; if (c < 1) c = 1;
    dinv[i] = 1.0f / sqrtf((float)c);
  } else if (i < 600000) {
    int c = cnt[i]; if (c < 1) c = 1;
    iinv[i - NNODES] = 1.0f / sqrtf((float)c);
  }
  if (i < 400000) {
    int c = outcnt[i]; if (c < 1) c = 1;
    oinv[i] = 1.0f / sqrtf((float)c);
  }
}

// ---------------- CSR scatter ----------------
__global__ void k_scatter_main(const int* __restrict__ src, const int* __restrict__ dst,
                               const int* __restrict__ off, int* __restrict__ cursor,
                               int* __restrict__ adj) {
  int e = blockIdx.x * 256 + threadIdx.x;
  if (e < E_UI) {
    int u = src[e];
    int it = NUSERS + dst[e];
    int p = atomicAdd(&cursor[u], 1);
    adj[off[u] + p] = it;
    int q = atomicAdd(&cursor[it], 1);
    adj[off[it] + q] = u;
  }
}

__global__ void k_scatter_mp(const int* __restrict__ mpu, const int* __restrict__ mpi,
                             const int* __restrict__ off, int* __restrict__ cursor,
                             int* __restrict__ adj) {
  int e = blockIdx.x * 256 + threadIdx.x;
  int g = blockIdx.y;
  if (e < E_MP) {
    const int* base = (g < 2) ? (mpu + (long long)g * 2 * E_MP)
                              : (mpi + (long long)(g - 2) * 2 * E_MP);
    int s = base[e];
    int d = base[E_MP + e];
    int node = NNODES + g * NUSERS + d;
    int p = atomicAdd(&cursor[node], 1);
    adj[off[node] + p] = s;
  }
}

// ---------------- emb init ----------------
__global__ void k_init(const float4* __restrict__ uf, const float4* __restrict__ itf,
                       float4* __restrict__ emb) {
  int i = blockIdx.x * 256 + threadIdx.x;
  if (i < 3200000) {
    emb[i] = (i < 1600000) ? uf[i] : itf[i - 1600000];
  }
}

// ---------------- weight transpose prep: WT[j*64+d] = W[d*128+j] ----------------
__global__ void k_tw(const float* __restrict__ UIu, const float* __restrict__ UIi,
                     const float* __restrict__ W1u, const float* __restrict__ W1i,
                     float* __restrict__ UITu, float* __restrict__ UITi,
                     float* __restrict__ W1Tu, float* __restrict__ W1Ti) {
  int t = blockIdx.x * 256 + threadIdx.x;
  if (t < 8192) {
    int d = t >> 7, j = t & 127;
    UITu[j * 64 + d] = UIu[t];
    UITi[j * 64 + d] = UIi[t];
    W1Tu[j * 64 + d] = W1u[t];
    W1Ti[j * 64 + d] = W1i[t];
  }
}

// ---------------- masked-unroll-8 gather (dim = lane) ----------------
__device__ __forceinline__ float gather_rows(const float* __restrict__ tbl,
                                             const int* __restrict__ adj,
                                             int start, int c,
                                             const float* __restrict__ warr, int wofs,
                                             int lane) {
  float acc = 0.0f;
  for (int kb = 0; kb < c; kb += 64) {
    int rem = c - kb; if (rem > 64) rem = 64;
    int mi = 0; float mw = 0.0f;
    if (lane < rem) { mi = adj[start + kb + lane]; mw = warr[wofs + mi]; }
    for (int k = 0; k < rem; k += 8) {
      int n0=__shfl(mi,k+0),n1=__shfl(mi,k+1),n2=__shfl(mi,k+2),n3=__shfl(mi,k+3);
      int n4=__shfl(mi,k+4),n5=__shfl(mi,k+5),n6=__shfl(mi,k+6),n7=__shfl(mi,k+7);
      float w0=__shfl(mw,k+0),w1=__shfl(mw,k+1),w2=__shfl(mw,k+2),w3=__shfl(mw,k+3);
      float w4=__shfl(mw,k+4),w5=__shfl(mw,k+5),w6=__shfl(mw,k+6),w7=__shfl(mw,k+7);
      float v0=tbl[((long long)n0<<6)+lane], v1=tbl[((long long)n1<<6)+lane];
      float v2=tbl[((long long)n2<<6)+lane], v3=tbl[((long long)n3<<6)+lane];
      float v4=tbl[((long long)n4<<6)+lane], v5=tbl[((long long)n5<<6)+lane];
      float v6=tbl[((long long)n6<<6)+lane], v7=tbl[((long long)n7<<6)+lane];
      acc += w0*v0; acc += w1*v1; acc += w2*v2; acc += w3*v3;
      acc += w4*v4; acc += w5*v5; acc += w6*v6; acc += w7*v7;
    }
  }
  return acc;
}

// ---------------- spmm: wave per row, gnn stashed into enext ----------------
__global__ __launch_bounds__(256) void k_spmm(
    const float* __restrict__ ecur, float* __restrict__ gnn,
    const int* __restrict__ adj, const int* __restrict__ off,
    const int* __restrict__ cnt, const float* __restrict__ dinv) {
  int row = (blockIdx.x << 2) + (threadIdx.x >> 6);
  int lane = threadIdx.x & 63;
  float acc = gather_rows(ecur, adj, off[row], cnt[row], dinv, 0, lane);
  gnn[((long long)row << 6) + lane] = dinv[row] * acc;
}

// ---------------- intent attention, node=lane, register-resident ----------------
// enext holds gnn on entry; exits holding new emb. total updated.
__global__ __launch_bounds__(128, 2) void k_attn(
    const float* __restrict__ ecur, float* __restrict__ enext, float* __restrict__ total,
    const float* __restrict__ UITu, const float* __restrict__ UITi, int layer) {
  __shared__ float sZ[2][64 * 68];   // stride 68: float4-aligned, structurally clean b128
  int lane = threadIdx.x & 63, w = threadIdx.x >> 6;
  int bx = blockIdx.x;
  int nb0, lim; const float* UIT;
  if (bx < 782) { nb0 = bx * 128 + w * 64; lim = NUSERS; UIT = UITu; }
  else          { nb0 = NUSERS + (bx - 782) * 128 + w * 64; lim = NNODES; UIT = UITi; }
  int mmax = lim - nb0; if (mmax > 64) mmax = 64;
  if (mmax <= 0) return;
  float* tz = sZ[w];

  // phase A: coalesced load of 64 node rows -> LDS transpose tile
  for (int m = 0; m < mmax; m++)
    tz[m * 68 + lane] = ecur[(((long long)(nb0 + m)) << 6) + lane];

  // phase B: lane = node; v,o forced into registers (float4 arrays, full unroll)
  float4 v4[16], o4[16];
#pragma unroll
  for (int q = 0; q < 16; q++) {
    v4[q] = *(const float4*)&tz[lane * 68 + q * 4];
    o4[q] = make_float4(0.f, 0.f, 0.f, 0.f);
  }
  float den = 0.0f;
  for (int j = 0; j < 128; j++) {
    const float4* wr = (const float4*)&UIT[j * 64];   // wave-uniform -> SGPR row
    float s = 0.0f;
#pragma unroll
    for (int q = 0; q < 16; q++) {
      float4 wq = wr[q];
      s += v4[q].x * wq.x + v4[q].y * wq.y + v4[q].z * wq.z + v4[q].w * wq.w;
    }
    float e = __expf(s);     // |s| << 1: no max-subtraction needed
    den += e;
#pragma unroll
    for (int q = 0; q < 16; q++) {
      float4 wq = wr[q];
      o4[q].x += e * wq.x; o4[q].y += e * wq.y;
      o4[q].z += e * wq.z; o4[q].w += e * wq.w;
    }
  }
  float rden = 1.0f / den;
#pragma unroll
  for (int q = 0; q < 16; q++) {
    float4 ov = o4[q];
    *(float4*)&tz[lane * 68 + q * 4] =
        make_float4(ov.x * rden, ov.y * rden, ov.z * rden, ov.w * rden);
  }

  // phase C: dim = lane, coalesced combine + store
#pragma unroll 4
  for (int m = 0; m < mmax; m++) {
    long long base = (((long long)(nb0 + m)) << 6) + lane;
    float ov = tz[m * 68 + lane];
    float vv = ecur[base];
    float gn = enext[base];
    float ne = gn + ov + vv;
    enext[base] = ne;
    total[base] = (layer == 0) ? (vv + ne) : (total[base] + ne);
  }
}

// ---------------- metapath graphconv + semantic-att score, node=lane ----------------
__global__ __launch_bounds__(64) void k_mp_score(
    const float* __restrict__ uf, const float* __restrict__ itf,
    const float* __restrict__ W1Tu, const float* __restrict__ b1u, const float* __restrict__ w2u,
    const float* __restrict__ W1Ti, const float* __restrict__ b1i, const float* __restrict__ w2i,
    const int* __restrict__ adj, const int* __restrict__ off, const int* __restrict__ cnt,
    const float* __restrict__ oinv, const float* __restrict__ iinv, float* __restrict__ partials) {
  __shared__ float sZ[64 * 65];
  int lane = threadIdx.x;
  int g = blockIdx.y;
  const float* feat = (g < 2) ? uf : itf;
  const float* W1T  = (g < 2) ? W1Tu : W1Ti;
  const float* b1   = (g < 2) ? b1u : b1i;
  const float* w2   = (g < 2) ? w2u : w2i;
  int gofs = g * NUSERS;
  int nb0 = blockIdx.x << 6;
  int mmax = NUSERS - nb0; if (mmax > 64) mmax = 64;

  for (int m = 0; m < mmax; m++) {
    int n = nb0 + m;
    int node = NNODES + gofs + n;
    float z = gather_rows(feat, adj, off[node], cnt[node], oinv, gofs, lane);
    sZ[m * 65 + lane] = z * iinv[gofs + n];
  }

  float z[64];
#pragma unroll
  for (int d = 0; d < 64; d++) z[d] = sZ[lane * 65 + d];
  float p = 0.0f;
  for (int j = 0; j < 128; j++) {
    const float* wr = &W1T[j * 64];
    float s = b1[j];
#pragma unroll
    for (int d = 0; d < 64; d++) s += z[d] * wr[d];
    float t = 1.0f - 2.0f / (__expf(2.0f * s) + 1.0f);
    p += t * w2[j];
  }
  if (lane >= mmax) p = 0.0f;
  for (int m = 32; m; m >>= 1) p += __shfl_xor(p, m);
  if (lane == 0) partials[g * NUBLK + blockIdx.x] = p;
}

__global__ void k_beta(const float* __restrict__ partials, float* __restrict__ wsum) {
  int g = blockIdx.x;
  float s = 0.0f;
  for (int i = threadIdx.x; i < NUBLK; i += 256) s += partials[g * NUBLK + i];
  for (int m = 32; m; m >>= 1) s += __shfl_xor(s, m);
  __shared__ float r[4];
  if ((threadIdx.x & 63) == 0) r[threadIdx.x >> 6] = s;
  __syncthreads();
  if (threadIdx.x == 0) wsum[g] = r[0] + r[1] + r[2] + r[3];
}

// ---------------- gather outputs + ssl embedding prep ----------------
__global__ __launch_bounds__(256) void k_h2out(
    const float* __restrict__ uf, const float* __restrict__ itf,
    const int* __restrict__ user_idx, const int* __restrict__ item_idx, const int* __restrict__ neg_idx,
    const float* __restrict__ total, const int* __restrict__ adj, const int* __restrict__ off,
    const int* __restrict__ cnt, const float* __restrict__ oinv, const float* __restrict__ iinv,
    const float* __restrict__ wsum, float* __restrict__ out,
    float* __restrict__ e1u, float* __restrict__ e2u,
    float* __restrict__ e1i, float* __restrict__ e2i, float* __restrict__ pos) {
  int lane = threadIdx.x & 63;
  int row = (blockIdx.x << 2) + (threadIdx.x >> 6);
  int seg = row >> 12;
  int r = row & 4095;
  int idx;
  const float* feat;
  int gbase;
  if (seg == 0)      { idx = user_idx[r]; feat = uf;  gbase = 0; }
  else if (seg == 1) { idx = item_idx[r]; feat = itf; gbase = 2; }
  else               { idx = neg_idx[r];  feat = itf; gbase = 2; }
  int tnode = gbase ? (NUSERS + idx) : idx;
  float t = total[((long long)tnode << 6) + lane];
  float w0 = wsum[gbase] * (1.0f / 100000.0f);
  float w1 = wsum[gbase + 1] * (1.0f / 100000.0f);
  float mb = fmaxf(w0, w1);
  float b0 = expf(w0 - mb), b1 = expf(w1 - mb);
  float bs = b0 + b1;
  b0 /= bs; b1 /= bs;
  float h2 = 0.0f;
  for (int m = 0; m < 2; m++) {
    int g = gbase + m;
    int gofs = g * NUSERS;
    int node = NNODES + g * NUSERS + idx;
    float z = gather_rows(feat, adj, off[node], cnt[node], oinv, gofs, lane);
    z *= iinv[gofs + idx];
    h2 += (m ? b1 : b0) * z;
  }
  out[((long long)row << 6) + lane] = 0.5f * t + 0.5f * h2;
  if (seg < 2) {
    float n1 = h2 * h2, n2 = t * t;
    for (int m = 32; m; m >>= 1) { n1 += __shfl_xor(n1, m); n2 += __shfl_xor(n2, m); }
    n1 = sqrtf(n1); n2 = sqrtf(n2);
    float a = h2 / n1, b = t / n2;
    float d = a * b;
    for (int m = 32; m; m >>= 1) d += __shfl_xor(d, m);
    float* e1 = seg ? e1i : e1u;
    float* e2 = seg ? e2i : e2u;
    e1[((long long)r << 6) + lane] = a;
    e2[((long long)r << 6) + lane] = b;
    if (lane == 0) pos[seg * BB + r] = 2.0f * d;
  }
}

// ---------------- ssl similarity matrix ----------------
__global__ __launch_bounds__(256) void k_gemm(const float* __restrict__ e1u, const float* __restrict__ e2u,
                                              const float* __restrict__ e1i, const float* __restrict__ e2i,
                                              float* __restrict__ sumexp) {
  int side = blockIdx.z;
  const float* A = side ? e1i : e1u;
  const float* Bm = side ? e2i : e2u;
  __shared__ float sA[16 * 65], sB[16 * 65];
  int bb = blockIdx.y, kk = blockIdx.x;
  for (int idx = threadIdx.x; idx < 1024; idx += 256) {
    int rr = idx >> 6, cc = idx & 63;
    sA[rr * 65 + cc] = A[(((long long)bb * 16 + rr) << 6) + cc];
    sB[rr * 65 + cc] = Bm[(((long long)kk * 16 + rr) << 6) + cc];
  }
  __syncthreads();
  int tx = threadIdx.x & 15, ty = threadIdx.x >> 4;
  float acc = 0.0f;
  for (int d = 0; d < 64; d++) acc += sA[ty * 65 + d] * sB[tx * 65 + d];
  float val = expf(2.0f * acc);
  for (int m = 8; m; m >>= 1) val += __shfl_down(val, m, 16);
  if (tx == 0)
    __hip_atomic_fetch_add(&sumexp[side * BB + bb * 16 + ty], val,
                           __ATOMIC_RELAXED, __HIP_MEMORY_SCOPE_AGENT);
}

__global__ void k_loss(const float* __restrict__ sumexp, const float* __restrict__ pos,
                       float* __restrict__ out) {
  float s = 0.0f;
  for (int i = threadIdx.x; i < 2 * BB; i += 256) s += logf(sumexp[i]) - pos[i];
  for (int m = 32; m; m >>= 1) s += __shfl_xor(s, m);
  __shared__ float r[4];
  if ((threadIdx.x & 63) == 0) r[threadIdx.x >> 6] = s;
  __syncthreads();
  if (threadIdx.x == 0) out[3 * BB * DD] = (r[0] + r[1] + r[2] + r[3]) * (1.0f / (float)BB);
}

// ---------------- launch ----------------
extern "C" void kernel_launch(void* const* d_in, const int* in_sizes, int n_in,
                              void* d_out, int out_size, void* d_ws, size_t ws_size,
                              hipStream_t stream) {
  const float* uf  = (const float*)d_in[0];
  const float* itf = (const float*)d_in[1];
  const float* UIu = (const float*)d_in[2];
  const float* UIi = (const float*)d_in[3];
  const float* W1u = (const float*)d_in[4];
  const float* b1u = (const float*)d_in[5];
  const float* w2u = (const float*)d_in[6];
  const float* W1i = (const float*)d_in[7];
  const float* b1i = (const float*)d_in[8];
  const float* w2i = (const float*)d_in[9];
  const int* ui_src   = (const int*)d_in[10];
  const int* ui_dst   = (const int*)d_in[11];
  const int* mpu      = (const int*)d_in[12];
  const int* mpi      = (const int*)d_in[13];
  const int* user_idx = (const int*)d_in[14];
  const int* item_idx = (const int*)d_in[15];
  const int* neg_idx  = (const int*)d_in[16];
  float* out = (float*)d_out;

  float* wf = (float*)d_ws;
  int*   wi = (int*)d_ws;

  int*   cnt      = wi + O_CNT;
  int*   outcnt   = wi + O_OUTCNT;
  int*   cursor   = wi + O_CURSOR;
  float* partials = wf + O_PARTIALS;
  float* UITu     = wf + O_UIT_U;
  float* UITi     = wf + O_UIT_I;
  float* W1Tu     = wf + O_W1T_U;
  float* W1Ti     = wf + O_W1T_I;
  float* sumexp   = wf + O_SUMEXP;
  float* pos      = wf + O_POS;
  int*   off      = wi + O_OFF;
  int*   bsum     = wi + O_BSUM;
  float* dinv     = wf + O_DINV;
  float* oinv     = wf + O_OINV;
  float* iinv     = wf + O_IINV;
  int*   adj      = wi + O_ADJ;
  float* wsum     = wf + O_WSUM;
  float* emba     = wf + O_EMBA;
  float* total    = wf + O_TOTAL;
  float* embb     = wf + O_EMBB;
  float* e1u      = wf + O_E1U;
  float* e2u      = wf + O_E2U;
  float* e1i      = wf + O_E1I;
  float* e2i      = wf + O_E2I;

  hipMemsetAsync(d_ws, 0, (size_t)ZEND * 4, stream);

  k_hist_main<<<(E_UI + 255) / 256, 256, 0, stream>>>(ui_src, ui_dst, cnt);
  k_hist_mp<<<dim3((E_MP + 255) / 256, 4), 256, 0, stream>>>(mpu, mpi, cnt, outcnt);

  const int NSCAN = 600000;
  const int NB = (NSCAN + 1023) / 1024;
  k_scan1<<<NB, 1024, 0, stream>>>(cnt, off, bsum, NSCAN);
  k_scan2<<<1, 1024, 0, stream>>>(bsum, NB);
  k_scan3<<<NB, 1024, 0, stream>>>(off, bsum, NSCAN);

  k_inv<<<(600000 + 255) / 256, 256, 0, stream>>>(cnt, outcnt, dinv, iinv, oinv);

  k_scatter_main<<<(E_UI + 255) / 256, 256, 0, stream>>>(ui_src, ui_dst, off, cursor, adj);
  k_scatter_mp<<<dim3((E_MP + 255) / 256, 4), 256, 0, stream>>>(mpu, mpi, off, cursor, adj);

  k_init<<<(3200000 + 255) / 256, 256, 0, stream>>>((const float4*)uf, (const float4*)itf,
                                                    (float4*)emba);
  k_tw<<<32, 256, 0, stream>>>(UIu, UIi, W1u, W1i, UITu, UITi, W1Tu, W1Ti);

  // layer 0: spmm (gnn -> embb), then attention combine in-place
  k_spmm<<<50000, 256, 0, stream>>>(emba, embb, adj, off, cnt, dinv);
  k_attn<<<1564, 128, 0, stream>>>(emba, embb, total, UITu, UITi, 0);
  // layer 1: spmm (gnn -> emba), then attention combine in-place
  k_spmm<<<50000, 256, 0, stream>>>(embb, emba, adj, off, cnt, dinv);
  k_attn<<<1564, 128, 0, stream>>>(embb, emba, total, UITu, UITi, 1);

  k_mp_score<<<dim3(NUBLK, 4), 64, 0, stream>>>(uf, itf, W1Tu, b1u, w2u, W1Ti, b1i, w2i,
                                                adj, off, cnt, oinv, iinv, partials);
  k_beta<<<4, 256, 0, stream>>>(partials, wsum);

  k_h2out<<<3072, 256, 0, stream>>>(uf, itf, user_idx, item_idx, neg_idx, total, adj, off, cnt,
                                    oinv, iinv, wsum, out, e1u, e2u, e1i, e2i, pos);

  k_gemm<<<dim3(256, 256, 2), 256, 0, stream>>>(e1u, e2u, e1i, e2i, sumexp);
  k_loss<<<1, 256, 0, stream>>>(sumexp, pos, out);
}

// Round 7
// 1565.297 us; speedup vs baseline: 2.4931x; 1.4362x over previous
//
#include <hip/hip_runtime.h>
#include <math.h>

// ---------------- problem constants ----------------
#define NUSERS   100000
#define NITEMS   100000
#define NNODES   200000
#define DD       64
#define NI       128
#define E_UI     1000000
#define E_MP     500000
#define BB       4096
#define NUBLK    1563          // ceil(100000/64)

// ---------------- workspace layout (float/int elements, 4B each) ----------------
#define O_CNT       0LL
#define O_OUTCNT    600000LL
#define O_CURSOR    1000000LL
#define O_PARTIALS  1600000LL   // 4*1563 used; +16384.. hold transposed weights
#define O_UIT_U     (O_PARTIALS + 16384)   // 8192
#define O_UIT_I     (O_PARTIALS + 24576)   // 8192
#define O_W1T_U     (O_PARTIALS + 32768)   // 8192
#define O_W1T_I     (O_PARTIALS + 40960)   // 8192
#define O_SUMEXP    1700000LL
#define O_POS       1708192LL
#define ZEND        1716384LL
#define O_OFF       1716384LL
#define O_BSUM      2316448LL
#define O_DINV      2317472LL
#define O_OINV      2517472LL
#define O_IINV      2917472LL
#define O_ADJ       3317472LL
#define O_WSUM      7317472LL
#define O_EMBA      7317480LL
#define O_TOTAL     20117480LL
#define O_EMBB      32917480LL
#define O_E1U       45717480LL
#define O_E2U       45979624LL
#define O_E1I       46241768LL
#define O_E2I       46503912LL

// ---------------- degree histograms ----------------
__global__ void k_hist_main(const int* __restrict__ src, const int* __restrict__ dst,
                            int* __restrict__ cnt) {
  int e = blockIdx.x * 256 + threadIdx.x;
  if (e < E_UI) {
    atomicAdd(&cnt[src[e]], 1);
    atomicAdd(&cnt[NUSERS + dst[e]], 1);
  }
}

__global__ void k_hist_mp(const int* __restrict__ mpu, const int* __restrict__ mpi,
                          int* __restrict__ cnt, int* __restrict__ outcnt) {
  int e = blockIdx.x * 256 + threadIdx.x;
  int g = blockIdx.y;
  if (e < E_MP) {
    const int* base = (g < 2) ? (mpu + (long long)g * 2 * E_MP)
                              : (mpi + (long long)(g - 2) * 2 * E_MP);
    int s = base[e];
    int d = base[E_MP + e];
    atomicAdd(&outcnt[g * NUSERS + s], 1);
    atomicAdd(&cnt[NNODES + g * NUSERS + d], 1);
  }
}

// ---------------- exclusive scan ----------------
__global__ __launch_bounds__(1024) void k_scan1(const int* __restrict__ in, int* __restrict__ out,
                                                int* __restrict__ bsum, int n) {
  __shared__ int s[1024];
  int i = blockIdx.x * 1024 + threadIdx.x;
  int v = (i < n) ? in[i] : 0;
  s[threadIdx.x] = v;
  __syncthreads();
  for (int off = 1; off < 1024; off <<= 1) {
    int x = (threadIdx.x >= off) ? s[threadIdx.x - off] : 0;
    __syncthreads();
    s[threadIdx.x] += x;
    __syncthreads();
  }
  if (i < n) out[i] = s[threadIdx.x] - v;
  if (threadIdx.x == 1023) bsum[blockIdx.x] = s[1023];
}

__global__ __launch_bounds__(1024) void k_scan2(int* __restrict__ bsum, int nb) {
  __shared__ int s[1024];
  int v = (threadIdx.x < nb) ? bsum[threadIdx.x] : 0;
  s[threadIdx.x] = v;
  __syncthreads();
  for (int off = 1; off < 1024; off <<= 1) {
    int x = (threadIdx.x >= off) ? s[threadIdx.x - off] : 0;
    __syncthreads();
    s[threadIdx.x] += x;
    __syncthreads();
  }
  if (threadIdx.x < nb) bsum[threadIdx.x] = s[threadIdx.x] - v;
}

__global__ __launch_bounds__(1024) void k_scan3(int* __restrict__ out, const int* __restrict__ bsum, int n) {
  int i = blockIdx.x * 1024 + threadIdx.x;
  if (i < n) out[i] += bsum[blockIdx.x];
}

// ---------------- inverse-sqrt degrees ----------------
__global__ void k_inv(const int* __restrict__ cnt, const int* __restrict__ outcnt,
                      float* __restrict__ dinv, float* __restrict__ iinv, float* __restrict__ oinv) {
  int i = blockIdx.x * 256 + threadIdx.x;
  if (i < NNODES) {
    int c = cnt[i]; if (c < 1) c = 1;
    dinv[i] = 1.0f / sqrtf((float)c);
  } else if (i < 600000) {
    int c = cnt[i]; if (c < 1) c = 1;
    iinv[i - NNODES] = 1.0f / sqrtf((float)c);
  }
  if (i < 400000) {
    int c = outcnt[i]; if (c < 1) c = 1;
    oinv[i] = 1.0f / sqrtf((float)c);
  }
}

// ---------------- CSR scatter ----------------
__global__ void k_scatter_main(const int* __restrict__ src, const int* __restrict__ dst,
                               const int* __restrict__ off, int* __restrict__ cursor,
                               int* __restrict__ adj) {
  int e = blockIdx.x * 256 + threadIdx.x;
  if (e < E_UI) {
    int u = src[e];
    int it = NUSERS + dst[e];
    int p = atomicAdd(&cursor[u], 1);
    adj[off[u] + p] = it;
    int q = atomicAdd(&cursor[it], 1);
    adj[off[it] + q] = u;
  }
}

__global__ void k_scatter_mp(const int* __restrict__ mpu, const int* __restrict__ mpi,
                             const int* __restrict__ off, int* __restrict__ cursor,
                             int* __restrict__ adj) {
  int e = blockIdx.x * 256 + threadIdx.x;
  int g = blockIdx.y;
  if (e < E_MP) {
    const int* base = (g < 2) ? (mpu + (long long)g * 2 * E_MP)
                              : (mpi + (long long)(g - 2) * 2 * E_MP);
    int s = base[e];
    int d = base[E_MP + e];
    int node = NNODES + g * NUSERS + d;
    int p = atomicAdd(&cursor[node], 1);
    adj[off[node] + p] = s;
  }
}

// ---------------- emb init ----------------
__global__ void k_init(const float4* __restrict__ uf, const float4* __restrict__ itf,
                       float4* __restrict__ emb) {
  int i = blockIdx.x * 256 + threadIdx.x;
  if (i < 3200000) {
    emb[i] = (i < 1600000) ? uf[i] : itf[i - 1600000];
  }
}

// ---------------- weight transpose prep: WT[j*64+d] = W[d*128+j] ----------------
__global__ void k_tw(const float* __restrict__ UIu, const float* __restrict__ UIi,
                     const float* __restrict__ W1u, const float* __restrict__ W1i,
                     float* __restrict__ UITu, float* __restrict__ UITi,
                     float* __restrict__ W1Tu, float* __restrict__ W1Ti) {
  int t = blockIdx.x * 256 + threadIdx.x;
  if (t < 8192) {
    int d = t >> 7, j = t & 127;
    UITu[j * 64 + d] = UIu[t];
    UITi[j * 64 + d] = UIi[t];
    W1Tu[j * 64 + d] = W1u[t];
    W1Ti[j * 64 + d] = W1i[t];
  }
}

// ---------------- masked-unroll-8 gather (dim = lane) ----------------
__device__ __forceinline__ float gather_rows(const float* __restrict__ tbl,
                                             const int* __restrict__ adj,
                                             int start, int c,
                                             const float* __restrict__ warr, int wofs,
                                             int lane) {
  float acc = 0.0f;
  for (int kb = 0; kb < c; kb += 64) {
    int rem = c - kb; if (rem > 64) rem = 64;
    int mi = 0; float mw = 0.0f;
    if (lane < rem) { mi = adj[start + kb + lane]; mw = warr[wofs + mi]; }
    for (int k = 0; k < rem; k += 8) {
      int n0=__shfl(mi,k+0),n1=__shfl(mi,k+1),n2=__shfl(mi,k+2),n3=__shfl(mi,k+3);
      int n4=__shfl(mi,k+4),n5=__shfl(mi,k+5),n6=__shfl(mi,k+6),n7=__shfl(mi,k+7);
      float w0=__shfl(mw,k+0),w1=__shfl(mw,k+1),w2=__shfl(mw,k+2),w3=__shfl(mw,k+3);
      float w4=__shfl(mw,k+4),w5=__shfl(mw,k+5),w6=__shfl(mw,k+6),w7=__shfl(mw,k+7);
      float v0=tbl[((long long)n0<<6)+lane], v1=tbl[((long long)n1<<6)+lane];
      float v2=tbl[((long long)n2<<6)+lane], v3=tbl[((long long)n3<<6)+lane];
      float v4=tbl[((long long)n4<<6)+lane], v5=tbl[((long long)n5<<6)+lane];
      float v6=tbl[((long long)n6<<6)+lane], v7=tbl[((long long)n7<<6)+lane];
      acc += w0*v0; acc += w1*v1; acc += w2*v2; acc += w3*v3;
      acc += w4*v4; acc += w5*v5; acc += w6*v6; acc += w7*v7;
    }
  }
  return acc;
}

// ---------------- spmm: wave per row, gnn stashed into enext ----------------
__global__ __launch_bounds__(256) void k_spmm(
    const float* __restrict__ ecur, float* __restrict__ gnn,
    const int* __restrict__ adj, const int* __restrict__ off,
    const int* __restrict__ cnt, const float* __restrict__ dinv) {
  int row = (blockIdx.x << 2) + (threadIdx.x >> 6);
  int lane = threadIdx.x & 63;
  float acc = gather_rows(ecur, adj, off[row], cnt[row], dinv, 0, lane);
  gnn[((long long)row << 6) + lane] = dinv[row] * acc;
}

// ---------------- intent attention: half-split (lane = node x half-dim) ----------------
// Each lane owns 32 dims of one node -> v,o,w are 8 NAMED float4 regs each (SROA-safe).
// Full dot via one shfl_xor(32) per j. Weights broadcast from LDS.
// enext holds gnn on entry; exits holding new emb. total updated.
__global__ __launch_bounds__(256, 3) void k_attn(
    const float* __restrict__ ecur, float* __restrict__ enext, float* __restrict__ total,
    const float* __restrict__ UITu, const float* __restrict__ UITi, int layer) {
  __shared__ float sW[NI * DD];   // [j][d] flat, 32 KB
  int tid = threadIdx.x;
  int bx = blockIdx.x;
  const float* UIT; long long nbase; long long lim;
  if (bx < 782) { UIT = UITu; nbase = (long long)bx * 128;            lim = NUSERS; }
  else          { UIT = UITi; nbase = NUSERS + (long long)(bx - 782) * 128; lim = NNODES; }
  {
    const float4* srcw = (const float4*)UIT;
    float4* dstw = (float4*)sW;
    for (int i = tid; i < 2048; i += 256) dstw[i] = srcw[i];
  }
  __syncthreads();
  int w = tid >> 6, lane = tid & 63;
  int nloc = lane & 31, h = lane >> 5;
  long long node = nbase + w * 32 + nloc;
  if (node >= lim) return;   // wave-uniform (boundaries are multiples of 32)

  const float* vp = ecur + (node << 6) + h * 32;
  float4 v0 = *(const float4*)(vp +  0);
  float4 v1 = *(const float4*)(vp +  4);
  float4 v2 = *(const float4*)(vp +  8);
  float4 v3 = *(const float4*)(vp + 12);
  float4 v4 = *(const float4*)(vp + 16);
  float4 v5 = *(const float4*)(vp + 20);
  float4 v6 = *(const float4*)(vp + 24);
  float4 v7 = *(const float4*)(vp + 28);
  float4 o0 = make_float4(0,0,0,0), o1 = o0, o2 = o0, o3 = o0;
  float4 o4 = o0, o5 = o0, o6 = o0, o7 = o0;
  float den = 0.0f;
  const float4* wb = ((const float4*)sW) + h * 8;   // float4 index: j*16 + h*8
  for (int j = 0; j < NI; j++) {
    const float4* wr = wb + j * 16;
    float4 w0 = wr[0], w1 = wr[1], w2 = wr[2], w3 = wr[3];
    float4 w4 = wr[4], w5 = wr[5], w6 = wr[6], w7 = wr[7];
    float p0 = v0.x*w0.x + v0.y*w0.y + v0.z*w0.z + v0.w*w0.w;
    float p1 = v1.x*w1.x + v1.y*w1.y + v1.z*w1.z + v1.w*w1.w;
    float p2 = v2.x*w2.x + v2.y*w2.y + v2.z*w2.z + v2.w*w2.w;
    float p3 = v3.x*w3.x + v3.y*w3.y + v3.z*w3.z + v3.w*w3.w;
    float p4 = v4.x*w4.x + v4.y*w4.y + v4.z*w4.z + v4.w*w4.w;
    float p5 = v5.x*w5.x + v5.y*w5.y + v5.z*w5.z + v5.w*w5.w;
    float p6 = v6.x*w6.x + v6.y*w6.y + v6.z*w6.z + v6.w*w6.w;
    float p7 = v7.x*w7.x + v7.y*w7.y + v7.z*w7.z + v7.w*w7.w;
    float s = ((p0 + p1) + (p2 + p3)) + ((p4 + p5) + (p6 + p7));
    s += __shfl_xor(s, 32);
    float e = __expf(s);          // |s| << 1: no max-subtraction needed
    den += e;
    o0.x += e*w0.x; o0.y += e*w0.y; o0.z += e*w0.z; o0.w += e*w0.w;
    o1.x += e*w1.x; o1.y += e*w1.y; o1.z += e*w1.z; o1.w += e*w1.w;
    o2.x += e*w2.x; o2.y += e*w2.y; o2.z += e*w2.z; o2.w += e*w2.w;
    o3.x += e*w3.x; o3.y += e*w3.y; o3.z += e*w3.z; o3.w += e*w3.w;
    o4.x += e*w4.x; o4.y += e*w4.y; o4.z += e*w4.z; o4.w += e*w4.w;
    o5.x += e*w5.x; o5.y += e*w5.y; o5.z += e*w5.z; o5.w += e*w5.w;
    o6.x += e*w6.x; o6.y += e*w6.y; o6.z += e*w6.z; o6.w += e*w6.w;
    o7.x += e*w7.x; o7.y += e*w7.y; o7.z += e*w7.z; o7.w += e*w7.w;
  }
  float r = 1.0f / den;
  float* ep = enext + (node << 6) + h * 32;
  float* tp = total + (node << 6) + h * 32;
#define FINISH(q, vq, oq)                                                       \
  { float4 gn = *(float4*)(ep + (q)*4);                                        \
    float4 ne = make_float4(gn.x + oq.x*r + vq.x, gn.y + oq.y*r + vq.y,        \
                            gn.z + oq.z*r + vq.z, gn.w + oq.w*r + vq.w);       \
    *(float4*)(ep + (q)*4) = ne;                                               \
    if (layer == 0) {                                                          \
      *(float4*)(tp + (q)*4) = make_float4(vq.x + ne.x, vq.y + ne.y,           \
                                           vq.z + ne.z, vq.w + ne.w);          \
    } else {                                                                   \
      float4 tt = *(float4*)(tp + (q)*4);                                      \
      *(float4*)(tp + (q)*4) = make_float4(tt.x + ne.x, tt.y + ne.y,           \
                                           tt.z + ne.z, tt.w + ne.w);          \
    } }
  FINISH(0, v0, o0) FINISH(1, v1, o1) FINISH(2, v2, o2) FINISH(3, v3, o3)
  FINISH(4, v4, o4) FINISH(5, v5, o5) FINISH(6, v6, o6) FINISH(7, v7, o7)
#undef FINISH
}

// ---------------- metapath graphconv + semantic-att score, node=lane ----------------
__global__ __launch_bounds__(64) void k_mp_score(
    const float* __restrict__ uf, const float* __restrict__ itf,
    const float* __restrict__ W1Tu, const float* __restrict__ b1u, const float* __restrict__ w2u,
    const float* __restrict__ W1Ti, const float* __restrict__ b1i, const float* __restrict__ w2i,
    const int* __restrict__ adj, const int* __restrict__ off, const int* __restrict__ cnt,
    const float* __restrict__ oinv, const float* __restrict__ iinv, float* __restrict__ partials) {
  __shared__ float sZ[64 * 65];
  int lane = threadIdx.x;
  int g = blockIdx.y;
  const float* feat = (g < 2) ? uf : itf;
  const float* W1T  = (g < 2) ? W1Tu : W1Ti;
  const float* b1   = (g < 2) ? b1u : b1i;
  const float* w2   = (g < 2) ? w2u : w2i;
  int gofs = g * NUSERS;
  int nb0 = blockIdx.x << 6;
  int mmax = NUSERS - nb0; if (mmax > 64) mmax = 64;

  for (int m = 0; m < mmax; m++) {
    int n = nb0 + m;
    int node = NNODES + gofs + n;
    float z = gather_rows(feat, adj, off[node], cnt[node], oinv, gofs, lane);
    sZ[m * 65 + lane] = z * iinv[gofs + n];
  }

  float z[64];
#pragma unroll
  for (int d = 0; d < 64; d++) z[d] = sZ[lane * 65 + d];
  float p = 0.0f;
  for (int j = 0; j < 128; j++) {
    const float* wr = &W1T[j * 64];
    float s = b1[j];
#pragma unroll
    for (int d = 0; d < 64; d++) s += z[d] * wr[d];
    float t = 1.0f - 2.0f / (__expf(2.0f * s) + 1.0f);
    p += t * w2[j];
  }
  if (lane >= mmax) p = 0.0f;
  for (int m = 32; m; m >>= 1) p += __shfl_xor(p, m);
  if (lane == 0) partials[g * NUBLK + blockIdx.x] = p;
}

__global__ void k_beta(const float* __restrict__ partials, float* __restrict__ wsum) {
  int g = blockIdx.x;
  float s = 0.0f;
  for (int i = threadIdx.x; i < NUBLK; i += 256) s += partials[g * NUBLK + i];
  for (int m = 32; m; m >>= 1) s += __shfl_xor(s, m);
  __shared__ float r[4];
  if ((threadIdx.x & 63) == 0) r[threadIdx.x >> 6] = s;
  __syncthreads();
  if (threadIdx.x == 0) wsum[g] = r[0] + r[1] + r[2] + r[3];
}

// ---------------- gather outputs + ssl embedding prep ----------------
__global__ __launch_bounds__(256) void k_h2out(
    const float* __restrict__ uf, const float* __restrict__ itf,
    const int* __restrict__ user_idx, const int* __restrict__ item_idx, const int* __restrict__ neg_idx,
    const float* __restrict__ total, const int* __restrict__ adj, const int* __restrict__ off,
    const int* __restrict__ cnt, const float* __restrict__ oinv, const float* __restrict__ iinv,
    const float* __restrict__ wsum, float* __restrict__ out,
    float* __restrict__ e1u, float* __restrict__ e2u,
    float* __restrict__ e1i, float* __restrict__ e2i, float* __restrict__ pos) {
  int lane = threadIdx.x & 63;
  int row = (blockIdx.x << 2) + (threadIdx.x >> 6);
  int seg = row >> 12;
  int r = row & 4095;
  int idx;
  const float* feat;
  int gbase;
  if (seg == 0)      { idx = user_idx[r]; feat = uf;  gbase = 0; }
  else if (seg == 1) { idx = item_idx[r]; feat = itf; gbase = 2; }
  else               { idx = neg_idx[r];  feat = itf; gbase = 2; }
  int tnode = gbase ? (NUSERS + idx) : idx;
  float t = total[((long long)tnode << 6) + lane];
  float w0 = wsum[gbase] * (1.0f / 100000.0f);
  float w1 = wsum[gbase + 1] * (1.0f / 100000.0f);
  float mb = fmaxf(w0, w1);
  float b0 = expf(w0 - mb), b1 = expf(w1 - mb);
  float bs = b0 + b1;
  b0 /= bs; b1 /= bs;
  float h2 = 0.0f;
  for (int m = 0; m < 2; m++) {
    int g = gbase + m;
    int gofs = g * NUSERS;
    int node = NNODES + g * NUSERS + idx;
    float z = gather_rows(feat, adj, off[node], cnt[node], oinv, gofs, lane);
    z *= iinv[gofs + idx];
    h2 += (m ? b1 : b0) * z;
  }
  out[((long long)row << 6) + lane] = 0.5f * t + 0.5f * h2;
  if (seg < 2) {
    float n1 = h2 * h2, n2 = t * t;
    for (int m = 32; m; m >>= 1) { n1 += __shfl_xor(n1, m); n2 += __shfl_xor(n2, m); }
    n1 = sqrtf(n1); n2 = sqrtf(n2);
    float a = h2 / n1, b = t / n2;
    float d = a * b;
    for (int m = 32; m; m >>= 1) d += __shfl_xor(d, m);
    float* e1 = seg ? e1i : e1u;
    float* e2 = seg ? e2i : e2u;
    e1[((long long)r << 6) + lane] = a;
    e2[((long long)r << 6) + lane] = b;
    if (lane == 0) pos[seg * BB + r] = 2.0f * d;
  }
}

// ---------------- ssl similarity: 64x64 tile per block, 4x4 per thread ----------------
__global__ __launch_bounds__(256) void k_gemm(const float* __restrict__ e1u, const float* __restrict__ e2u,
                                              const float* __restrict__ e1i, const float* __restrict__ e2i,
                                              float* __restrict__ sumexp) {
  int side = blockIdx.z;
  const float* A = side ? e1i : e1u;
  const float* Bm = side ? e2i : e2u;
  __shared__ float sA[64][68], sB[64][68];
  int bb = blockIdx.y, kk = blockIdx.x;
  int tid = threadIdx.x;
  for (int i = tid; i < 1024; i += 256) {
    int row = i >> 4, d4 = (i & 15) << 2;
    float4 a = *(const float4*)&A[(((long long)(bb * 64 + row)) << 6) + d4];
    float4 b = *(const float4*)&Bm[(((long long)(kk * 64 + row)) << 6) + d4];
    *(float4*)&sA[row][d4] = a;
    *(float4*)&sB[row][d4] = b;
  }
  __syncthreads();
  int tx = tid & 15, ty = tid >> 4;
  int r0 = ty << 2, c0 = tx << 2;
  float acc[4][4] = {{0}};
  for (int k = 0; k < 64; k += 4) {
    float4 a0 = *(const float4*)&sA[r0 + 0][k];
    float4 a1 = *(const float4*)&sA[r0 + 1][k];
    float4 a2 = *(const float4*)&sA[r0 + 2][k];
    float4 a3 = *(const float4*)&sA[r0 + 3][k];
    float4 b0 = *(const float4*)&sB[c0 + 0][k];
    float4 b1 = *(const float4*)&sB[c0 + 1][k];
    float4 b2 = *(const float4*)&sB[c0 + 2][k];
    float4 b3 = *(const float4*)&sB[c0 + 3][k];
#define DOT(u_, v_) (u_.x*v_.x + u_.y*v_.y + u_.z*v_.z + u_.w*v_.w)
    acc[0][0] += DOT(a0, b0); acc[0][1] += DOT(a0, b1); acc[0][2] += DOT(a0, b2); acc[0][3] += DOT(a0, b3);
    acc[1][0] += DOT(a1, b0); acc[1][1] += DOT(a1, b1); acc[1][2] += DOT(a1, b2); acc[1][3] += DOT(a1, b3);
    acc[2][0] += DOT(a2, b0); acc[2][1] += DOT(a2, b1); acc[2][2] += DOT(a2, b2); acc[2][3] += DOT(a2, b3);
    acc[3][0] += DOT(a3, b0); acc[3][1] += DOT(a3, b1); acc[3][2] += DOT(a3, b2); acc[3][3] += DOT(a3, b3);
#undef DOT
  }
#pragma unroll
  for (int i = 0; i < 4; i++) {
    float rs = __expf(2.0f * acc[i][0]) + __expf(2.0f * acc[i][1])
             + __expf(2.0f * acc[i][2]) + __expf(2.0f * acc[i][3]);
    for (int m = 1; m < 16; m <<= 1) rs += __shfl_xor(rs, m);
    if (tx == 0)
      __hip_atomic_fetch_add(&sumexp[side * BB + bb * 64 + r0 + i], rs,
                             __ATOMIC_RELAXED, __HIP_MEMORY_SCOPE_AGENT);
  }
}

__global__ void k_loss(const float* __restrict__ sumexp, const float* __restrict__ pos,
                       float* __restrict__ out) {
  float s = 0.0f;
  for (int i = threadIdx.x; i < 2 * BB; i += 256) s += logf(sumexp[i]) - pos[i];
  for (int m = 32; m; m >>= 1) s += __shfl_xor(s, m);
  __shared__ float r[4];
  if ((threadIdx.x & 63) == 0) r[threadIdx.x >> 6] = s;
  __syncthreads();
  if (threadIdx.x == 0) out[3 * BB * DD] = (r[0] + r[1] + r[2] + r[3]) * (1.0f / (float)BB);
}

// ---------------- launch ----------------
extern "C" void kernel_launch(void* const* d_in, const int* in_sizes, int n_in,
                              void* d_out, int out_size, void* d_ws, size_t ws_size,
                              hipStream_t stream) {
  const float* uf  = (const float*)d_in[0];
  const float* itf = (const float*)d_in[1];
  const float* UIu = (const float*)d_in[2];
  const float* UIi = (const float*)d_in[3];
  const float* W1u = (const float*)d_in[4];
  const float* b1u = (const float*)d_in[5];
  const float* w2u = (const float*)d_in[6];
  const float* W1i = (const float*)d_in[7];
  const float* b1i = (const float*)d_in[8];
  const float* w2i = (const float*)d_in[9];
  const int* ui_src   = (const int*)d_in[10];
  const int* ui_dst   = (const int*)d_in[11];
  const int* mpu      = (const int*)d_in[12];
  const int* mpi      = (const int*)d_in[13];
  const int* user_idx = (const int*)d_in[14];
  const int* item_idx = (const int*)d_in[15];
  const int* neg_idx  = (const int*)d_in[16];
  float* out = (float*)d_out;

  float* wf = (float*)d_ws;
  int*   wi = (int*)d_ws;

  int*   cnt      = wi + O_CNT;
  int*   outcnt   = wi + O_OUTCNT;
  int*   cursor   = wi + O_CURSOR;
  float* partials = wf + O_PARTIALS;
  float* UITu     = wf + O_UIT_U;
  float* UITi     = wf + O_UIT_I;
  float* W1Tu     = wf + O_W1T_U;
  float* W1Ti     = wf + O_W1T_I;
  float* sumexp   = wf + O_SUMEXP;
  float* pos      = wf + O_POS;
  int*   off      = wi + O_OFF;
  int*   bsum     = wi + O_BSUM;
  float* dinv     = wf + O_DINV;
  float* oinv     = wf + O_OINV;
  float* iinv     = wf + O_IINV;
  int*   adj      = wi + O_ADJ;
  float* wsum     = wf + O_WSUM;
  float* emba     = wf + O_EMBA;
  float* total    = wf + O_TOTAL;
  float* embb     = wf + O_EMBB;
  float* e1u      = wf + O_E1U;
  float* e2u      = wf + O_E2U;
  float* e1i      = wf + O_E1I;
  float* e2i      = wf + O_E2I;

  hipMemsetAsync(d_ws, 0, (size_t)ZEND * 4, stream);

  k_hist_main<<<(E_UI + 255) / 256, 256, 0, stream>>>(ui_src, ui_dst, cnt);
  k_hist_mp<<<dim3((E_MP + 255) / 256, 4), 256, 0, stream>>>(mpu, mpi, cnt, outcnt);

  const int NSCAN = 600000;
  const int NB = (NSCAN + 1023) / 1024;
  k_scan1<<<NB, 1024, 0, stream>>>(cnt, off, bsum, NSCAN);
  k_scan2<<<1, 1024, 0, stream>>>(bsum, NB);
  k_scan3<<<NB, 1024, 0, stream>>>(off, bsum, NSCAN);

  k_inv<<<(600000 + 255) / 256, 256, 0, stream>>>(cnt, outcnt, dinv, iinv, oinv);

  k_scatter_main<<<(E_UI + 255) / 256, 256, 0, stream>>>(ui_src, ui_dst, off, cursor, adj);
  k_scatter_mp<<<dim3((E_MP + 255) / 256, 4), 256, 0, stream>>>(mpu, mpi, off, cursor, adj);

  k_init<<<(3200000 + 255) / 256, 256, 0, stream>>>((const float4*)uf, (const float4*)itf,
                                                    (float4*)emba);
  k_tw<<<32, 256, 0, stream>>>(UIu, UIi, W1u, W1i, UITu, UITi, W1Tu, W1Ti);

  // layer 0: spmm (gnn -> embb), then attention combine in-place
  k_spmm<<<50000, 256, 0, stream>>>(emba, embb, adj, off, cnt, dinv);
  k_attn<<<1564, 256, 0, stream>>>(emba, embb, total, UITu, UITi, 0);
  // layer 1: spmm (gnn -> emba), then attention combine in-place
  k_spmm<<<50000, 256, 0, stream>>>(embb, emba, adj, off, cnt, dinv);
  k_attn<<<1564, 256, 0, stream>>>(embb, emba, total, UITu, UITi, 1);

  k_mp_score<<<dim3(NUBLK, 4), 64, 0, stream>>>(uf, itf, W1Tu, b1u, w2u, W1Ti, b1i, w2i,
                                                adj, off, cnt, oinv, iinv, partials);
  k_beta<<<4, 256, 0, stream>>>(partials, wsum);

  k_h2out<<<3072, 256, 0, stream>>>(uf, itf, user_idx, item_idx, neg_idx, total, adj, off, cnt,
                                    oinv, iinv, wsum, out, e1u, e2u, e1i, e2i, pos);

  k_gemm<<<dim3(64, 64, 2), 256, 0, stream>>>(e1u, e2u, e1i, e2i, sumexp);
  k_loss<<<1, 256, 0, stream>>>(sumexp, pos, out);
}

// Round 8
// 1555.742 us; speedup vs baseline: 2.5084x; 1.0061x over previous
//
#include <hip/hip_runtime.h>
#include <math.h>

// ---------------- problem constants ----------------
#define NUSERS   100000
#define NITEMS   100000
#define NNODES   200000
#define DD       64
#define NI       128
#define E_UI     1000000
#define E_MP     500000
#define BB       4096
#define NBLKM    782           // ceil(100000/128)

// ---------------- workspace layout (float/int elements, 4B each) ----------------
#define O_CNT       0LL
#define O_OUTCNT    600000LL
#define O_CURSOR    1000000LL
#define O_PARTIALS  1600000LL   // 4*782 used; +16384.. hold transposed weights
#define O_UIT_U     (O_PARTIALS + 16384)   // 8192
#define O_UIT_I     (O_PARTIALS + 24576)   // 8192
#define O_W1T_U     (O_PARTIALS + 32768)   // 8192
#define O_W1T_I     (O_PARTIALS + 40960)   // 8192
#define O_SUMEXP    1700000LL
#define O_POS       1708192LL
#define ZEND        1716384LL
#define O_OFF       1716384LL
#define O_BSUM      2316448LL
#define O_DINV      2317472LL
#define O_OINV      2517472LL
#define O_IINV      2917472LL
#define O_ADJ       3317472LL
#define O_WSUM      7317472LL
#define O_EMBA      7317480LL   // 12.8M: layer ping; reused as zbuf for mp graphs 0,1
#define O_TOTAL     20117480LL
#define O_EMBB      32917480LL  // 12.8M: layer pong; reused as zbuf for mp graphs 2,3
#define O_E1U       45717480LL
#define O_E2U       45979624LL
#define O_E1I       46241768LL
#define O_E2I       46503912LL

// ---------------- degree histograms ----------------
__global__ void k_hist_main(const int* __restrict__ src, const int* __restrict__ dst,
                            int* __restrict__ cnt) {
  int e = blockIdx.x * 256 + threadIdx.x;
  if (e < E_UI) {
    atomicAdd(&cnt[src[e]], 1);
    atomicAdd(&cnt[NUSERS + dst[e]], 1);
  }
}

__global__ void k_hist_mp(const int* __restrict__ mpu, const int* __restrict__ mpi,
                          int* __restrict__ cnt, int* __restrict__ outcnt) {
  int e = blockIdx.x * 256 + threadIdx.x;
  int g = blockIdx.y;
  if (e < E_MP) {
    const int* base = (g < 2) ? (mpu + (long long)g * 2 * E_MP)
                              : (mpi + (long long)(g - 2) * 2 * E_MP);
    int s = base[e];
    int d = base[E_MP + e];
    atomicAdd(&outcnt[g * NUSERS + s], 1);
    atomicAdd(&cnt[NNODES + g * NUSERS + d], 1);
  }
}

// ---------------- exclusive scan ----------------
__global__ __launch_bounds__(1024) void k_scan1(const int* __restrict__ in, int* __restrict__ out,
                                                int* __restrict__ bsum, int n) {
  __shared__ int s[1024];
  int i = blockIdx.x * 1024 + threadIdx.x;
  int v = (i < n) ? in[i] : 0;
  s[threadIdx.x] = v;
  __syncthreads();
  for (int off = 1; off < 1024; off <<= 1) {
    int x = (threadIdx.x >= off) ? s[threadIdx.x - off] : 0;
    __syncthreads();
    s[threadIdx.x] += x;
    __syncthreads();
  }
  if (i < n) out[i] = s[threadIdx.x] - v;
  if (threadIdx.x == 1023) bsum[blockIdx.x] = s[1023];
}

__global__ __launch_bounds__(1024) void k_scan2(int* __restrict__ bsum, int nb) {
  __shared__ int s[1024];
  int v = (threadIdx.x < nb) ? bsum[threadIdx.x] : 0;
  s[threadIdx.x] = v;
  __syncthreads();
  for (int off = 1; off < 1024; off <<= 1) {
    int x = (threadIdx.x >= off) ? s[threadIdx.x - off] : 0;
    __syncthreads();
    s[threadIdx.x] += x;
    __syncthreads();
  }
  if (threadIdx.x < nb) bsum[threadIdx.x] = s[threadIdx.x] - v;
}

__global__ __launch_bounds__(1024) void k_scan3(int* __restrict__ out, const int* __restrict__ bsum, int n) {
  int i = blockIdx.x * 1024 + threadIdx.x;
  if (i < n) out[i] += bsum[blockIdx.x];
}

// ---------------- inverse-sqrt degrees ----------------
__global__ void k_inv(const int* __restrict__ cnt, const int* __restrict__ outcnt,
                      float* __restrict__ dinv, float* __restrict__ iinv, float* __restrict__ oinv) {
  int i = blockIdx.x * 256 + threadIdx.x;
  if (i < NNODES) {
    int c = cnt[i]; if (c < 1) c = 1;
    dinv[i] = 1.0f / sqrtf((float)c);
  } else if (i < 600000) {
    int c = cnt[i]; if (c < 1) c = 1;
    iinv[i - NNODES] = 1.0f / sqrtf((float)c);
  }
  if (i < 400000) {
    int c = outcnt[i]; if (c < 1) c = 1;
    oinv[i] = 1.0f / sqrtf((float)c);
  }
}

// ---------------- CSR scatter ----------------
__global__ void k_scatter_main(const int* __restrict__ src, const int* __restrict__ dst,
                               const int* __restrict__ off, int* __restrict__ cursor,
                               int* __restrict__ adj) {
  int e = blockIdx.x * 256 + threadIdx.x;
  if (e < E_UI) {
    int u = src[e];
    int it = NUSERS + dst[e];
    int p = atomicAdd(&cursor[u], 1);
    adj[off[u] + p] = it;
    int q = atomicAdd(&cursor[it], 1);
    adj[off[it] + q] = u;
  }
}

__global__ void k_scatter_mp(const int* __restrict__ mpu, const int* __restrict__ mpi,
                             const int* __restrict__ off, int* __restrict__ cursor,
                             int* __restrict__ adj) {
  int e = blockIdx.x * 256 + threadIdx.x;
  int g = blockIdx.y;
  if (e < E_MP) {
    const int* base = (g < 2) ? (mpu + (long long)g * 2 * E_MP)
                              : (mpi + (long long)(g - 2) * 2 * E_MP);
    int s = base[e];
    int d = base[E_MP + e];
    int node = NNODES + g * NUSERS + d;
    int p = atomicAdd(&cursor[node], 1);
    adj[off[node] + p] = s;
  }
}

// ---------------- emb init ----------------
__global__ void k_init(const float4* __restrict__ uf, const float4* __restrict__ itf,
                       float4* __restrict__ emb) {
  int i = blockIdx.x * 256 + threadIdx.x;
  if (i < 3200000) {
    emb[i] = (i < 1600000) ? uf[i] : itf[i - 1600000];
  }
}

// ---------------- weight transpose prep: WT[j*64+d] = W[d*128+j] ----------------
__global__ void k_tw(const float* __restrict__ UIu, const float* __restrict__ UIi,
                     const float* __restrict__ W1u, const float* __restrict__ W1i,
                     float* __restrict__ UITu, float* __restrict__ UITi,
                     float* __restrict__ W1Tu, float* __restrict__ W1Ti) {
  int t = blockIdx.x * 256 + threadIdx.x;
  if (t < 8192) {
    int d = t >> 7, j = t & 127;
    UITu[j * 64 + d] = UIu[t];
    UITi[j * 64 + d] = UIi[t];
    W1Tu[j * 64 + d] = W1u[t];
    W1Ti[j * 64 + d] = W1i[t];
  }
}

// ---------------- masked-unroll-8 gather (dim = lane) ----------------
__device__ __forceinline__ float gather_rows(const float* __restrict__ tbl,
                                             const int* __restrict__ adj,
                                             int start, int c,
                                             const float* __restrict__ warr, int wofs,
                                             int lane) {
  float acc = 0.0f;
  for (int kb = 0; kb < c; kb += 64) {
    int rem = c - kb; if (rem > 64) rem = 64;
    int mi = 0; float mw = 0.0f;
    if (lane < rem) { mi = adj[start + kb + lane]; mw = warr[wofs + mi]; }
    for (int k = 0; k < rem; k += 8) {
      int n0=__shfl(mi,k+0),n1=__shfl(mi,k+1),n2=__shfl(mi,k+2),n3=__shfl(mi,k+3);
      int n4=__shfl(mi,k+4),n5=__shfl(mi,k+5),n6=__shfl(mi,k+6),n7=__shfl(mi,k+7);
      float w0=__shfl(mw,k+0),w1=__shfl(mw,k+1),w2=__shfl(mw,k+2),w3=__shfl(mw,k+3);
      float w4=__shfl(mw,k+4),w5=__shfl(mw,k+5),w6=__shfl(mw,k+6),w7=__shfl(mw,k+7);
      float v0=tbl[((long long)n0<<6)+lane], v1=tbl[((long long)n1<<6)+lane];
      float v2=tbl[((long long)n2<<6)+lane], v3=tbl[((long long)n3<<6)+lane];
      float v4=tbl[((long long)n4<<6)+lane], v5=tbl[((long long)n5<<6)+lane];
      float v6=tbl[((long long)n6<<6)+lane], v7=tbl[((long long)n7<<6)+lane];
      acc += w0*v0; acc += w1*v1; acc += w2*v2; acc += w3*v3;
      acc += w4*v4; acc += w5*v5; acc += w6*v6; acc += w7*v7;
    }
  }
  return acc;
}

// ---------------- spmm: wave per row, gnn stashed into enext ----------------
__global__ __launch_bounds__(256, 6) void k_spmm(
    const float* __restrict__ ecur, float* __restrict__ gnn,
    const int* __restrict__ adj, const int* __restrict__ off,
    const int* __restrict__ cnt, const float* __restrict__ dinv) {
  int row = (blockIdx.x << 2) + (threadIdx.x >> 6);
  int lane = threadIdx.x & 63;
  float acc = gather_rows(ecur, adj, off[row], cnt[row], dinv, 0, lane);
  gnn[((long long)row << 6) + lane] = dinv[row] * acc;
}

// ---------------- intent attention: half-split (lane = node x half-dim) ----------------
__global__ __launch_bounds__(256, 3) void k_attn(
    const float* __restrict__ ecur, float* __restrict__ enext, float* __restrict__ total,
    const float* __restrict__ UITu, const float* __restrict__ UITi, int layer) {
  __shared__ float sW[NI * DD];   // [j][d] flat, 32 KB
  int tid = threadIdx.x;
  int bx = blockIdx.x;
  const float* UIT; long long nbase; long long lim;
  if (bx < 782) { UIT = UITu; nbase = (long long)bx * 128;            lim = NUSERS; }
  else          { UIT = UITi; nbase = NUSERS + (long long)(bx - 782) * 128; lim = NNODES; }
  {
    const float4* srcw = (const float4*)UIT;
    float4* dstw = (float4*)sW;
    for (int i = tid; i < 2048; i += 256) dstw[i] = srcw[i];
  }
  __syncthreads();
  int w = tid >> 6, lane = tid & 63;
  int nloc = lane & 31, h = lane >> 5;
  long long node = nbase + w * 32 + nloc;
  if (node >= lim) return;   // wave-uniform (boundaries are multiples of 32)

  const float* vp = ecur + (node << 6) + h * 32;
  float4 v0 = *(const float4*)(vp +  0);
  float4 v1 = *(const float4*)(vp +  4);
  float4 v2 = *(const float4*)(vp +  8);
  float4 v3 = *(const float4*)(vp + 12);
  float4 v4 = *(const float4*)(vp + 16);
  float4 v5 = *(const float4*)(vp + 20);
  float4 v6 = *(const float4*)(vp + 24);
  float4 v7 = *(const float4*)(vp + 28);
  float4 o0 = make_float4(0,0,0,0), o1 = o0, o2 = o0, o3 = o0;
  float4 o4 = o0, o5 = o0, o6 = o0, o7 = o0;
  float den = 0.0f;
  const float4* wb = ((const float4*)sW) + h * 8;   // float4 index: j*16 + h*8
  for (int j = 0; j < NI; j++) {
    const float4* wr = wb + j * 16;
    float4 w0 = wr[0], w1 = wr[1], w2 = wr[2], w3 = wr[3];
    float4 w4 = wr[4], w5 = wr[5], w6 = wr[6], w7 = wr[7];
    float p0 = v0.x*w0.x + v0.y*w0.y + v0.z*w0.z + v0.w*w0.w;
    float p1 = v1.x*w1.x + v1.y*w1.y + v1.z*w1.z + v1.w*w1.w;
    float p2 = v2.x*w2.x + v2.y*w2.y + v2.z*w2.z + v2.w*w2.w;
    float p3 = v3.x*w3.x + v3.y*w3.y + v3.z*w3.z + v3.w*w3.w;
    float p4 = v4.x*w4.x + v4.y*w4.y + v4.z*w4.z + v4.w*w4.w;
    float p5 = v5.x*w5.x + v5.y*w5.y + v5.z*w5.z + v5.w*w5.w;
    float p6 = v6.x*w6.x + v6.y*w6.y + v6.z*w6.z + v6.w*w6.w;
    float p7 = v7.x*w7.x + v7.y*w7.y + v7.z*w7.z + v7.w*w7.w;
    float s = ((p0 + p1) + (p2 + p3)) + ((p4 + p5) + (p6 + p7));
    s += __shfl_xor(s, 32);
    float e = __expf(s);          // |s| << 1: no max-subtraction needed
    den += e;
    o0.x += e*w0.x; o0.y += e*w0.y; o0.z += e*w0.z; o0.w += e*w0.w;
    o1.x += e*w1.x; o1.y += e*w1.y; o1.z += e*w1.z; o1.w += e*w1.w;
    o2.x += e*w2.x; o2.y += e*w2.y; o2.z += e*w2.z; o2.w += e*w2.w;
    o3.x += e*w3.x; o3.y += e*w3.y; o3.z += e*w3.z; o3.w += e*w3.w;
    o4.x += e*w4.x; o4.y += e*w4.y; o4.z += e*w4.z; o4.w += e*w4.w;
    o5.x += e*w5.x; o5.y += e*w5.y; o5.z += e*w5.z; o5.w += e*w5.w;
    o6.x += e*w6.x; o6.y += e*w6.y; o6.z += e*w6.z; o6.w += e*w6.w;
    o7.x += e*w7.x; o7.y += e*w7.y; o7.z += e*w7.z; o7.w += e*w7.w;
  }
  float r = 1.0f / den;
  float* ep = enext + (node << 6) + h * 32;
  float* tp = total + (node << 6) + h * 32;
#define FINISH(q, vq, oq)                                                       \
  { float4 gn = *(float4*)(ep + (q)*4);                                        \
    float4 ne = make_float4(gn.x + oq.x*r + vq.x, gn.y + oq.y*r + vq.y,        \
                            gn.z + oq.z*r + vq.z, gn.w + oq.w*r + vq.w);       \
    *(float4*)(ep + (q)*4) = ne;                                               \
    if (layer == 0) {                                                          \
      *(float4*)(tp + (q)*4) = make_float4(vq.x + ne.x, vq.y + ne.y,           \
                                           vq.z + ne.z, vq.w + ne.w);          \
    } else {                                                                   \
      float4 tt = *(float4*)(tp + (q)*4);                                      \
      *(float4*)(tp + (q)*4) = make_float4(tt.x + ne.x, tt.y + ne.y,           \
                                           tt.z + ne.z, tt.w + ne.w);          \
    } }
  FINISH(0, v0, o0) FINISH(1, v1, o1) FINISH(2, v2, o2) FINISH(3, v3, o3)
  FINISH(4, v4, o4) FINISH(5, v5, o5) FINISH(6, v6, o6) FINISH(7, v7, o7)
#undef FINISH
}

// ---------------- metapath graphconv gather: z (x iinv) -> zbuf ----------------
__global__ __launch_bounds__(256, 6) void k_mp_gather(
    const float* __restrict__ uf, const float* __restrict__ itf,
    const int* __restrict__ adj, const int* __restrict__ off, const int* __restrict__ cnt,
    const float* __restrict__ oinv, const float* __restrict__ iinv,
    float* __restrict__ zu, float* __restrict__ zi) {
  int g = blockIdx.y;
  const float* feat = (g < 2) ? uf : itf;
  float* zb = (g < 2) ? zu + ((long long)g * NUSERS << 6)
                      : zi + ((long long)(g - 2) * NUSERS << 6);
  int n = (blockIdx.x << 2) + (threadIdx.x >> 6);
  int lane = threadIdx.x & 63;
  int gofs = g * NUSERS;
  int node = NNODES + gofs + n;
  float z = gather_rows(feat, adj, off[node], cnt[node], oinv, gofs, lane);
  zb[((long long)n << 6) + lane] = z * iinv[gofs + n];
}

// ---------------- metapath MLP score: half-split, register-resident ----------------
__global__ __launch_bounds__(256, 4) void k_mp_mlp(
    const float* __restrict__ zu, const float* __restrict__ zi,
    const float* __restrict__ W1Tu, const float* __restrict__ b1u, const float* __restrict__ w2u,
    const float* __restrict__ W1Ti, const float* __restrict__ b1i, const float* __restrict__ w2i,
    float* __restrict__ partials) {
  __shared__ float sW[NI * DD];   // 32 KB
  __shared__ float red[4];
  int g = blockIdx.y;
  const float* W1T = (g < 2) ? W1Tu : W1Ti;
  const float* b1  = (g < 2) ? b1u : b1i;
  const float* w2  = (g < 2) ? w2u : w2i;
  const float* zb  = (g < 2) ? zu + ((long long)g * NUSERS << 6)
                             : zi + ((long long)(g - 2) * NUSERS << 6);
  int tid = threadIdx.x;
  {
    const float4* srcw = (const float4*)W1T;
    float4* dstw = (float4*)sW;
    for (int i = tid; i < 2048; i += 256) dstw[i] = srcw[i];
  }
  __syncthreads();
  int w = tid >> 6, lane = tid & 63;
  int nloc = lane & 31, h = lane >> 5;
  int n = blockIdx.x * 128 + w * 32 + nloc;
  float p = 0.0f;
  if (n < NUSERS) {   // wave-uniform (mmax multiples of 32)
    const float* vp = zb + ((long long)n << 6) + h * 32;
    float4 v0 = *(const float4*)(vp +  0);
    float4 v1 = *(const float4*)(vp +  4);
    float4 v2 = *(const float4*)(vp +  8);
    float4 v3 = *(const float4*)(vp + 12);
    float4 v4 = *(const float4*)(vp + 16);
    float4 v5 = *(const float4*)(vp + 20);
    float4 v6 = *(const float4*)(vp + 24);
    float4 v7 = *(const float4*)(vp + 28);
    const float4* wb = ((const float4*)sW) + h * 8;
    for (int j = 0; j < NI; j++) {
      const float4* wr = wb + j * 16;
      float4 w0 = wr[0], w1 = wr[1], w2q = wr[2], w3 = wr[3];
      float4 w4 = wr[4], w5 = wr[5], w6 = wr[6], w7 = wr[7];
      float p0 = v0.x*w0.x + v0.y*w0.y + v0.z*w0.z + v0.w*w0.w;
      float p1 = v1.x*w1.x + v1.y*w1.y + v1.z*w1.z + v1.w*w1.w;
      float p2 = v2.x*w2q.x + v2.y*w2q.y + v2.z*w2q.z + v2.w*w2q.w;
      float p3 = v3.x*w3.x + v3.y*w3.y + v3.z*w3.z + v3.w*w3.w;
      float p4 = v4.x*w4.x + v4.y*w4.y + v4.z*w4.z + v4.w*w4.w;
      float p5 = v5.x*w5.x + v5.y*w5.y + v5.z*w5.z + v5.w*w5.w;
      float p6 = v6.x*w6.x + v6.y*w6.y + v6.z*w6.z + v6.w*w6.w;
      float p7 = v7.x*w7.x + v7.y*w7.y + v7.z*w7.z + v7.w*w7.w;
      float s = ((p0 + p1) + (p2 + p3)) + ((p4 + p5) + (p6 + p7));
      s += __shfl_xor(s, 32);
      s += b1[j];
      float t = 1.0f - 2.0f / (__expf(2.0f * s) + 1.0f);
      p += t * w2[j];
    }
  }
  if (h == 1) p = 0.0f;               // halves computed identical p
  for (int m = 32; m; m >>= 1) p += __shfl_xor(p, m);
  if (lane == 0) red[w] = p;
  __syncthreads();
  if (tid == 0) partials[g * NBLKM + blockIdx.x] = red[0] + red[1] + red[2] + red[3];
}

__global__ void k_beta(const float* __restrict__ partials, float* __restrict__ wsum) {
  int g = blockIdx.x;
  float s = 0.0f;
  for (int i = threadIdx.x; i < NBLKM; i += 256) s += partials[g * NBLKM + i];
  for (int m = 32; m; m >>= 1) s += __shfl_xor(s, m);
  __shared__ float r[4];
  if ((threadIdx.x & 63) == 0) r[threadIdx.x >> 6] = s;
  __syncthreads();
  if (threadIdx.x == 0) wsum[g] = r[0] + r[1] + r[2] + r[3];
}

// ---------------- gather outputs + ssl embedding prep (z precomputed) ----------------
__global__ __launch_bounds__(256) void k_h2out(
    const float* __restrict__ zu, const float* __restrict__ zi,
    const int* __restrict__ user_idx, const int* __restrict__ item_idx, const int* __restrict__ neg_idx,
    const float* __restrict__ total,
    const float* __restrict__ wsum, float* __restrict__ out,
    float* __restrict__ e1u, float* __restrict__ e2u,
    float* __restrict__ e1i, float* __restrict__ e2i, float* __restrict__ pos) {
  int lane = threadIdx.x & 63;
  int row = (blockIdx.x << 2) + (threadIdx.x >> 6);
  int seg = row >> 12;
  int r = row & 4095;
  int idx;
  const float* zb;
  int gbase;
  if (seg == 0)      { idx = user_idx[r]; zb = zu; gbase = 0; }
  else if (seg == 1) { idx = item_idx[r]; zb = zi; gbase = 2; }
  else               { idx = neg_idx[r];  zb = zi; gbase = 2; }
  int tnode = gbase ? (NUSERS + idx) : idx;
  float t = total[((long long)tnode << 6) + lane];
  float w0 = wsum[gbase] * (1.0f / 100000.0f);
  float w1 = wsum[gbase + 1] * (1.0f / 100000.0f);
  float mb = fmaxf(w0, w1);
  float b0 = expf(w0 - mb), b1 = expf(w1 - mb);
  float bs = b0 + b1;
  b0 /= bs; b1 /= bs;
  float z0 = zb[((long long)idx << 6) + lane];
  float z1 = zb[(((long long)NUSERS + idx) << 6) + lane];
  float h2 = b0 * z0 + b1 * z1;
  out[((long long)row << 6) + lane] = 0.5f * t + 0.5f * h2;
  if (seg < 2) {
    float n1 = h2 * h2, n2 = t * t;
    for (int m = 32; m; m >>= 1) { n1 += __shfl_xor(n1, m); n2 += __shfl_xor(n2, m); }
    n1 = sqrtf(n1); n2 = sqrtf(n2);
    float a = h2 / n1, b = t / n2;
    float d = a * b;
    for (int m = 32; m; m >>= 1) d += __shfl_xor(d, m);
    float* e1 = seg ? e1i : e1u;
    float* e2 = seg ? e2i : e2u;
    e1[((long long)r << 6) + lane] = a;
    e2[((long long)r << 6) + lane] = b;
    if (lane == 0) pos[seg * BB + r] = 2.0f * d;
  }
}

// ---------------- ssl similarity: 64x64 tile per block, 4x4 per thread ----------------
__global__ __launch_bounds__(256) void k_gemm(const float* __restrict__ e1u, const float* __restrict__ e2u,
                                              const float* __restrict__ e1i, const float* __restrict__ e2i,
                                              float* __restrict__ sumexp) {
  int side = blockIdx.z;
  const float* A = side ? e1i : e1u;
  const float* Bm = side ? e2i : e2u;
  __shared__ float sA[64][68], sB[64][68];
  int bb = blockIdx.y, kk = blockIdx.x;
  int tid = threadIdx.x;
  for (int i = tid; i < 1024; i += 256) {
    int row = i >> 4, d4 = (i & 15) << 2;
    float4 a = *(const float4*)&A[(((long long)(bb * 64 + row)) << 6) + d4];
    float4 b = *(const float4*)&Bm[(((long long)(kk * 64 + row)) << 6) + d4];
    *(float4*)&sA[row][d4] = a;
    *(float4*)&sB[row][d4] = b;
  }
  __syncthreads();
  int tx = tid & 15, ty = tid >> 4;
  int r0 = ty << 2, c0 = tx << 2;
  float acc[4][4] = {{0}};
  for (int k = 0; k < 64; k += 4) {
    float4 a0 = *(const float4*)&sA[r0 + 0][k];
    float4 a1 = *(const float4*)&sA[r0 + 1][k];
    float4 a2 = *(const float4*)&sA[r0 + 2][k];
    float4 a3 = *(const float4*)&sA[r0 + 3][k];
    float4 b0 = *(const float4*)&sB[c0 + 0][k];
    float4 b1 = *(const float4*)&sB[c0 + 1][k];
    float4 b2 = *(const float4*)&sB[c0 + 2][k];
    float4 b3 = *(const float4*)&sB[c0 + 3][k];
#define DOT(u_, v_) (u_.x*v_.x + u_.y*v_.y + u_.z*v_.z + u_.w*v_.w)
    acc[0][0] += DOT(a0, b0); acc[0][1] += DOT(a0, b1); acc[0][2] += DOT(a0, b2); acc[0][3] += DOT(a0, b3);
    acc[1][0] += DOT(a1, b0); acc[1][1] += DOT(a1, b1); acc[1][2] += DOT(a1, b2); acc[1][3] += DOT(a1, b3);
    acc[2][0] += DOT(a2, b0); acc[2][1] += DOT(a2, b1); acc[2][2] += DOT(a2, b2); acc[2][3] += DOT(a2, b3);
    acc[3][0] += DOT(a3, b0); acc[3][1] += DOT(a3, b1); acc[3][2] += DOT(a3, b2); acc[3][3] += DOT(a3, b3);
#undef DOT
  }
#pragma unroll
  for (int i = 0; i < 4; i++) {
    float rs = __expf(2.0f * acc[i][0]) + __expf(2.0f * acc[i][1])
             + __expf(2.0f * acc[i][2]) + __expf(2.0f * acc[i][3]);
    for (int m = 1; m < 16; m <<= 1) rs += __shfl_xor(rs, m);
    if (tx == 0)
      __hip_atomic_fetch_add(&sumexp[side * BB + bb * 64 + r0 + i], rs,
                             __ATOMIC_RELAXED, __HIP_MEMORY_SCOPE_AGENT);
  }
}

__global__ void k_loss(const float* __restrict__ sumexp, const float* __restrict__ pos,
                       float* __restrict__ out) {
  float s = 0.0f;
  for (int i = threadIdx.x; i < 2 * BB; i += 256) s += logf(sumexp[i]) - pos[i];
  for (int m = 32; m; m >>= 1) s += __shfl_xor(s, m);
  __shared__ float r[4];
  if ((threadIdx.x & 63) == 0) r[threadIdx.x >> 6] = s;
  __syncthreads();
  if (threadIdx.x == 0) out[3 * BB * DD] = (r[0] + r[1] + r[2] + r[3]) * (1.0f / (float)BB);
}

// ---------------- launch ----------------
extern "C" void kernel_launch(void* const* d_in, const int* in_sizes, int n_in,
                              void* d_out, int out_size, void* d_ws, size_t ws_size,
                              hipStream_t stream) {
  const float* uf  = (const float*)d_in[0];
  const float* itf = (const float*)d_in[1];
  const float* UIu = (const float*)d_in[2];
  const float* UIi = (const float*)d_in[3];
  const float* W1u = (const float*)d_in[4];
  const float* b1u = (const float*)d_in[5];
  const float* w2u = (const float*)d_in[6];
  const float* W1i = (const float*)d_in[7];
  const float* b1i = (const float*)d_in[8];
  const float* w2i = (const float*)d_in[9];
  const int* ui_src   = (const int*)d_in[10];
  const int* ui_dst   = (const int*)d_in[11];
  const int* mpu      = (const int*)d_in[12];
  const int* mpi      = (const int*)d_in[13];
  const int* user_idx = (const int*)d_in[14];
  const int* item_idx = (const int*)d_in[15];
  const int* neg_idx  = (const int*)d_in[16];
  float* out = (float*)d_out;

  float* wf = (float*)d_ws;
  int*   wi = (int*)d_ws;

  int*   cnt      = wi + O_CNT;
  int*   outcnt   = wi + O_OUTCNT;
  int*   cursor   = wi + O_CURSOR;
  float* partials = wf + O_PARTIALS;
  float* UITu     = wf + O_UIT_U;
  float* UITi     = wf + O_UIT_I;
  float* W1Tu     = wf + O_W1T_U;
  float* W1Ti     = wf + O_W1T_I;
  float* sumexp   = wf + O_SUMEXP;
  float* pos      = wf + O_POS;
  int*   off      = wi + O_OFF;
  int*   bsum     = wi + O_BSUM;
  float* dinv     = wf + O_DINV;
  float* oinv     = wf + O_OINV;
  float* iinv     = wf + O_IINV;
  int*   adj      = wi + O_ADJ;
  float* wsum     = wf + O_WSUM;
  float* emba     = wf + O_EMBA;
  float* total    = wf + O_TOTAL;
  float* embb     = wf + O_EMBB;
  float* e1u      = wf + O_E1U;
  float* e2u      = wf + O_E2U;
  float* e1i      = wf + O_E1I;
  float* e2i      = wf + O_E2I;

  hipMemsetAsync(d_ws, 0, (size_t)ZEND * 4, stream);

  k_hist_main<<<(E_UI + 255) / 256, 256, 0, stream>>>(ui_src, ui_dst, cnt);
  k_hist_mp<<<dim3((E_MP + 255) / 256, 4), 256, 0, stream>>>(mpu, mpi, cnt, outcnt);

  const int NSCAN = 600000;
  const int NB = (NSCAN + 1023) / 1024;
  k_scan1<<<NB, 1024, 0, stream>>>(cnt, off, bsum, NSCAN);
  k_scan2<<<1, 1024, 0, stream>>>(bsum, NB);
  k_scan3<<<NB, 1024, 0, stream>>>(off, bsum, NSCAN);

  k_inv<<<(600000 + 255) / 256, 256, 0, stream>>>(cnt, outcnt, dinv, iinv, oinv);

  k_scatter_main<<<(E_UI + 255) / 256, 256, 0, stream>>>(ui_src, ui_dst, off, cursor, adj);
  k_scatter_mp<<<dim3((E_MP + 255) / 256, 4), 256, 0, stream>>>(mpu, mpi, off, cursor, adj);

  k_init<<<(3200000 + 255) / 256, 256, 0, stream>>>((const float4*)uf, (const float4*)itf,
                                                    (float4*)emba);
  k_tw<<<32, 256, 0, stream>>>(UIu, UIi, W1u, W1i, UITu, UITi, W1Tu, W1Ti);

  // layer 0: spmm (gnn -> embb), then attention combine in-place
  k_spmm<<<50000, 256, 0, stream>>>(emba, embb, adj, off, cnt, dinv);
  k_attn<<<1564, 256, 0, stream>>>(emba, embb, total, UITu, UITi, 0);
  // layer 1: spmm (gnn -> emba), then attention combine in-place
  k_spmm<<<50000, 256, 0, stream>>>(embb, emba, adj, off, cnt, dinv);
  k_attn<<<1564, 256, 0, stream>>>(embb, emba, total, UITu, UITi, 1);

  // metapath: gather z into reused emba (graphs 0,1) / embb (graphs 2,3), then MLP score
  k_mp_gather<<<dim3(25000, 4), 256, 0, stream>>>(uf, itf, adj, off, cnt, oinv, iinv,
                                                  emba, embb);
  k_mp_mlp<<<dim3(NBLKM, 4), 256, 0, stream>>>(emba, embb, W1Tu, b1u, w2u, W1Ti, b1i, w2i,
                                               partials);
  k_beta<<<4, 256, 0, stream>>>(partials, wsum);

  k_h2out<<<3072, 256, 0, stream>>>(emba, embb, user_idx, item_idx, neg_idx, total,
                                    wsum, out, e1u, e2u, e1i, e2i, pos);

  k_gemm<<<dim3(64, 64, 2), 256, 0, stream>>>(e1u, e2u, e1i, e2i, sumexp);
  k_loss<<<1, 256, 0, stream>>>(sumexp, pos, out);
}

// Round 9
// 1397.894 us; speedup vs baseline: 2.7917x; 1.1129x over previous
//
#include <hip/hip_runtime.h>
#include <math.h>

// ---------------- problem constants ----------------
#define NUSERS   100000
#define NITEMS   100000
#define NNODES   200000
#define DD       64
#define NI       128
#define E_UI     1000000
#define E_MP     500000
#define BB       4096
#define NSTRIP   6250          // 100000 / 16

// ---------------- workspace layout (float/int elements, 4B each) ----------------
#define O_CNT       0LL
#define O_OUTCNT    600000LL
#define O_CURSOR    1000000LL
#define O_PARTIALS  1600000LL   // 25000 used (4 graphs x 6250 strips)
#define O_UIT_U     1625600LL   // 8192 f32
#define O_UIT_I     1633792LL   // 8192 f32
#define O_W1B_U     1641984LL   // 4096 f32-slots = 8192 bf16
#define O_W1B_I     1646080LL   // 4096
#define O_SUMEXP    1700000LL
#define O_POS       1708192LL
#define ZEND        1716384LL
#define O_OFF       1716384LL
#define O_BSUM      2316448LL
#define O_DINV      2317472LL
#define O_OINV      2517472LL
#define O_IINV      2917472LL
#define O_ADJ       3317472LL
#define O_WSUM      7317472LL
#define O_EMBA      7317480LL   // 12.8M: layer ping; reused as zbuf for mp graphs 0,1
#define O_TOTAL     20117480LL
#define O_EMBB      32917480LL  // 12.8M: layer pong; reused as zbuf for mp graphs 2,3
#define O_E1U       45717480LL
#define O_E2U       45979624LL
#define O_E1I       46241768LL
#define O_E2I       46503912LL

typedef __attribute__((ext_vector_type(8))) short short8;
typedef __attribute__((ext_vector_type(4))) float f32x4;

__device__ __forceinline__ short f2bf(float x) {
  unsigned u = __float_as_uint(x);
  unsigned r = (u + 0x7FFFu + ((u >> 16) & 1u)) >> 16;
  return (short)r;
}

// ---------------- degree histograms ----------------
__global__ void k_hist_main(const int* __restrict__ src, const int* __restrict__ dst,
                            int* __restrict__ cnt) {
  int e = blockIdx.x * 256 + threadIdx.x;
  if (e < E_UI) {
    atomicAdd(&cnt[src[e]], 1);
    atomicAdd(&cnt[NUSERS + dst[e]], 1);
  }
}

__global__ void k_hist_mp(const int* __restrict__ mpu, const int* __restrict__ mpi,
                          int* __restrict__ cnt, int* __restrict__ outcnt) {
  int e = blockIdx.x * 256 + threadIdx.x;
  int g = blockIdx.y;
  if (e < E_MP) {
    const int* base = (g < 2) ? (mpu + (long long)g * 2 * E_MP)
                              : (mpi + (long long)(g - 2) * 2 * E_MP);
    int s = base[e];
    int d = base[E_MP + e];
    atomicAdd(&outcnt[g * NUSERS + s], 1);
    atomicAdd(&cnt[NNODES + g * NUSERS + d], 1);
  }
}

// ---------------- exclusive scan ----------------
__global__ __launch_bounds__(1024) void k_scan1(const int* __restrict__ in, int* __restrict__ out,
                                                int* __restrict__ bsum, int n) {
  __shared__ int s[1024];
  int i = blockIdx.x * 1024 + threadIdx.x;
  int v = (i < n) ? in[i] : 0;
  s[threadIdx.x] = v;
  __syncthreads();
  for (int off = 1; off < 1024; off <<= 1) {
    int x = (threadIdx.x >= off) ? s[threadIdx.x - off] : 0;
    __syncthreads();
    s[threadIdx.x] += x;
    __syncthreads();
  }
  if (i < n) out[i] = s[threadIdx.x] - v;
  if (threadIdx.x == 1023) bsum[blockIdx.x] = s[1023];
}

__global__ __launch_bounds__(1024) void k_scan2(int* __restrict__ bsum, int nb) {
  __shared__ int s[1024];
  int v = (threadIdx.x < nb) ? bsum[threadIdx.x] : 0;
  s[threadIdx.x] = v;
  __syncthreads();
  for (int off = 1; off < 1024; off <<= 1) {
    int x = (threadIdx.x >= off) ? s[threadIdx.x - off] : 0;
    __syncthreads();
    s[threadIdx.x] += x;
    __syncthreads();
  }
  if (threadIdx.x < nb) bsum[threadIdx.x] = s[threadIdx.x] - v;
}

__global__ __launch_bounds__(1024) void k_scan3(int* __restrict__ out, const int* __restrict__ bsum, int n) {
  int i = blockIdx.x * 1024 + threadIdx.x;
  if (i < n) out[i] += bsum[blockIdx.x];
}

// ---------------- inverse-sqrt degrees ----------------
__global__ void k_inv(const int* __restrict__ cnt, const int* __restrict__ outcnt,
                      float* __restrict__ dinv, float* __restrict__ iinv, float* __restrict__ oinv) {
  int i = blockIdx.x * 256 + threadIdx.x;
  if (i < NNODES) {
    int c = cnt[i]; if (c < 1) c = 1;
    dinv[i] = 1.0f / sqrtf((float)c);
  } else if (i < 600000) {
    int c = cnt[i]; if (c < 1) c = 1;
    iinv[i - NNODES] = 1.0f / sqrtf((float)c);
  }
  if (i < 400000) {
    int c = outcnt[i]; if (c < 1) c = 1;
    oinv[i] = 1.0f / sqrtf((float)c);
  }
}

// ---------------- CSR scatter ----------------
__global__ void k_scatter_main(const int* __restrict__ src, const int* __restrict__ dst,
                               const int* __restrict__ off, int* __restrict__ cursor,
                               int* __restrict__ adj) {
  int e = blockIdx.x * 256 + threadIdx.x;
  if (e < E_UI) {
    int u = src[e];
    int it = NUSERS + dst[e];
    int p = atomicAdd(&cursor[u], 1);
    adj[off[u] + p] = it;
    int q = atomicAdd(&cursor[it], 1);
    adj[off[it] + q] = u;
  }
}

__global__ void k_scatter_mp(const int* __restrict__ mpu, const int* __restrict__ mpi,
                             const int* __restrict__ off, int* __restrict__ cursor,
                             int* __restrict__ adj) {
  int e = blockIdx.x * 256 + threadIdx.x;
  int g = blockIdx.y;
  if (e < E_MP) {
    const int* base = (g < 2) ? (mpu + (long long)g * 2 * E_MP)
                              : (mpi + (long long)(g - 2) * 2 * E_MP);
    int s = base[e];
    int d = base[E_MP + e];
    int node = NNODES + g * NUSERS + d;
    int p = atomicAdd(&cursor[node], 1);
    adj[off[node] + p] = s;
  }
}

// ---------------- emb init ----------------
__global__ void k_init(const float4* __restrict__ uf, const float4* __restrict__ itf,
                       float4* __restrict__ emb) {
  int i = blockIdx.x * 256 + threadIdx.x;
  if (i < 3200000) {
    emb[i] = (i < 1600000) ? uf[i] : itf[i - 1600000];
  }
}

// ---------------- weight prep: UIT f32 transposed; W1 -> bf16 [j][k] ----------------
__global__ void k_tw(const float* __restrict__ UIu, const float* __restrict__ UIi,
                     const float* __restrict__ W1u, const float* __restrict__ W1i,
                     float* __restrict__ UITu, float* __restrict__ UITi,
                     short* __restrict__ W1Bu, short* __restrict__ W1Bi) {
  int t = blockIdx.x * 256 + threadIdx.x;
  if (t < 8192) {
    int d = t >> 7, j = t & 127;
    UITu[j * 64 + d] = UIu[t];
    UITi[j * 64 + d] = UIi[t];
    W1Bu[j * 64 + d] = f2bf(W1u[t]);
    W1Bi[j * 64 + d] = f2bf(W1i[t]);
  }
}

// ---------------- masked-unroll-8 gather (dim = lane) ----------------
__device__ __forceinline__ float gather_rows(const float* __restrict__ tbl,
                                             const int* __restrict__ adj,
                                             int start, int c,
                                             const float* __restrict__ warr, int wofs,
                                             int lane) {
  float acc = 0.0f;
  for (int kb = 0; kb < c; kb += 64) {
    int rem = c - kb; if (rem > 64) rem = 64;
    int mi = 0; float mw = 0.0f;
    if (lane < rem) { mi = adj[start + kb + lane]; mw = warr[wofs + mi]; }
    for (int k = 0; k < rem; k += 8) {
      int n0=__shfl(mi,k+0),n1=__shfl(mi,k+1),n2=__shfl(mi,k+2),n3=__shfl(mi,k+3);
      int n4=__shfl(mi,k+4),n5=__shfl(mi,k+5),n6=__shfl(mi,k+6),n7=__shfl(mi,k+7);
      float w0=__shfl(mw,k+0),w1=__shfl(mw,k+1),w2=__shfl(mw,k+2),w3=__shfl(mw,k+3);
      float w4=__shfl(mw,k+4),w5=__shfl(mw,k+5),w6=__shfl(mw,k+6),w7=__shfl(mw,k+7);
      float v0=tbl[((long long)n0<<6)+lane], v1=tbl[((long long)n1<<6)+lane];
      float v2=tbl[((long long)n2<<6)+lane], v3=tbl[((long long)n3<<6)+lane];
      float v4=tbl[((long long)n4<<6)+lane], v5=tbl[((long long)n5<<6)+lane];
      float v6=tbl[((long long)n6<<6)+lane], v7=tbl[((long long)n7<<6)+lane];
      acc += w0*v0; acc += w1*v1; acc += w2*v2; acc += w3*v3;
      acc += w4*v4; acc += w5*v5; acc += w6*v6; acc += w7*v7;
    }
  }
  return acc;
}

// ---------------- spmm: wave per row, gnn stashed into enext ----------------
__global__ __launch_bounds__(256, 6) void k_spmm(
    const float* __restrict__ ecur, float* __restrict__ gnn,
    const int* __restrict__ adj, const int* __restrict__ off,
    const int* __restrict__ cnt, const float* __restrict__ dinv) {
  int row = (blockIdx.x << 2) + (threadIdx.x >> 6);
  int lane = threadIdx.x & 63;
  float acc = gather_rows(ecur, adj, off[row], cnt[row], dinv, 0, lane);
  gnn[((long long)row << 6) + lane] = dinv[row] * acc;
}

// ---------------- intent attention: half-split (lane = node x half-dim) ----------------
__global__ __launch_bounds__(256, 3) void k_attn(
    const float* __restrict__ ecur, float* __restrict__ enext, float* __restrict__ total,
    const float* __restrict__ UITu, const float* __restrict__ UITi, int layer) {
  __shared__ float sW[NI * DD];   // [j][d] flat, 32 KB
  int tid = threadIdx.x;
  int bx = blockIdx.x;
  const float* UIT; long long nbase; long long lim;
  if (bx < 782) { UIT = UITu; nbase = (long long)bx * 128;            lim = NUSERS; }
  else          { UIT = UITi; nbase = NUSERS + (long long)(bx - 782) * 128; lim = NNODES; }
  {
    const float4* srcw = (const float4*)UIT;
    float4* dstw = (float4*)sW;
    for (int i = tid; i < 2048; i += 256) dstw[i] = srcw[i];
  }
  __syncthreads();
  int w = tid >> 6, lane = tid & 63;
  int nloc = lane & 31, h = lane >> 5;
  long long node = nbase + w * 32 + nloc;
  if (node >= lim) return;   // wave-uniform (boundaries are multiples of 32)

  const float* vp = ecur + (node << 6) + h * 32;
  float4 v0 = *(const float4*)(vp +  0);
  float4 v1 = *(const float4*)(vp +  4);
  float4 v2 = *(const float4*)(vp +  8);
  float4 v3 = *(const float4*)(vp + 12);
  float4 v4 = *(const float4*)(vp + 16);
  float4 v5 = *(const float4*)(vp + 20);
  float4 v6 = *(const float4*)(vp + 24);
  float4 v7 = *(const float4*)(vp + 28);
  float4 o0 = make_float4(0,0,0,0), o1 = o0, o2 = o0, o3 = o0;
  float4 o4 = o0, o5 = o0, o6 = o0, o7 = o0;
  float den = 0.0f;
  const float4* wb = ((const float4*)sW) + h * 8;   // float4 index: j*16 + h*8
  for (int j = 0; j < NI; j++) {
    const float4* wr = wb + j * 16;
    float4 w0 = wr[0], w1 = wr[1], w2 = wr[2], w3 = wr[3];
    float4 w4 = wr[4], w5 = wr[5], w6 = wr[6], w7 = wr[7];
    float p0 = v0.x*w0.x + v0.y*w0.y + v0.z*w0.z + v0.w*w0.w;
    float p1 = v1.x*w1.x + v1.y*w1.y + v1.z*w1.z + v1.w*w1.w;
    float p2 = v2.x*w2.x + v2.y*w2.y + v2.z*w2.z + v2.w*w2.w;
    float p3 = v3.x*w3.x + v3.y*w3.y + v3.z*w3.z + v3.w*w3.w;
    float p4 = v4.x*w4.x + v4.y*w4.y + v4.z*w4.z + v4.w*w4.w;
    float p5 = v5.x*w5.x + v5.y*w5.y + v5.z*w5.z + v5.w*w5.w;
    float p6 = v6.x*w6.x + v6.y*w6.y + v6.z*w6.z + v6.w*w6.w;
    float p7 = v7.x*w7.x + v7.y*w7.y + v7.z*w7.z + v7.w*w7.w;
    float s = ((p0 + p1) + (p2 + p3)) + ((p4 + p5) + (p6 + p7));
    s += __shfl_xor(s, 32);
    float e = __expf(s);          // |s| << 1: no max-subtraction needed
    den += e;
    o0.x += e*w0.x; o0.y += e*w0.y; o0.z += e*w0.z; o0.w += e*w0.w;
    o1.x += e*w1.x; o1.y += e*w1.y; o1.z += e*w1.z; o1.w += e*w1.w;
    o2.x += e*w2.x; o2.y += e*w2.y; o2.z += e*w2.z; o2.w += e*w2.w;
    o3.x += e*w3.x; o3.y += e*w3.y; o3.z += e*w3.z; o3.w += e*w3.w;
    o4.x += e*w4.x; o4.y += e*w4.y; o4.z += e*w4.z; o4.w += e*w4.w;
    o5.x += e*w5.x; o5.y += e*w5.y; o5.z += e*w5.z; o5.w += e*w5.w;
    o6.x += e*w6.x; o6.y += e*w6.y; o6.z += e*w6.z; o6.w += e*w6.w;
    o7.x += e*w7.x; o7.y += e*w7.y; o7.z += e*w7.z; o7.w += e*w7.w;
  }
  float r = 1.0f / den;
  float* ep = enext + (node << 6) + h * 32;
  float* tp = total + (node << 6) + h * 32;
#define FINISH(q, vq, oq)                                                       \
  { float4 gn = *(float4*)(ep + (q)*4);                                        \
    float4 ne = make_float4(gn.x + oq.x*r + vq.x, gn.y + oq.y*r + vq.y,        \
                            gn.z + oq.z*r + vq.z, gn.w + oq.w*r + vq.w);       \
    *(float4*)(ep + (q)*4) = ne;                                               \
    if (layer == 0) {                                                          \
      *(float4*)(tp + (q)*4) = make_float4(vq.x + ne.x, vq.y + ne.y,           \
                                           vq.z + ne.z, vq.w + ne.w);          \
    } else {                                                                   \
      float4 tt = *(float4*)(tp + (q)*4);                                      \
      *(float4*)(tp + (q)*4) = make_float4(tt.x + ne.x, tt.y + ne.y,           \
                                           tt.z + ne.z, tt.w + ne.w);          \
    } }
  FINISH(0, v0, o0) FINISH(1, v1, o1) FINISH(2, v2, o2) FINISH(3, v3, o3)
  FINISH(4, v4, o4) FINISH(5, v5, o5) FINISH(6, v6, o6) FINISH(7, v7, o7)
#undef FINISH
}

// ---------------- metapath graphconv gather: z (x iinv) -> zbuf ----------------
__global__ __launch_bounds__(256, 6) void k_mp_gather(
    const float* __restrict__ uf, const float* __restrict__ itf,
    const int* __restrict__ adj, const int* __restrict__ off, const int* __restrict__ cnt,
    const float* __restrict__ oinv, const float* __restrict__ iinv,
    float* __restrict__ zu, float* __restrict__ zi) {
  int g = blockIdx.y;
  const float* feat = (g < 2) ? uf : itf;
  float* zb = (g < 2) ? zu + ((long long)g * NUSERS << 6)
                      : zi + ((long long)(g - 2) * NUSERS << 6);
  int n = (blockIdx.x << 2) + (threadIdx.x >> 6);
  int lane = threadIdx.x & 63;
  int gofs = g * NUSERS;
  int node = NNODES + gofs + n;
  float z = gather_rows(feat, adj, off[node], cnt[node], oinv, gofs, lane);
  zb[((long long)n << 6) + lane] = z * iinv[gofs + n];
}

// ---------------- metapath MLP score via MFMA ----------------
// One wave per 16-node strip: D(16x128) = z(16x64) @ W1(64x128) via 16 mfma 16x16x32,
// epilogue tanh(.+b1).w2 summed over everything (only the mean matters).
__global__ __launch_bounds__(256, 4) void k_mp_mlp(
    const float* __restrict__ zu, const float* __restrict__ zi,
    const short* __restrict__ W1Bu, const float* __restrict__ b1u, const float* __restrict__ w2u,
    const short* __restrict__ W1Bi, const float* __restrict__ b1i, const float* __restrict__ w2i,
    float* __restrict__ partials) {
  int g = blockIdx.y;
  const short* W1B = (g < 2) ? W1Bu : W1Bi;
  const float* b1  = (g < 2) ? b1u : b1i;
  const float* w2  = (g < 2) ? w2u : w2i;
  const float* zb  = (g < 2) ? zu + ((long long)g * NUSERS << 6)
                             : zi + ((long long)(g - 2) * NUSERS << 6);
  int w = threadIdx.x >> 6, lane = threadIdx.x & 63;
  int strip = blockIdx.x * 4 + w;
  if (strip >= NSTRIP) return;
  int quad = lane >> 4, mrow = lane & 15;
  // A fragments: A[m=mrow][k=quad*8+i], k-halves 0..31 / 32..63
  const float* zrow = zb + (((long long)(strip * 16 + mrow)) << 6) + quad * 8;
  float4 za0 = *(const float4*)(zrow);
  float4 za1 = *(const float4*)(zrow + 4);
  float4 zc0 = *(const float4*)(zrow + 32);
  float4 zc1 = *(const float4*)(zrow + 36);
  short8 a0 = { f2bf(za0.x), f2bf(za0.y), f2bf(za0.z), f2bf(za0.w),
                f2bf(za1.x), f2bf(za1.y), f2bf(za1.z), f2bf(za1.w) };
  short8 a1 = { f2bf(zc0.x), f2bf(zc0.y), f2bf(zc0.z), f2bf(zc0.w),
                f2bf(zc1.x), f2bf(zc1.y), f2bf(zc1.z), f2bf(zc1.w) };
  float psum = 0.0f;
#pragma unroll
  for (int jt = 0; jt < 8; jt++) {
    // B fragments: B[n=mrow (j within tile)][k=quad*8+i]
    const short* wr = W1B + ((jt * 16 + mrow) << 6) + quad * 8;
    short8 b0 = *(const short8*)(wr);
    short8 bh = *(const short8*)(wr + 32);
    f32x4 acc = {0.f, 0.f, 0.f, 0.f};
    acc = __builtin_amdgcn_mfma_f32_16x16x32_bf16(a0, b0, acc, 0, 0, 0);
    acc = __builtin_amdgcn_mfma_f32_16x16x32_bf16(a1, bh, acc, 0, 0, 0);
    // D: col(lane&15) = j within tile; row(quad*4+r) = node within strip
    int j = jt * 16 + mrow;
    float bj = b1[j], wj = w2[j];
#pragma unroll
    for (int r = 0; r < 4; r++) {
      float s = acc[r] + bj;
      psum += wj * (1.0f - 2.0f / (__expf(2.0f * s) + 1.0f));
    }
  }
  for (int m = 32; m; m >>= 1) psum += __shfl_xor(psum, m);
  if (lane == 0) partials[g * NSTRIP + strip] = psum;
}

__global__ void k_beta(const float* __restrict__ partials, float* __restrict__ wsum) {
  int g = blockIdx.x;
  float s = 0.0f;
  for (int i = threadIdx.x; i < NSTRIP; i += 256) s += partials[g * NSTRIP + i];
  for (int m = 32; m; m >>= 1) s += __shfl_xor(s, m);
  __shared__ float r[4];
  if ((threadIdx.x & 63) == 0) r[threadIdx.x >> 6] = s;
  __syncthreads();
  if (threadIdx.x == 0) wsum[g] = r[0] + r[1] + r[2] + r[3];
}

// ---------------- gather outputs + ssl embedding prep (z precomputed) ----------------
__global__ __launch_bounds__(256) void k_h2out(
    const float* __restrict__ zu, const float* __restrict__ zi,
    const int* __restrict__ user_idx, const int* __restrict__ item_idx, const int* __restrict__ neg_idx,
    const float* __restrict__ total,
    const float* __restrict__ wsum, float* __restrict__ out,
    float* __restrict__ e1u, float* __restrict__ e2u,
    float* __restrict__ e1i, float* __restrict__ e2i, float* __restrict__ pos) {
  int lane = threadIdx.x & 63;
  int row = (blockIdx.x << 2) + (threadIdx.x >> 6);
  int seg = row >> 12;
  int r = row & 4095;
  int idx;
  const float* zb;
  int gbase;
  if (seg == 0)      { idx = user_idx[r]; zb = zu; gbase = 0; }
  else if (seg == 1) { idx = item_idx[r]; zb = zi; gbase = 2; }
  else               { idx = neg_idx[r];  zb = zi; gbase = 2; }
  int tnode = gbase ? (NUSERS + idx) : idx;
  float t = total[((long long)tnode << 6) + lane];
  float w0 = wsum[gbase] * (1.0f / 100000.0f);
  float w1 = wsum[gbase + 1] * (1.0f / 100000.0f);
  float mb = fmaxf(w0, w1);
  float b0 = expf(w0 - mb), b1 = expf(w1 - mb);
  float bs = b0 + b1;
  b0 /= bs; b1 /= bs;
  float z0 = zb[((long long)idx << 6) + lane];
  float z1 = zb[(((long long)NUSERS + idx) << 6) + lane];
  float h2 = b0 * z0 + b1 * z1;
  out[((long long)row << 6) + lane] = 0.5f * t + 0.5f * h2;
  if (seg < 2) {
    float n1 = h2 * h2, n2 = t * t;
    for (int m = 32; m; m >>= 1) { n1 += __shfl_xor(n1, m); n2 += __shfl_xor(n2, m); }
    n1 = sqrtf(n1); n2 = sqrtf(n2);
    float a = h2 / n1, b = t / n2;
    float d = a * b;
    for (int m = 32; m; m >>= 1) d += __shfl_xor(d, m);
    float* e1 = seg ? e1i : e1u;
    float* e2 = seg ? e2i : e2u;
    e1[((long long)r << 6) + lane] = a;
    e2[((long long)r << 6) + lane] = b;
    if (lane == 0) pos[seg * BB + r] = 2.0f * d;
  }
}

// ---------------- ssl similarity: 64x64 tile per block, 4x4 per thread ----------------
__global__ __launch_bounds__(256) void k_gemm(const float* __restrict__ e1u, const float* __restrict__ e2u,
                                              const float* __restrict__ e1i, const float* __restrict__ e2i,
                                              float* __restrict__ sumexp) {
  int side = blockIdx.z;
  const float* A = side ? e1i : e1u;
  const float* Bm = side ? e2i : e2u;
  __shared__ float sA[64][68], sB[64][68];
  int bb = blockIdx.y, kk = blockIdx.x;
  int tid = threadIdx.x;
  for (int i = tid; i < 1024; i += 256) {
    int row = i >> 4, d4 = (i & 15) << 2;
    float4 a = *(const float4*)&A[(((long long)(bb * 64 + row)) << 6) + d4];
    float4 b = *(const float4*)&Bm[(((long long)(kk * 64 + row)) << 6) + d4];
    *(float4*)&sA[row][d4] = a;
    *(float4*)&sB[row][d4] = b;
  }
  __syncthreads();
  int tx = tid & 15, ty = tid >> 4;
  int r0 = ty << 2, c0 = tx << 2;
  float acc[4][4] = {{0}};
  for (int k = 0; k < 64; k += 4) {
    float4 a0 = *(const float4*)&sA[r0 + 0][k];
    float4 a1 = *(const float4*)&sA[r0 + 1][k];
    float4 a2 = *(const float4*)&sA[r0 + 2][k];
    float4 a3 = *(const float4*)&sA[r0 + 3][k];
    float4 b0 = *(const float4*)&sB[c0 + 0][k];
    float4 b1 = *(const float4*)&sB[c0 + 1][k];
    float4 b2 = *(const float4*)&sB[c0 + 2][k];
    float4 b3 = *(const float4*)&sB[c0 + 3][k];
#define DOT(u_, v_) (u_.x*v_.x + u_.y*v_.y + u_.z*v_.z + u_.w*v_.w)
    acc[0][0] += DOT(a0, b0); acc[0][1] += DOT(a0, b1); acc[0][2] += DOT(a0, b2); acc[0][3] += DOT(a0, b3);
    acc[1][0] += DOT(a1, b0); acc[1][1] += DOT(a1, b1); acc[1][2] += DOT(a1, b2); acc[1][3] += DOT(a1, b3);
    acc[2][0] += DOT(a2, b0); acc[2][1] += DOT(a2, b1); acc[2][2] += DOT(a2, b2); acc[2][3] += DOT(a2, b3);
    acc[3][0] += DOT(a3, b0); acc[3][1] += DOT(a3, b1); acc[3][2] += DOT(a3, b2); acc[3][3] += DOT(a3, b3);
#undef DOT
  }
#pragma unroll
  for (int i = 0; i < 4; i++) {
    float rs = __expf(2.0f * acc[i][0]) + __expf(2.0f * acc[i][1])
             + __expf(2.0f * acc[i][2]) + __expf(2.0f * acc[i][3]);
    for (int m = 1; m < 16; m <<= 1) rs += __shfl_xor(rs, m);
    if (tx == 0)
      __hip_atomic_fetch_add(&sumexp[side * BB + bb * 64 + r0 + i], rs,
                             __ATOMIC_RELAXED, __HIP_MEMORY_SCOPE_AGENT);
  }
}

__global__ void k_loss(const float* __restrict__ sumexp, const float* __restrict__ pos,
                       float* __restrict__ out) {
  float s = 0.0f;
  for (int i = threadIdx.x; i < 2 * BB; i += 256) s += logf(sumexp[i]) - pos[i];
  for (int m = 32; m; m >>= 1) s += __shfl_xor(s, m);
  __shared__ float r[4];
  if ((threadIdx.x & 63) == 0) r[threadIdx.x >> 6] = s;
  __syncthreads();
  if (threadIdx.x == 0) out[3 * BB * DD] = (r[0] + r[1] + r[2] + r[3]) * (1.0f / (float)BB);
}

// ---------------- launch ----------------
extern "C" void kernel_launch(void* const* d_in, const int* in_sizes, int n_in,
                              void* d_out, int out_size, void* d_ws, size_t ws_size,
                              hipStream_t stream) {
  const float* uf  = (const float*)d_in[0];
  const float* itf = (const float*)d_in[1];
  const float* UIu = (const float*)d_in[2];
  const float* UIi = (const float*)d_in[3];
  const float* W1u = (const float*)d_in[4];
  const float* b1u = (const float*)d_in[5];
  const float* w2u = (const float*)d_in[6];
  const float* W1i = (const float*)d_in[7];
  const float* b1i = (const float*)d_in[8];
  const float* w2i = (const float*)d_in[9];
  const int* ui_src   = (const int*)d_in[10];
  const int* ui_dst   = (const int*)d_in[11];
  const int* mpu      = (const int*)d_in[12];
  const int* mpi      = (const int*)d_in[13];
  const int* user_idx = (const int*)d_in[14];
  const int* item_idx = (const int*)d_in[15];
  const int* neg_idx  = (const int*)d_in[16];
  float* out = (float*)d_out;

  float* wf = (float*)d_ws;
  int*   wi = (int*)d_ws;

  int*   cnt      = wi + O_CNT;
  int*   outcnt   = wi + O_OUTCNT;
  int*   cursor   = wi + O_CURSOR;
  float* partials = wf + O_PARTIALS;
  float* UITu     = wf + O_UIT_U;
  float* UITi     = wf + O_UIT_I;
  short* W1Bu     = (short*)(wf + O_W1B_U);
  short* W1Bi     = (short*)(wf + O_W1B_I);
  float* sumexp   = wf + O_SUMEXP;
  float* pos      = wf + O_POS;
  int*   off      = wi + O_OFF;
  int*   bsum     = wi + O_BSUM;
  float* dinv     = wf + O_DINV;
  float* oinv     = wf + O_OINV;
  float* iinv     = wf + O_IINV;
  int*   adj      = wi + O_ADJ;
  float* wsum     = wf + O_WSUM;
  float* emba     = wf + O_EMBA;
  float* total    = wf + O_TOTAL;
  float* embb     = wf + O_EMBB;
  float* e1u      = wf + O_E1U;
  float* e2u      = wf + O_E2U;
  float* e1i      = wf + O_E1I;
  float* e2i      = wf + O_E2I;

  hipMemsetAsync(d_ws, 0, (size_t)ZEND * 4, stream);

  k_hist_main<<<(E_UI + 255) / 256, 256, 0, stream>>>(ui_src, ui_dst, cnt);
  k_hist_mp<<<dim3((E_MP + 255) / 256, 4), 256, 0, stream>>>(mpu, mpi, cnt, outcnt);

  const int NSCAN = 600000;
  const int NB = (NSCAN + 1023) / 1024;
  k_scan1<<<NB, 1024, 0, stream>>>(cnt, off, bsum, NSCAN);
  k_scan2<<<1, 1024, 0, stream>>>(bsum, NB);
  k_scan3<<<NB, 1024, 0, stream>>>(off, bsum, NSCAN);

  k_inv<<<(600000 + 255) / 256, 256, 0, stream>>>(cnt, outcnt, dinv, iinv, oinv);

  k_scatter_main<<<(E_UI + 255) / 256, 256, 0, stream>>>(ui_src, ui_dst, off, cursor, adj);
  k_scatter_mp<<<dim3((E_MP + 255) / 256, 4), 256, 0, stream>>>(mpu, mpi, off, cursor, adj);

  k_init<<<(3200000 + 255) / 256, 256, 0, stream>>>((const float4*)uf, (const float4*)itf,
                                                    (float4*)emba);
  k_tw<<<32, 256, 0, stream>>>(UIu, UIi, W1u, W1i, UITu, UITi, W1Bu, W1Bi);

  // layer 0: spmm (gnn -> embb), then attention combine in-place
  k_spmm<<<50000, 256, 0, stream>>>(emba, embb, adj, off, cnt, dinv);
  k_attn<<<1564, 256, 0, stream>>>(emba, embb, total, UITu, UITi, 0);
  // layer 1: spmm (gnn -> emba), then attention combine in-place
  k_spmm<<<50000, 256, 0, stream>>>(embb, emba, adj, off, cnt, dinv);
  k_attn<<<1564, 256, 0, stream>>>(embb, emba, total, UITu, UITi, 1);

  // metapath: gather z into reused emba (graphs 0,1) / embb (graphs 2,3), then MFMA MLP score
  k_mp_gather<<<dim3(25000, 4), 256, 0, stream>>>(uf, itf, adj, off, cnt, oinv, iinv,
                                                  emba, embb);
  k_mp_mlp<<<dim3((NSTRIP + 3) / 4, 4), 256, 0, stream>>>(emba, embb, W1Bu, b1u, w2u,
                                                          W1Bi, b1i, w2i, partials);
  k_beta<<<4, 256, 0, stream>>>(partials, wsum);

  k_h2out<<<3072, 256, 0, stream>>>(emba, embb, user_idx, item_idx, neg_idx, total,
                                    wsum, out, e1u, e2u, e1i, e2i, pos);

  k_gemm<<<dim3(64, 64, 2), 256, 0, stream>>>(e1u, e2u, e1i, e2i, sumexp);
  k_loss<<<1, 256, 0, stream>>>(sumexp, pos, out);
}

// Round 10
// 1349.766 us; speedup vs baseline: 2.8912x; 1.0357x over previous
//
#include <hip/hip_runtime.h>
#include <math.h>

// ---------------- problem constants ----------------
#define NUSERS   100000
#define NITEMS   100000
#define NNODES   200000
#define DD       64
#define NI       128
#define E_UI     1000000
#define E_MP     500000
#define BB       4096
#define NSTRIP   6250          // 100000 / 16

// ---------------- workspace layout (float/int elements, 4B each) ----------------
#define O_CNT       0LL
#define O_OUTCNT    600000LL
#define O_CURSOR    1000000LL
#define O_PARTIALS  1600000LL   // 25000 used (4 graphs x 6250 strips)
#define O_UITB_U    1625600LL   // 4096 f32 slots = 8192 bf16 (UI^T j-major)
#define O_UITB_I    1629696LL
#define O_UIB_U     1633792LL   // 4096 (UI d-major)
#define O_UIB_I     1637888LL
#define O_W1B_U     1641984LL   // 4096 (W1^T j-major)
#define O_W1B_I     1646080LL
#define O_SUMEXP    1700000LL
#define O_POS       1708192LL
#define ZEND        1716384LL
#define O_OFF       1716384LL
#define O_BSUM      2316448LL
#define O_DINV      2317472LL
#define O_OINV      2517472LL
#define O_IINV      2917472LL
#define O_ADJ       3317472LL
#define O_WSUM      7317472LL
#define O_EMBA      7317480LL   // 12.8M: layer ping; reused as zbuf for mp graphs 0,1
#define O_TOTAL     20117480LL
#define O_EMBB      32917480LL  // 12.8M: layer pong; reused as zbuf for mp graphs 2,3
#define O_E1U       45717480LL
#define O_E2U       45979624LL
#define O_E1I       46241768LL
#define O_E2I       46503912LL

typedef __attribute__((ext_vector_type(8))) short short8;
typedef __attribute__((ext_vector_type(4))) float f32x4;

__device__ __forceinline__ short f2bf(float x) {
  unsigned u = __float_as_uint(x);
  unsigned r = (u + 0x7FFFu + ((u >> 16) & 1u)) >> 16;
  return (short)r;
}

// ---------------- degree histograms ----------------
__global__ void k_hist_main(const int* __restrict__ src, const int* __restrict__ dst,
                            int* __restrict__ cnt) {
  int e = blockIdx.x * 256 + threadIdx.x;
  if (e < E_UI) {
    atomicAdd(&cnt[src[e]], 1);
    atomicAdd(&cnt[NUSERS + dst[e]], 1);
  }
}

__global__ void k_hist_mp(const int* __restrict__ mpu, const int* __restrict__ mpi,
                          int* __restrict__ cnt, int* __restrict__ outcnt) {
  int e = blockIdx.x * 256 + threadIdx.x;
  int g = blockIdx.y;
  if (e < E_MP) {
    const int* base = (g < 2) ? (mpu + (long long)g * 2 * E_MP)
                              : (mpi + (long long)(g - 2) * 2 * E_MP);
    int s = base[e];
    int d = base[E_MP + e];
    atomicAdd(&outcnt[g * NUSERS + s], 1);
    atomicAdd(&cnt[NNODES + g * NUSERS + d], 1);
  }
}

// ---------------- exclusive scan ----------------
__global__ __launch_bounds__(1024) void k_scan1(const int* __restrict__ in, int* __restrict__ out,
                                                int* __restrict__ bsum, int n) {
  __shared__ int s[1024];
  int i = blockIdx.x * 1024 + threadIdx.x;
  int v = (i < n) ? in[i] : 0;
  s[threadIdx.x] = v;
  __syncthreads();
  for (int off = 1; off < 1024; off <<= 1) {
    int x = (threadIdx.x >= off) ? s[threadIdx.x - off] : 0;
    __syncthreads();
    s[threadIdx.x] += x;
    __syncthreads();
  }
  if (i < n) out[i] = s[threadIdx.x] - v;
  if (threadIdx.x == 1023) bsum[blockIdx.x] = s[1023];
}

__global__ __launch_bounds__(1024) void k_scan2(int* __restrict__ bsum, int nb) {
  __shared__ int s[1024];
  int v = (threadIdx.x < nb) ? bsum[threadIdx.x] : 0;
  s[threadIdx.x] = v;
  __syncthreads();
  for (int off = 1; off < 1024; off <<= 1) {
    int x = (threadIdx.x >= off) ? s[threadIdx.x - off] : 0;
    __syncthreads();
    s[threadIdx.x] += x;
    __syncthreads();
  }
  if (threadIdx.x < nb) bsum[threadIdx.x] = s[threadIdx.x] - v;
}

__global__ __launch_bounds__(1024) void k_scan3(int* __restrict__ out, const int* __restrict__ bsum, int n) {
  int i = blockIdx.x * 1024 + threadIdx.x;
  if (i < n) out[i] += bsum[blockIdx.x];
}

// ---------------- inverse-sqrt degrees ----------------
__global__ void k_inv(const int* __restrict__ cnt, const int* __restrict__ outcnt,
                      float* __restrict__ dinv, float* __restrict__ iinv, float* __restrict__ oinv) {
  int i = blockIdx.x * 256 + threadIdx.x;
  if (i < NNODES) {
    int c = cnt[i]; if (c < 1) c = 1;
    dinv[i] = 1.0f / sqrtf((float)c);
  } else if (i < 600000) {
    int c = cnt[i]; if (c < 1) c = 1;
    iinv[i - NNODES] = 1.0f / sqrtf((float)c);
  }
  if (i < 400000) {
    int c = outcnt[i]; if (c < 1) c = 1;
    oinv[i] = 1.0f / sqrtf((float)c);
  }
}

// ---------------- CSR scatter ----------------
__global__ void k_scatter_main(const int* __restrict__ src, const int* __restrict__ dst,
                               const int* __restrict__ off, int* __restrict__ cursor,
                               int* __restrict__ adj) {
  int e = blockIdx.x * 256 + threadIdx.x;
  if (e < E_UI) {
    int u = src[e];
    int it = NUSERS + dst[e];
    int p = atomicAdd(&cursor[u], 1);
    adj[off[u] + p] = it;
    int q = atomicAdd(&cursor[it], 1);
    adj[off[it] + q] = u;
  }
}

__global__ void k_scatter_mp(const int* __restrict__ mpu, const int* __restrict__ mpi,
                             const int* __restrict__ off, int* __restrict__ cursor,
                             int* __restrict__ adj) {
  int e = blockIdx.x * 256 + threadIdx.x;
  int g = blockIdx.y;
  if (e < E_MP) {
    const int* base = (g < 2) ? (mpu + (long long)g * 2 * E_MP)
                              : (mpi + (long long)(g - 2) * 2 * E_MP);
    int s = base[e];
    int d = base[E_MP + e];
    int node = NNODES + g * NUSERS + d;
    int p = atomicAdd(&cursor[node], 1);
    adj[off[node] + p] = s;
  }
}

// ---------------- emb init ----------------
__global__ void k_init(const float4* __restrict__ uf, const float4* __restrict__ itf,
                       float4* __restrict__ emb) {
  int i = blockIdx.x * 256 + threadIdx.x;
  if (i < 3200000) {
    emb[i] = (i < 1600000) ? uf[i] : itf[i - 1600000];
  }
}

// ---------------- weight prep (bf16 variants) ----------------
__global__ void k_tw(const float* __restrict__ UIu, const float* __restrict__ UIi,
                     const float* __restrict__ W1u, const float* __restrict__ W1i,
                     short* __restrict__ UITBu, short* __restrict__ UITBi,
                     short* __restrict__ UIBu,  short* __restrict__ UIBi,
                     short* __restrict__ W1Bu,  short* __restrict__ W1Bi) {
  int t = blockIdx.x * 256 + threadIdx.x;
  if (t < 8192) {
    int d = t >> 7, j = t & 127;
    UITBu[j * 64 + d] = f2bf(UIu[t]);
    UITBi[j * 64 + d] = f2bf(UIi[t]);
    UIBu[t] = f2bf(UIu[t]);
    UIBi[t] = f2bf(UIi[t]);
    W1Bu[j * 64 + d] = f2bf(W1u[t]);
    W1Bi[j * 64 + d] = f2bf(W1i[t]);
  }
}

// ---------------- masked-unroll-8 gather (dim = lane) ----------------
__device__ __forceinline__ float gather_rows(const float* __restrict__ tbl,
                                             const int* __restrict__ adj,
                                             int start, int c,
                                             const float* __restrict__ warr, int wofs,
                                             int lane) {
  float acc = 0.0f;
  for (int kb = 0; kb < c; kb += 64) {
    int rem = c - kb; if (rem > 64) rem = 64;
    int mi = 0; float mw = 0.0f;
    if (lane < rem) { mi = adj[start + kb + lane]; mw = warr[wofs + mi]; }
    for (int k = 0; k < rem; k += 8) {
      int n0=__shfl(mi,k+0),n1=__shfl(mi,k+1),n2=__shfl(mi,k+2),n3=__shfl(mi,k+3);
      int n4=__shfl(mi,k+4),n5=__shfl(mi,k+5),n6=__shfl(mi,k+6),n7=__shfl(mi,k+7);
      float w0=__shfl(mw,k+0),w1=__shfl(mw,k+1),w2=__shfl(mw,k+2),w3=__shfl(mw,k+3);
      float w4=__shfl(mw,k+4),w5=__shfl(mw,k+5),w6=__shfl(mw,k+6),w7=__shfl(mw,k+7);
      float v0=tbl[((long long)n0<<6)+lane], v1=tbl[((long long)n1<<6)+lane];
      float v2=tbl[((long long)n2<<6)+lane], v3=tbl[((long long)n3<<6)+lane];
      float v4=tbl[((long long)n4<<6)+lane], v5=tbl[((long long)n5<<6)+lane];
      float v6=tbl[((long long)n6<<6)+lane], v7=tbl[((long long)n7<<6)+lane];
      acc += w0*v0; acc += w1*v1; acc += w2*v2; acc += w3*v3;
      acc += w4*v4; acc += w5*v5; acc += w6*v6; acc += w7*v7;
    }
  }
  return acc;
}

// ---------------- fused layer: spmm + MFMA intent attention + residual + total ----------------
// Block = 4 waves; wave = one 16-node strip (16 | 100000 so strips never straddle sides).
// sZ: gathered gnn rows (dim-major). sP: exp(S) rows (node-major, stride 132).
// No __syncthreads needed: all LDS producer/consumer pairs are same-wave.
__global__ __launch_bounds__(256) void k_layer(
    const float* __restrict__ ecur, float* __restrict__ enext, float* __restrict__ total,
    const int* __restrict__ adj, const int* __restrict__ off, const int* __restrict__ cnt,
    const float* __restrict__ dinv,
    const short* __restrict__ UITBu, const short* __restrict__ UITBi,
    const short* __restrict__ UIBu,  const short* __restrict__ UIBi, int layer) {
  __shared__ float sZ[4][16 * 68];
  __shared__ float sP[4][16 * 132];
  int w = threadIdx.x >> 6, lane = threadIdx.x & 63;
  int nb = blockIdx.x * 64 + w * 16;
  const short* UITB = (nb < NUSERS) ? UITBu : UITBi;
  const short* UIB  = (nb < NUSERS) ? UIBu  : UIBi;
  float* rowZ = sZ[w];
  float* rowP = sP[w];

  // ---- gather: gnn rows -> sZ ----
  for (int m = 0; m < 16; m++) {
    int node = nb + m;
    float acc = gather_rows(ecur, adj, off[node], cnt[node], dinv, 0, lane);
    rowZ[m * 68 + lane] = dinv[node] * acc;
  }

  int quad = lane >> 4, mrow = lane & 15;
  // ---- phase 1: S = v @ UI ; P = exp(S) -> sP ; den per node ----
  const float* vrow = ecur + (((long long)(nb + mrow)) << 6) + quad * 8;
  float4 va0 = *(const float4*)(vrow);
  float4 va1 = *(const float4*)(vrow + 4);
  float4 vc0 = *(const float4*)(vrow + 32);
  float4 vc1 = *(const float4*)(vrow + 36);
  short8 a0 = { f2bf(va0.x), f2bf(va0.y), f2bf(va0.z), f2bf(va0.w),
                f2bf(va1.x), f2bf(va1.y), f2bf(va1.z), f2bf(va1.w) };
  short8 a1 = { f2bf(vc0.x), f2bf(vc0.y), f2bf(vc0.z), f2bf(vc0.w),
                f2bf(vc1.x), f2bf(vc1.y), f2bf(vc1.z), f2bf(vc1.w) };
  float den0 = 0.f, den1 = 0.f, den2 = 0.f, den3 = 0.f;
  float* pw = rowP + (quad * 4) * 132 + mrow;
#pragma unroll
  for (int jt = 0; jt < 8; jt++) {
    const short* wr = UITB + ((jt * 16 + mrow) << 6) + quad * 8;
    short8 b0 = *(const short8*)(wr);
    short8 bh = *(const short8*)(wr + 32);
    f32x4 acc = {0.f, 0.f, 0.f, 0.f};
    acc = __builtin_amdgcn_mfma_f32_16x16x32_bf16(a0, b0, acc, 0, 0, 0);
    acc = __builtin_amdgcn_mfma_f32_16x16x32_bf16(a1, bh, acc, 0, 0, 0);
    float e0 = __expf(acc[0]), e1 = __expf(acc[1]);
    float e2 = __expf(acc[2]), e3 = __expf(acc[3]);
    den0 += e0; den1 += e1; den2 += e2; den3 += e3;
    float* pj = pw + jt * 16;
    pj[0] = e0; pj[132] = e1; pj[264] = e2; pj[396] = e3;
  }
  for (int mask = 1; mask <= 8; mask <<= 1) {
    den0 += __shfl_xor(den0, mask); den1 += __shfl_xor(den1, mask);
    den2 += __shfl_xor(den2, mask); den3 += __shfl_xor(den3, mask);
  }
  float rd0 = 1.f / den0, rd1 = 1.f / den1, rd2 = 1.f / den2, rd3 = 1.f / den3;

  // ---- phase 2: O = P @ UI^T (K=128) ; combine + store ----
#pragma unroll
  for (int dt = 0; dt < 4; dt++) {
    f32x4 acc = {0.f, 0.f, 0.f, 0.f};
#pragma unroll
    for (int c = 0; c < 4; c++) {
      const float* pr = rowP + mrow * 132 + c * 32 + quad * 8;
      float4 p0 = *(const float4*)(pr);
      float4 p1 = *(const float4*)(pr + 4);
      short8 af = { f2bf(p0.x), f2bf(p0.y), f2bf(p0.z), f2bf(p0.w),
                    f2bf(p1.x), f2bf(p1.y), f2bf(p1.z), f2bf(p1.w) };
      const short* br = UIB + ((dt * 16 + mrow) << 7) + c * 32 + quad * 8;
      short8 bf = *(const short8*)(br);
      acc = __builtin_amdgcn_mfma_f32_16x16x32_bf16(af, bf, acc, 0, 0, 0);
    }
    int d = dt * 16 + mrow;
#define COMB(r, rd)                                                            \
    { int node = nb + quad * 4 + r;                                            \
      long long base = (((long long)node) << 6) + d;                           \
      float o = acc[r] * rd;                                                   \
      float gn = rowZ[(quad * 4 + r) * 68 + d];                                \
      float vv = ecur[base];                                                   \
      float ne = gn + o + vv;                                                  \
      enext[base] = ne;                                                        \
      total[base] = (layer == 0) ? (vv + ne) : (total[base] + ne); }
    COMB(0, rd0) COMB(1, rd1) COMB(2, rd2) COMB(3, rd3)
#undef COMB
  }
}

// ---------------- metapath graphconv gather: z (x iinv) -> zbuf ----------------
__global__ __launch_bounds__(256, 6) void k_mp_gather(
    const float* __restrict__ uf, const float* __restrict__ itf,
    const int* __restrict__ adj, const int* __restrict__ off, const int* __restrict__ cnt,
    const float* __restrict__ oinv, const float* __restrict__ iinv,
    float* __restrict__ zu, float* __restrict__ zi) {
  int g = blockIdx.y;
  const float* feat = (g < 2) ? uf : itf;
  float* zb = (g < 2) ? zu + ((long long)g * NUSERS << 6)
                      : zi + ((long long)(g - 2) * NUSERS << 6);
  int n = (blockIdx.x << 2) + (threadIdx.x >> 6);
  int lane = threadIdx.x & 63;
  int gofs = g * NUSERS;
  int node = NNODES + gofs + n;
  float z = gather_rows(feat, adj, off[node], cnt[node], oinv, gofs, lane);
  zb[((long long)n << 6) + lane] = z * iinv[gofs + n];
}

// ---------------- metapath MLP score via MFMA ----------------
__global__ __launch_bounds__(256, 4) void k_mp_mlp(
    const float* __restrict__ zu, const float* __restrict__ zi,
    const short* __restrict__ W1Bu, const float* __restrict__ b1u, const float* __restrict__ w2u,
    const short* __restrict__ W1Bi, const float* __restrict__ b1i, const float* __restrict__ w2i,
    float* __restrict__ partials) {
  int g = blockIdx.y;
  const short* W1B = (g < 2) ? W1Bu : W1Bi;
  const float* b1  = (g < 2) ? b1u : b1i;
  const float* w2  = (g < 2) ? w2u : w2i;
  const float* zb  = (g < 2) ? zu + ((long long)g * NUSERS << 6)
                             : zi + ((long long)(g - 2) * NUSERS << 6);
  int w = threadIdx.x >> 6, lane = threadIdx.x & 63;
  int strip = blockIdx.x * 4 + w;
  if (strip >= NSTRIP) return;
  int quad = lane >> 4, mrow = lane & 15;
  const float* zrow = zb + (((long long)(strip * 16 + mrow)) << 6) + quad * 8;
  float4 za0 = *(const float4*)(zrow);
  float4 za1 = *(const float4*)(zrow + 4);
  float4 zc0 = *(const float4*)(zrow + 32);
  float4 zc1 = *(const float4*)(zrow + 36);
  short8 a0 = { f2bf(za0.x), f2bf(za0.y), f2bf(za0.z), f2bf(za0.w),
                f2bf(za1.x), f2bf(za1.y), f2bf(za1.z), f2bf(za1.w) };
  short8 a1 = { f2bf(zc0.x), f2bf(zc0.y), f2bf(zc0.z), f2bf(zc0.w),
                f2bf(zc1.x), f2bf(zc1.y), f2bf(zc1.z), f2bf(zc1.w) };
  float psum = 0.0f;
#pragma unroll
  for (int jt = 0; jt < 8; jt++) {
    const short* wr = W1B + ((jt * 16 + mrow) << 6) + quad * 8;
    short8 b0 = *(const short8*)(wr);
    short8 bh = *(const short8*)(wr + 32);
    f32x4 acc = {0.f, 0.f, 0.f, 0.f};
    acc = __builtin_amdgcn_mfma_f32_16x16x32_bf16(a0, b0, acc, 0, 0, 0);
    acc = __builtin_amdgcn_mfma_f32_16x16x32_bf16(a1, bh, acc, 0, 0, 0);
    int j = jt * 16 + mrow;
    float bj = b1[j], wj = w2[j];
#pragma unroll
    for (int r = 0; r < 4; r++) {
      float s = acc[r] + bj;
      psum += wj * (1.0f - 2.0f / (__expf(2.0f * s) + 1.0f));
    }
  }
  for (int m = 32; m; m >>= 1) psum += __shfl_xor(psum, m);
  if (lane == 0) partials[g * NSTRIP + strip] = psum;
}

__global__ void k_beta(const float* __restrict__ partials, float* __restrict__ wsum) {
  int g = blockIdx.x;
  float s = 0.0f;
  for (int i = threadIdx.x; i < NSTRIP; i += 256) s += partials[g * NSTRIP + i];
  for (int m = 32; m; m >>= 1) s += __shfl_xor(s, m);
  __shared__ float r[4];
  if ((threadIdx.x & 63) == 0) r[threadIdx.x >> 6] = s;
  __syncthreads();
  if (threadIdx.x == 0) wsum[g] = r[0] + r[1] + r[2] + r[3];
}

// ---------------- gather outputs + ssl embedding prep (z precomputed) ----------------
__global__ __launch_bounds__(256) void k_h2out(
    const float* __restrict__ zu, const float* __restrict__ zi,
    const int* __restrict__ user_idx, const int* __restrict__ item_idx, const int* __restrict__ neg_idx,
    const float* __restrict__ total,
    const float* __restrict__ wsum, float* __restrict__ out,
    float* __restrict__ e1u, float* __restrict__ e2u,
    float* __restrict__ e1i, float* __restrict__ e2i, float* __restrict__ pos) {
  int lane = threadIdx.x & 63;
  int row = (blockIdx.x << 2) + (threadIdx.x >> 6);
  int seg = row >> 12;
  int r = row & 4095;
  int idx;
  const float* zb;
  int gbase;
  if (seg == 0)      { idx = user_idx[r]; zb = zu; gbase = 0; }
  else if (seg == 1) { idx = item_idx[r]; zb = zi; gbase = 2; }
  else               { idx = neg_idx[r];  zb = zi; gbase = 2; }
  int tnode = gbase ? (NUSERS + idx) : idx;
  float t = total[((long long)tnode << 6) + lane];
  float w0 = wsum[gbase] * (1.0f / 100000.0f);
  float w1 = wsum[gbase + 1] * (1.0f / 100000.0f);
  float mb = fmaxf(w0, w1);
  float b0 = expf(w0 - mb), b1 = expf(w1 - mb);
  float bs = b0 + b1;
  b0 /= bs; b1 /= bs;
  float z0 = zb[((long long)idx << 6) + lane];
  float z1 = zb[(((long long)NUSERS + idx) << 6) + lane];
  float h2 = b0 * z0 + b1 * z1;
  out[((long long)row << 6) + lane] = 0.5f * t + 0.5f * h2;
  if (seg < 2) {
    float n1 = h2 * h2, n2 = t * t;
    for (int m = 32; m; m >>= 1) { n1 += __shfl_xor(n1, m); n2 += __shfl_xor(n2, m); }
    n1 = sqrtf(n1); n2 = sqrtf(n2);
    float a = h2 / n1, b = t / n2;
    float d = a * b;
    for (int m = 32; m; m >>= 1) d += __shfl_xor(d, m);
    float* e1 = seg ? e1i : e1u;
    float* e2 = seg ? e2i : e2u;
    e1[((long long)r << 6) + lane] = a;
    e2[((long long)r << 6) + lane] = b;
    if (lane == 0) pos[seg * BB + r] = 2.0f * d;
  }
}

// ---------------- ssl similarity: 64x64 tile per block, 4x4 per thread ----------------
__global__ __launch_bounds__(256) void k_gemm(const float* __restrict__ e1u, const float* __restrict__ e2u,
                                              const float* __restrict__ e1i, const float* __restrict__ e2i,
                                              float* __restrict__ sumexp) {
  int side = blockIdx.z;
  const float* A = side ? e1i : e1u;
  const float* Bm = side ? e2i : e2u;
  __shared__ float sA[64][68], sB[64][68];
  int bb = blockIdx.y, kk = blockIdx.x;
  int tid = threadIdx.x;
  for (int i = tid; i < 1024; i += 256) {
    int row = i >> 4, d4 = (i & 15) << 2;
    float4 a = *(const float4*)&A[(((long long)(bb * 64 + row)) << 6) + d4];
    float4 b = *(const float4*)&Bm[(((long long)(kk * 64 + row)) << 6) + d4];
    *(float4*)&sA[row][d4] = a;
    *(float4*)&sB[row][d4] = b;
  }
  __syncthreads();
  int tx = tid & 15, ty = tid >> 4;
  int r0 = ty << 2, c0 = tx << 2;
  float acc[4][4] = {{0}};
  for (int k = 0; k < 64; k += 4) {
    float4 a0 = *(const float4*)&sA[r0 + 0][k];
    float4 a1 = *(const float4*)&sA[r0 + 1][k];
    float4 a2 = *(const float4*)&sA[r0 + 2][k];
    float4 a3 = *(const float4*)&sA[r0 + 3][k];
    float4 b0 = *(const float4*)&sB[c0 + 0][k];
    float4 b1 = *(const float4*)&sB[c0 + 1][k];
    float4 b2 = *(const float4*)&sB[c0 + 2][k];
    float4 b3 = *(const float4*)&sB[c0 + 3][k];
#define DOT(u_, v_) (u_.x*v_.x + u_.y*v_.y + u_.z*v_.z + u_.w*v_.w)
    acc[0][0] += DOT(a0, b0); acc[0][1] += DOT(a0, b1); acc[0][2] += DOT(a0, b2); acc[0][3] += DOT(a0, b3);
    acc[1][0] += DOT(a1, b0); acc[1][1] += DOT(a1, b1); acc[1][2] += DOT(a1, b2); acc[1][3] += DOT(a1, b3);
    acc[2][0] += DOT(a2, b0); acc[2][1] += DOT(a2, b1); acc[2][2] += DOT(a2, b2); acc[2][3] += DOT(a2, b3);
    acc[3][0] += DOT(a3, b0); acc[3][1] += DOT(a3, b1); acc[3][2] += DOT(a3, b2); acc[3][3] += DOT(a3, b3);
#undef DOT
  }
#pragma unroll
  for (int i = 0; i < 4; i++) {
    float rs = __expf(2.0f * acc[i][0]) + __expf(2.0f * acc[i][1])
             + __expf(2.0f * acc[i][2]) + __expf(2.0f * acc[i][3]);
    for (int m = 1; m < 16; m <<= 1) rs += __shfl_xor(rs, m);
    if (tx == 0)
      __hip_atomic_fetch_add(&sumexp[side * BB + bb * 64 + r0 + i], rs,
                             __ATOMIC_RELAXED, __HIP_MEMORY_SCOPE_AGENT);
  }
}

__global__ void k_loss(const float* __restrict__ sumexp, const float* __restrict__ pos,
                       float* __restrict__ out) {
  float s = 0.0f;
  for (int i = threadIdx.x; i < 2 * BB; i += 256) s += logf(sumexp[i]) - pos[i];
  for (int m = 32; m; m >>= 1) s += __shfl_xor(s, m);
  __shared__ float r[4];
  if ((threadIdx.x & 63) == 0) r[threadIdx.x >> 6] = s;
  __syncthreads();
  if (threadIdx.x == 0) out[3 * BB * DD] = (r[0] + r[1] + r[2] + r[3]) * (1.0f / (float)BB);
}

// ---------------- launch ----------------
extern "C" void kernel_launch(void* const* d_in, const int* in_sizes, int n_in,
                              void* d_out, int out_size, void* d_ws, size_t ws_size,
                              hipStream_t stream) {
  const float* uf  = (const float*)d_in[0];
  const float* itf = (const float*)d_in[1];
  const float* UIu = (const float*)d_in[2];
  const float* UIi = (const float*)d_in[3];
  const float* W1u = (const float*)d_in[4];
  const float* b1u = (const float*)d_in[5];
  const float* w2u = (const float*)d_in[6];
  const float* W1i = (const float*)d_in[7];
  const float* b1i = (const float*)d_in[8];
  const float* w2i = (const float*)d_in[9];
  const int* ui_src   = (const int*)d_in[10];
  const int* ui_dst   = (const int*)d_in[11];
  const int* mpu      = (const int*)d_in[12];
  const int* mpi      = (const int*)d_in[13];
  const int* user_idx = (const int*)d_in[14];
  const int* item_idx = (const int*)d_in[15];
  const int* neg_idx  = (const int*)d_in[16];
  float* out = (float*)d_out;

  float* wf = (float*)d_ws;
  int*   wi = (int*)d_ws;

  int*   cnt      = wi + O_CNT;
  int*   outcnt   = wi + O_OUTCNT;
  int*   cursor   = wi + O_CURSOR;
  float* partials = wf + O_PARTIALS;
  short* UITBu    = (short*)(wf + O_UITB_U);
  short* UITBi    = (short*)(wf + O_UITB_I);
  short* UIBu     = (short*)(wf + O_UIB_U);
  short* UIBi     = (short*)(wf + O_UIB_I);
  short* W1Bu     = (short*)(wf + O_W1B_U);
  short* W1Bi     = (short*)(wf + O_W1B_I);
  float* sumexp   = wf + O_SUMEXP;
  float* pos      = wf + O_POS;
  int*   off      = wi + O_OFF;
  int*   bsum     = wi + O_BSUM;
  float* dinv     = wf + O_DINV;
  float* oinv     = wf + O_OINV;
  float* iinv     = wf + O_IINV;
  int*   adj      = wi + O_ADJ;
  float* wsum     = wf + O_WSUM;
  float* emba     = wf + O_EMBA;
  float* total    = wf + O_TOTAL;
  float* embb     = wf + O_EMBB;
  float* e1u      = wf + O_E1U;
  float* e2u      = wf + O_E2U;
  float* e1i      = wf + O_E1I;
  float* e2i      = wf + O_E2I;

  hipMemsetAsync(d_ws, 0, (size_t)ZEND * 4, stream);

  k_hist_main<<<(E_UI + 255) / 256, 256, 0, stream>>>(ui_src, ui_dst, cnt);
  k_hist_mp<<<dim3((E_MP + 255) / 256, 4), 256, 0, stream>>>(mpu, mpi, cnt, outcnt);

  const int NSCAN = 600000;
  const int NB = (NSCAN + 1023) / 1024;
  k_scan1<<<NB, 1024, 0, stream>>>(cnt, off, bsum, NSCAN);
  k_scan2<<<1, 1024, 0, stream>>>(bsum, NB);
  k_scan3<<<NB, 1024, 0, stream>>>(off, bsum, NSCAN);

  k_inv<<<(600000 + 255) / 256, 256, 0, stream>>>(cnt, outcnt, dinv, iinv, oinv);

  k_scatter_main<<<(E_UI + 255) / 256, 256, 0, stream>>>(ui_src, ui_dst, off, cursor, adj);
  k_scatter_mp<<<dim3((E_MP + 255) / 256, 4), 256, 0, stream>>>(mpu, mpi, off, cursor, adj);

  k_init<<<(3200000 + 255) / 256, 256, 0, stream>>>((const float4*)uf, (const float4*)itf,
                                                    (float4*)emba);
  k_tw<<<32, 256, 0, stream>>>(UIu, UIi, W1u, W1i, UITBu, UITBi, UIBu, UIBi, W1Bu, W1Bi);

  // fused layers (spmm + MFMA attention + residual + total)
  k_layer<<<3125, 256, 0, stream>>>(emba, embb, total, adj, off, cnt, dinv,
                                    UITBu, UITBi, UIBu, UIBi, 0);
  k_layer<<<3125, 256, 0, stream>>>(embb, emba, total, adj, off, cnt, dinv,
                                    UITBu, UITBi, UIBu, UIBi, 1);

  // metapath: gather z into reused emba (graphs 0,1) / embb (graphs 2,3), then MFMA MLP score
  k_mp_gather<<<dim3(25000, 4), 256, 0, stream>>>(uf, itf, adj, off, cnt, oinv, iinv,
                                                  emba, embb);
  k_mp_mlp<<<dim3((NSTRIP + 3) / 4, 4), 256, 0, stream>>>(emba, embb, W1Bu, b1u, w2u,
                                                          W1Bi, b1i, w2i, partials);
  k_beta<<<4, 256, 0, stream>>>(partials, wsum);

  k_h2out<<<3072, 256, 0, stream>>>(emba, embb, user_idx, item_idx, neg_idx, total,
                                    wsum, out, e1u, e2u, e1i, e2i, pos);

  k_gemm<<<dim3(64, 64, 2), 256, 0, stream>>>(e1u, e2u, e1i, e2i, sumexp);
  k_loss<<<1, 256, 0, stream>>>(sumexp, pos, out);
}